// Round 4
// baseline (855.152 us; speedup 1.0000x reference)
//
#include <hip/hip_runtime.h>
#include <cmath>

// Shapes (fixed by the problem)
#define AT 225      // Z*Y*X anchors
#define NP 128      // points per sample
#define MT 1024     // B*T
#define NSEL 8
#define HD 64

// workspace float offsets
#define SZ_VOX  (1024u*64u*225u)      // 14,745,600  vox[m][h][a]
#define SZ_C1   (1024u*96u*63u)      // 6,193,152   c1[m][o][p]  (idx aliases this before conv1)
#define SZ_C2   (1024u*128u*5u)      // 655,360     c2[m][o][zo]
#define SZ_VV   (1024u*64u)          // 65,536
#define SZ_XWI  (1024u*256u)         // 262,144  (w3m aliases its head before k_xwi runs)
#define SZ_W1T  (64u*27u*96u)        // 165,888 floats reserved; holds w1m (165,888 bf16)
#define SZ_W2T  (96u*27u*128u)       // 331,776
#define SZ_W3T  (640u*64u)           // 40,960

typedef __attribute__((ext_vector_type(8))) short bf16x8;
typedef __attribute__((ext_vector_type(4))) float f32x4;

__device__ __forceinline__ float sigm(float x) { return 1.0f / (1.0f + expf(-x)); }

__device__ __forceinline__ unsigned short f2bf(float f) {
    unsigned u = __float_as_uint(f);
    unsigned r = u + 0x7FFF + ((u >> 16) & 1);   // RNE
    return (unsigned short)(r >> 16);
}

// ---------------------------------------------------------------- transpose
// w1m: conv1 MFMA A-frag pre-swizzle (see round 2).
// w2t[(c*27+tap)*128+o] = w2[o][c][tap]   (128,96,27)
// w3t[k*64+u]           = w3[u][k]        (64,640)
// w3m: pn_w3 B-frag pre-swizzle: entry(nt,lane,j) = bf16(pn_w3[k][n]),
//      n = nt*16+(lane&15), k = (lane>>4)*8+j;  linear = (nt*64+lane)*8+j
__global__ __launch_bounds__(256) void k_transpose(
    const float* __restrict__ w1, const float* __restrict__ w2,
    const float* __restrict__ w3, const float* __restrict__ pnw3,
    unsigned short* __restrict__ w1m, float* __restrict__ w2t,
    float* __restrict__ w3t, unsigned short* __restrict__ w3m)
{
    int idx = blockIdx.x * 256 + threadIdx.x;
    if (idx < 20736) {
        int lane = idx & 63, r = idx >> 6;
        int t = r % 6, s = r / 6;
        int o = t * 16 + (lane & 15);
        int kb = s * 32 + (lane >> 4) * 8;
        unsigned int dw[4];
        #pragma unroll
        for (int jd = 0; jd < 4; ++jd) {
            int k0 = kb + 2 * jd, k1 = k0 + 1;
            int tap0 = k0 >> 6, c0 = k0 & 63;
            int tap1 = k1 >> 6, c1 = k1 & 63;
            unsigned short lo = f2bf(w1[o * 1728 + c0 * 27 + tap0]);
            unsigned short hi = f2bf(w1[o * 1728 + c1 * 27 + tap1]);
            dw[jd] = (unsigned)lo | ((unsigned)hi << 16);
        }
        uint4 v; v.x = dw[0]; v.y = dw[1]; v.z = dw[2]; v.w = dw[3];
        ((uint4*)w1m)[idx] = v;
    } else if (idx < (int)(20736 + SZ_W2T)) {
        int k = idx - 20736;
        int o = k % 128, r = k / 128;
        w2t[k] = w2[o * 2592 + r];
    } else if (idx < (int)(20736 + SZ_W2T + SZ_W3T)) {
        int k = idx - (20736 + SZ_W2T);
        int u = k & 63, r = k >> 6;
        w3t[k] = w3[u * 640 + r];
    } else if (idx < (int)(20736 + SZ_W2T + SZ_W3T + 256)) {
        int k = idx - (20736 + SZ_W2T + SZ_W3T);
        int lane = k & 63, nt = k >> 6;
        int n = nt * 16 + (lane & 15);
        int kb = (lane >> 4) * 8;
        unsigned int dw[4];
        #pragma unroll
        for (int jd = 0; jd < 4; ++jd) {
            int k0 = kb + 2 * jd;
            unsigned short lo = f2bf(pnw3[k0 * 64 + n]);
            unsigned short hi = f2bf(pnw3[(k0 + 1) * 64 + n]);
            dw[jd] = (unsigned)lo | ((unsigned)hi << 16);
        }
        uint4 v; v.x = dw[0]; v.y = dw[1]; v.z = dw[2]; v.w = dw[3];
        ((uint4*)w3m)[k] = v;
    }
}

// ---------------------------------------------------------------- grouping
__global__ __launch_bounds__(256) void k_group(
    const float* __restrict__ x, const float* __restrict__ g_loc,
    int* __restrict__ idxbuf)
{
    const int m = blockIdx.x;
    const int tid = threadIdx.x;
    __shared__ float pts[3][NP];

    for (int idx = tid; idx < NP * 5; idx += 256) {
        int n = idx / 5, c = idx % 5;
        if (c < 3) pts[c][n] = x[m * (NP * 5) + idx];
    }
    __syncthreads();

    const float gx = g_loc[m * 2 + 0], gy = g_loc[m * 2 + 1];
    const int grp = tid >> 3, li = tid & 7;

    for (int ca = 0; ca < 256; ca += 32) {
        const int a = ca + grp;
        const bool active = (a < AT);
        const int aa = active ? a : (AT - 1);
        const int azi = aa / 25, ar = aa % 25, ayi = ar / 5, axi = ar % 5;
        const float fx = ((float)axi - 2.0f) * 0.2f + gx;
        const float fy = ((float)ayi - 2.0f) * 0.2f + gy;
        const float fz = (float)azi * 0.22f + 0.1f;
        const float sa = fx * fx + fy * fy + fz * fz;

        float d[16];
        #pragma unroll
        for (int r = 0; r < 16; ++r) {
            int n = li * 16 + r;
            float px = pts[0][n], py = pts[1][n], pz = pts[2][n];
            d[r] = sa - 2.0f * (fx * px + fy * py + fz * pz)
                      + (px * px + py * py + pz * pz);
        }
        int nidx = 0;
        for (int j = 0; j < NSEL; ++j) {
            float best = 1e30f; int bidx = 0;
            #pragma unroll
            for (int r = 0; r < 16; ++r) {
                int n = li * 16 + r;
                if (d[r] < best) { best = d[r]; bidx = n; }
            }
            #pragma unroll
            for (int off = 1; off < 8; off <<= 1) {
                float ov = __shfl_xor(best, off);
                int   oi = __shfl_xor(bidx, off);
                if (ov < best || (ov == best && oi < bidx)) { best = ov; bidx = oi; }
            }
            if (li == j) nidx = bidx;
            if ((bidx >> 4) == li) {
                int slot = bidx & 15;
                #pragma unroll
                for (int r = 0; r < 16; ++r)
                    if (r == slot) d[r] = 1e30f;
            }
        }
        if (active) idxbuf[(m * AT + a) * NSEL + li] = nidx;
    }
}

// ---------------------------------------------------------------- MLP (MFMA)
// 128 threads = 2 waves = 128 rows. Layers 1-2 per-thread f32; f2 staged to
// LDS as bf16 (row stride 17 dwords, conflict-free); layer 3 = 4 M-tiles x
// 4 N-tiles of mfma_f32_16x16x32_bf16 per wave; attention softmax + weighted
// sum done in the MFMA D layout (row=quad*4+reg, col=lane&15) via shfl_xor.
__global__ __launch_bounds__(128) void k_mlpm(
    const float* __restrict__ x, const float* __restrict__ g_loc,
    const int* __restrict__ idxbuf,
    const float* __restrict__ w1, const float* __restrict__ b1,
    const float* __restrict__ w2, const float* __restrict__ b2,
    const unsigned short* __restrict__ w3m, const float* __restrict__ b3,
    const float* __restrict__ aw, const float* __restrict__ ab,
    float* __restrict__ vox, float* __restrict__ attn_out)
{
    const int tid = threadIdx.x;
    const int row0 = blockIdx.x * 128;
    const int row = row0 + tid;

    __shared__ float pts[2][5][NP];          // 5120 B
    __shared__ unsigned int f2frag[128 * 17];// 8704 B  (bf16 pairs, stride 17 dw)
    __shared__ float at_lds[128];            // 512 B
    __shared__ float sbuf[16 * 65];          // 4160 B   total 18496 B -> 8 blk/CU

    const int m0 = row0 / 1800;
    const int m1 = (row0 + 127) / 1800;
    #pragma unroll
    for (int mm = 0; mm < 2; ++mm) {
        int mload = (mm == 0) ? m0 : m1;
        for (int i = tid; i < NP * 5; i += 128) {
            int n = i / 5, c = i % 5;
            pts[mm][c][n] = x[mload * (NP * 5) + i];
        }
    }
    __syncthreads();

    // ---- phase A: layers 1-2, per-thread ----
    const int m = row / 1800;
    const int rr = row % 1800;
    const int a = rr >> 3;
    const int sel = (m == m0) ? 0 : 1;

    const int azi = a / 25, ar = a % 25, ayi = ar / 5, axi = ar % 5;
    const float gx = g_loc[m * 2 + 0], gy = g_loc[m * 2 + 1];
    const float fx = ((float)axi - 2.0f) * 0.2f + gx;
    const float fy = ((float)ayi - 2.0f) * 0.2f + gy;
    const float fz = (float)azi * 0.22f + 0.1f;

    const int nidx = idxbuf[row];
    const float in0 = pts[sel][0][nidx] - fx;
    const float in1 = pts[sel][1][nidx] - fy;
    const float in2 = pts[sel][2][nidx] - fz;
    const float in3 = pts[sel][3][nidx];
    const float in4 = pts[sel][4][nidx];

    float f1v[16];
    #pragma unroll
    for (int j = 0; j < 16; ++j) {
        float s = b1[j];
        s += in0 * w1[0 * 16 + j] + in1 * w1[1 * 16 + j] + in2 * w1[2 * 16 + j]
           + in3 * w1[3 * 16 + j] + in4 * w1[4 * 16 + j];
        f1v[j] = fmaxf(s, 0.0f);
    }
    float f2v[32];
    #pragma unroll
    for (int j = 0; j < 32; ++j) {
        float s = b2[j];
        #pragma unroll
        for (int i = 0; i < 16; ++i) s += f1v[i] * w2[i * 32 + j];
        f2v[j] = fmaxf(s, 0.0f);
    }
    // stage f2 as bf16 pairs
    #pragma unroll
    for (int kd = 0; kd < 16; ++kd) {
        unsigned dw = (unsigned)f2bf(f2v[2 * kd]) |
                      ((unsigned)f2bf(f2v[2 * kd + 1]) << 16);
        f2frag[tid * 17 + kd] = dw;
    }
    __syncthreads();

    // ---- phase B: MFMA layer 3 + attention epilogue ----
    const int wv = tid >> 6, lane = tid & 63;
    const int quad = lane >> 4, mcol = lane & 15;

    bf16x8 w3f[4];
    #pragma unroll
    for (int nt = 0; nt < 4; ++nt) {
        uint4 u = ((const uint4*)w3m)[nt * 64 + lane];
        w3f[nt] = __builtin_bit_cast(bf16x8, u);
    }
    float b3v[4], awv[4];
    #pragma unroll
    for (int nt = 0; nt < 4; ++nt) {
        b3v[nt] = b3[nt * 16 + mcol];
        awv[nt] = aw[nt * 16 + mcol];
    }
    const float ab0 = ab[0];

    #pragma unroll
    for (int mt = 0; mt < 4; ++mt) {
        const int trow = (wv * 4 + mt) * 16 + mcol;
        const int abase = trow * 17 + quad * 4;
        uint4 au;
        au.x = f2frag[abase + 0]; au.y = f2frag[abase + 1];
        au.z = f2frag[abase + 2]; au.w = f2frag[abase + 3];
        bf16x8 af = __builtin_bit_cast(bf16x8, au);

        f32x4 acc[4];
        #pragma unroll
        for (int nt = 0; nt < 4; ++nt) {
            f32x4 z = (f32x4){0.f, 0.f, 0.f, 0.f};
            acc[nt] = __builtin_amdgcn_mfma_f32_16x16x32_bf16(af, w3f[nt], z, 0, 0, 0);
        }
        // f3 = relu(acc + b3); sc partial per row(reg)
        float f3[4][4];
        float part[4] = {0.f, 0.f, 0.f, 0.f};
        #pragma unroll
        for (int nt = 0; nt < 4; ++nt)
            #pragma unroll
            for (int reg = 0; reg < 4; ++reg) {
                float v = fmaxf(acc[nt][reg] + b3v[nt], 0.0f);
                f3[nt][reg] = v;
                part[reg] = fmaf(v, awv[nt], part[reg]);
            }
        #pragma unroll
        for (int off = 1; off < 16; off <<= 1)
            #pragma unroll
            for (int reg = 0; reg < 4; ++reg)
                part[reg] += __shfl_xor(part[reg], off);
        float sc[4];
        #pragma unroll
        for (int reg = 0; reg < 4; ++reg) sc[reg] = part[reg] + ab0;

        // softmax over the 8 rows of the anchor (this quad + partner quad)
        float mx4 = fmaxf(fmaxf(sc[0], sc[1]), fmaxf(sc[2], sc[3]));
        float mx = fmaxf(mx4, __shfl_xor(mx4, 16));
        float e[4]; float dh = 0.f;
        #pragma unroll
        for (int reg = 0; reg < 4; ++reg) { e[reg] = expf(sc[reg] - mx); dh += e[reg]; }
        float den = dh + __shfl_xor(dh, 16);
        float at[4];
        #pragma unroll
        for (int reg = 0; reg < 4; ++reg) at[reg] = e[reg] / den;

        if (mcol == 0) {
            #pragma unroll
            for (int reg = 0; reg < 4; ++reg)
                at_lds[(wv * 4 + mt) * 16 + quad * 4 + reg] = at[reg];
        }
        // weighted sum over the anchor's 8 rows
        #pragma unroll
        for (int nt = 0; nt < 4; ++nt) {
            float po = at[0] * f3[nt][0] + at[1] * f3[nt][1]
                     + at[2] * f3[nt][2] + at[3] * f3[nt][3];
            po += __shfl_xor(po, 16);
            if ((quad & 1) == 0) {
                int a_loc = (wv * 4 + mt) * 2 + (quad >> 1);
                sbuf[a_loc * 65 + nt * 16 + mcol] = po;
            }
        }
    }
    __syncthreads();

    // coalesced outputs
    attn_out[row0 + tid] = at_lds[tid];
    const int al = tid & 15, j = tid >> 4;
    const int ga = (row0 >> 3) + al;
    const int ma = ga / 225, aa2 = ga % 225;
    #pragma unroll
    for (int rep = 0; rep < 8; ++rep) {
        int h = j * 8 + rep;
        vox[(ma * 64 + h) * AT + aa2] = sbuf[al * 65 + h];
    }
}

// ---------------------------------------------------------------- conv1 MFMA
__global__ __launch_bounds__(256) void k_conv1m(
    const float* __restrict__ vox, const unsigned short* __restrict__ w1m,
    const float* __restrict__ b1, float* __restrict__ out)
{
    const int m = blockIdx.x;
    const int tid = threadIdx.x;
    __shared__ unsigned short voxT[225 * 66];

    for (int i = tid; i < 64 * 225; i += 256) {
        int c = i / 225, a = i - c * 225;
        voxT[a * 66 + c] = f2bf(vox[m * (64 * 225) + i]);
    }
    __syncthreads();

    const int wv = tid >> 6, lane = tid & 63;
    const int quad = lane >> 4, n = lane & 15;
    const int p = wv * 16 + n;
    const int pe = (p > 62) ? 62 : p;
    const int zo = pe / 9, pr = pe % 9, yo = pr / 3, xo = pr % 3;
    const int basep = zo * 25 + yo * 5 + xo;

    f32x4 acc[6];
    #pragma unroll
    for (int t = 0; t < 6; ++t) acc[t] = (f32x4){0.f, 0.f, 0.f, 0.f};

    const uint4* Aptr = (const uint4*)w1m;

    auto loadB = [&](int s) -> uint4 {
        int tap = s >> 1;
        int dz = tap / 9, tr = tap % 9, dy = tr / 3, dx = tr % 3;
        int row = basep + dz * 25 + dy * 5 + dx;
        int bidx = row * 66 + (s & 1) * 32 + quad * 8;
        const unsigned int* vp = (const unsigned int*)(voxT + bidx);
        uint4 r; r.x = vp[0]; r.y = vp[1]; r.z = vp[2]; r.w = vp[3];
        return r;
    };

    uint4 Acur[6], Anxt[6];
    #pragma unroll
    for (int t = 0; t < 6; ++t) Acur[t] = Aptr[t * 64 + lane];
    uint4 Bcur = loadB(0), Bnxt;

    for (int s = 0; s < 54; ++s) {
        if (s < 53) {
            Bnxt = loadB(s + 1);
            #pragma unroll
            for (int t = 0; t < 6; ++t)
                Anxt[t] = Aptr[((s + 1) * 6 + t) * 64 + lane];
        }
        bf16x8 bf = __builtin_bit_cast(bf16x8, Bcur);
        #pragma unroll
        for (int t = 0; t < 6; ++t) {
            bf16x8 af = __builtin_bit_cast(bf16x8, Acur[t]);
            acc[t] = __builtin_amdgcn_mfma_f32_16x16x32_bf16(af, bf, acc[t], 0, 0, 0);
        }
        #pragma unroll
        for (int t = 0; t < 6; ++t) Acur[t] = Anxt[t];
        Bcur = Bnxt;
    }

    if (p < 63) {
        #pragma unroll
        for (int t = 0; t < 6; ++t) {
            #pragma unroll
            for (int r = 0; r < 4; ++r) {
                int o = t * 16 + quad * 4 + r;
                out[m * (96 * 63) + o * 63 + p] = fmaxf(acc[t][r] + b1[o], 0.0f);
            }
        }
    }
}

// ---------------------------------------------------------------- conv2
__global__ __launch_bounds__(256) void k_conv2(
    const float* __restrict__ c1, const float* __restrict__ w2t,
    const float* __restrict__ b2, float* __restrict__ out)
{
    const int tid = threadIdx.x;
    const int mm = tid >> 7, o = tid & 127;
    const int m0 = blockIdx.x * 2;
    __shared__ float inb[2][96 * 63];
    for (int idx = tid; idx < 2 * 96 * 63; idx += 256)
        inb[idx / (96 * 63)][idx % (96 * 63)] = c1[m0 * (96 * 63) + idx];
    __syncthreads();

    float acc[5] = {0, 0, 0, 0, 0};
    for (int c = 0; c < 96; ++c) {
        #pragma unroll
        for (int tap = 0; tap < 27; ++tap) {
            const int dz = tap / 9, r9 = tap % 9;
            float w = w2t[(c * 27 + tap) * 128 + o];
            #pragma unroll
            for (int zo = 0; zo < 5; ++zo)
                acc[zo] = fmaf(w, inb[mm][c * 63 + (zo + dz) * 9 + r9], acc[zo]);
        }
    }
    float bias = b2[o];
    #pragma unroll
    for (int zo = 0; zo < 5; ++zo)
        out[(m0 + mm) * (128 * 5) + o * 5 + zo] = fmaxf(acc[zo] + bias, 0.0f);
}

// ---------------------------------------------------------------- conv3
__global__ __launch_bounds__(256) void k_conv3(
    const float* __restrict__ c2, const float* __restrict__ w3t,
    const float* __restrict__ b3, float* __restrict__ vv)
{
    const int tid = threadIdx.x;
    const int mm = tid >> 6, u = tid & 63;
    const int m0 = blockIdx.x * 4;
    __shared__ float inb[4][640];
    for (int idx = tid; idx < 4 * 640; idx += 256)
        inb[idx / 640][idx % 640] = c2[m0 * 640 + idx];
    __syncthreads();
    float acc = b3[u];
    for (int k = 0; k < 640; ++k)
        acc = fmaf(inb[mm][k], w3t[k * 64 + u], acc);
    vv[(m0 + mm) * 64 + u] = acc;
}

// ---------------------------------------------------------------- x @ Wi + b
__global__ __launch_bounds__(256) void k_xwi(
    const float* __restrict__ vv, const float* __restrict__ wi,
    const float* __restrict__ lb, float* __restrict__ xwi)
{
    const int m = blockIdx.x;
    const int j = threadIdx.x;
    float acc = lb[j];
    #pragma unroll
    for (int k = 0; k < 64; ++k)
        acc = fmaf(vv[m * 64 + k], wi[k * 256 + j], acc);
    xwi[m * 256 + j] = acc;
}

// ---------------------------------------------------------------- LSTM
__global__ __launch_bounds__(256) void k_lstm(
    const float* __restrict__ xwi, const float* __restrict__ whg,
    const float* __restrict__ h0, const float* __restrict__ c0,
    float* __restrict__ avec, float* __restrict__ hn, float* __restrict__ cn)
{
    const int b = blockIdx.x;
    const int j = threadIdx.x;
    __shared__ float hbuf[64];
    __shared__ float gbuf[256];

    float wh[64];
    #pragma unroll
    for (int k = 0; k < 64; ++k) wh[k] = whg[k * 256 + j];

    if (j < 64) hbuf[j] = h0[b * 64 + j];
    float c = (j < 64) ? c0[b * 64 + j] : 0.0f;
    __syncthreads();

    for (int t = 0; t < 64; ++t) {
        float g = xwi[(b * 64 + t) * 256 + j];
        #pragma unroll
        for (int k = 0; k < 64; ++k) g = fmaf(hbuf[k], wh[k], g);
        gbuf[j] = g;
        __syncthreads();
        if (j < 64) {
            float gi = gbuf[j], gf = gbuf[64 + j], gg = gbuf[128 + j], go = gbuf[192 + j];
            c = sigm(gf) * c + sigm(gi) * tanhf(gg);
            float h = sigm(go) * tanhf(c);
            hbuf[j] = h;
            avec[(b * 64 + t) * 64 + j] = h;
        }
        __syncthreads();
    }
    if (j < 64) {
        hn[b * 64 + j] = hbuf[j];
        cn[b * 64 + j] = c;
    }
}

// ---------------------------------------------------------------- launch
extern "C" void kernel_launch(void* const* d_in, const int* in_sizes, int n_in,
                              void* d_out, int out_size, void* d_ws, size_t ws_size,
                              hipStream_t stream) {
    const float* x     = (const float*)d_in[0];
    const float* g_loc = (const float*)d_in[1];
    const float* h0    = (const float*)d_in[2];
    const float* c0    = (const float*)d_in[3];
    const float* pn_w1 = (const float*)d_in[4];
    const float* pn_b1 = (const float*)d_in[5];
    const float* pn_w2 = (const float*)d_in[6];
    const float* pn_b2 = (const float*)d_in[7];
    const float* pn_w3 = (const float*)d_in[8];
    const float* pn_b3 = (const float*)d_in[9];
    const float* aw    = (const float*)d_in[10];
    const float* ab    = (const float*)d_in[11];
    const float* vx_w1 = (const float*)d_in[12];
    const float* vx_b1 = (const float*)d_in[13];
    const float* vx_w2 = (const float*)d_in[14];
    const float* vx_b2 = (const float*)d_in[15];
    const float* vx_w3 = (const float*)d_in[16];
    const float* vx_b3 = (const float*)d_in[17];
    const float* lwi   = (const float*)d_in[18];
    const float* lwh   = (const float*)d_in[19];
    const float* lb    = (const float*)d_in[20];

    float* ws  = (float*)d_ws;
    float* vox = ws;
    float* c1  = vox + SZ_VOX;
    float* c2  = c1 + SZ_C1;
    float* vv  = c2 + SZ_C2;
    float* xwi = vv + SZ_VV;
    float* w1r = xwi + SZ_XWI;            // region reserved SZ_W1T floats
    float* w2t = w1r + SZ_W1T;
    float* w3t = w2t + SZ_W2T;
    unsigned short* w1m = (unsigned short*)w1r;
    unsigned short* w3m = (unsigned short*)xwi;  // aliases xwi head; xwi written later
    int*   idxb = (int*)c1;               // idx lives in the (not-yet-written) c1 region

    float* out   = (float*)d_out;
    float* avec  = out;                   // 65536
    float* attnw = out + 65536;           // 1843200
    float* hn    = out + 65536 + 1843200; // 1024
    float* cn    = hn + 1024;             // 1024

    k_transpose<<<1538, 256, 0, stream>>>(vx_w1, vx_w2, vx_w3, pn_w3,
                                          w1m, w2t, w3t, w3m);
    k_group<<<1024, 256, 0, stream>>>(x, g_loc, idxb);
    k_mlpm<<<14400, 128, 0, stream>>>(x, g_loc, idxb, pn_w1, pn_b1, pn_w2, pn_b2,
                                      w3m, pn_b3, aw, ab, vox, attnw);
    k_conv1m<<<1024, 256, 0, stream>>>(vox, w1m, vx_b1, c1);
    k_conv2<<<512, 256, 0, stream>>>(c1, w2t, vx_b2, c2);
    k_conv3<<<256, 256, 0, stream>>>(c2, w3t, vx_b3, vv);
    k_xwi<<<1024, 256, 0, stream>>>(vv, lwi, lb, xwi);
    k_lstm<<<16, 256, 0, stream>>>(xwi, lwh, h0, c0, avec, hn, cn);
}

// Round 5
// 530.526 us; speedup vs baseline: 1.6119x; 1.6119x over previous
//
#include <hip/hip_runtime.h>
#include <cmath>

// Shapes (fixed by the problem)
#define AT 225      // Z*Y*X anchors
#define NP 128      // points per sample
#define MT 1024     // B*T
#define NSEL 8
#define HD 64

// workspace float offsets
#define SZ_VOX  (1024u*64u*225u)      // 14,745,600  vox[m][h][a]
#define SZ_C1   (1024u*96u*63u)      // 6,193,152   c1[m][o][p]  (idx aliases this before conv1)
#define SZ_C2   (1024u*128u*5u)      // 655,360     c2[m][o][zo]
#define SZ_VV   (1024u*64u)          // 65,536
#define SZ_XWI  (1024u*256u)         // 262,144  (w3m aliases its head before k_xwi runs)
#define SZ_W1T  (64u*27u*96u)        // 165,888 floats reserved; holds w1m (165,888 bf16)
#define SZ_W2T  (96u*27u*128u)       // 331,776
#define SZ_W3T  (640u*64u)           // 40,960

typedef __attribute__((ext_vector_type(8))) short bf16x8;
typedef __attribute__((ext_vector_type(4))) float f32x4;

__device__ __forceinline__ float sigm(float x) { return 1.0f / (1.0f + expf(-x)); }

__device__ __forceinline__ unsigned short f2bf(float f) {
    unsigned u = __float_as_uint(f);
    unsigned r = u + 0x7FFF + ((u >> 16) & 1);   // RNE
    return (unsigned short)(r >> 16);
}
__device__ __forceinline__ float bf2f(unsigned short s) {
    return __uint_as_float(((unsigned)s) << 16);
}

// ---------------------------------------------------------------- transpose
// w1m: conv1 MFMA A-frag pre-swizzle (see round 2).
// w2t[(c*27+tap)*128+o] = w2[o][c][tap]   (128,96,27)
// w3t[k*64+u]           = w3[u][k]        (64,640)
// w3m: pn_w3 B-frag pre-swizzle: entry(nt,lane,j) = bf16(pn_w3[k][n]),
//      n = nt*16+(lane&15), k = (lane>>4)*8+j;  linear = (nt*64+lane)*8+j
__global__ __launch_bounds__(256) void k_transpose(
    const float* __restrict__ w1, const float* __restrict__ w2,
    const float* __restrict__ w3, const float* __restrict__ pnw3,
    unsigned short* __restrict__ w1m, float* __restrict__ w2t,
    float* __restrict__ w3t, unsigned short* __restrict__ w3m)
{
    int idx = blockIdx.x * 256 + threadIdx.x;
    if (idx < 20736) {
        int lane = idx & 63, r = idx >> 6;
        int t = r % 6, s = r / 6;
        int o = t * 16 + (lane & 15);
        int kb = s * 32 + (lane >> 4) * 8;
        unsigned int dw[4];
        #pragma unroll
        for (int jd = 0; jd < 4; ++jd) {
            int k0 = kb + 2 * jd, k1 = k0 + 1;
            int tap0 = k0 >> 6, c0 = k0 & 63;
            int tap1 = k1 >> 6, c1 = k1 & 63;
            unsigned short lo = f2bf(w1[o * 1728 + c0 * 27 + tap0]);
            unsigned short hi = f2bf(w1[o * 1728 + c1 * 27 + tap1]);
            dw[jd] = (unsigned)lo | ((unsigned)hi << 16);
        }
        uint4 v; v.x = dw[0]; v.y = dw[1]; v.z = dw[2]; v.w = dw[3];
        ((uint4*)w1m)[idx] = v;
    } else if (idx < (int)(20736 + SZ_W2T)) {
        int k = idx - 20736;
        int o = k % 128, r = k / 128;
        w2t[k] = w2[o * 2592 + r];
    } else if (idx < (int)(20736 + SZ_W2T + SZ_W3T)) {
        int k = idx - (20736 + SZ_W2T);
        int u = k & 63, r = k >> 6;
        w3t[k] = w3[u * 640 + r];
    } else if (idx < (int)(20736 + SZ_W2T + SZ_W3T + 256)) {
        int k = idx - (20736 + SZ_W2T + SZ_W3T);
        int lane = k & 63, nt = k >> 6;
        int n = nt * 16 + (lane & 15);
        int kb = (lane >> 4) * 8;
        unsigned int dw[4];
        #pragma unroll
        for (int jd = 0; jd < 4; ++jd) {
            int k0 = kb + 2 * jd;
            unsigned short lo = f2bf(pnw3[k0 * 64 + n]);
            unsigned short hi = f2bf(pnw3[(k0 + 1) * 64 + n]);
            dw[jd] = (unsigned)lo | ((unsigned)hi << 16);
        }
        uint4 v; v.x = dw[0]; v.y = dw[1]; v.z = dw[2]; v.w = dw[3];
        ((uint4*)w3m)[k] = v;
    }
}

// ---------------------------------------------------------------- grouping
__global__ __launch_bounds__(256) void k_group(
    const float* __restrict__ x, const float* __restrict__ g_loc,
    int* __restrict__ idxbuf)
{
    const int m = blockIdx.x;
    const int tid = threadIdx.x;
    __shared__ float pts[3][NP];

    for (int idx = tid; idx < NP * 5; idx += 256) {
        int n = idx / 5, c = idx % 5;
        if (c < 3) pts[c][n] = x[m * (NP * 5) + idx];
    }
    __syncthreads();

    const float gx = g_loc[m * 2 + 0], gy = g_loc[m * 2 + 1];
    const int grp = tid >> 3, li = tid & 7;

    for (int ca = 0; ca < 256; ca += 32) {
        const int a = ca + grp;
        const bool active = (a < AT);
        const int aa = active ? a : (AT - 1);
        const int azi = aa / 25, ar = aa % 25, ayi = ar / 5, axi = ar % 5;
        const float fx = ((float)axi - 2.0f) * 0.2f + gx;
        const float fy = ((float)ayi - 2.0f) * 0.2f + gy;
        const float fz = (float)azi * 0.22f + 0.1f;
        const float sa = fx * fx + fy * fy + fz * fz;

        float d[16];
        #pragma unroll
        for (int r = 0; r < 16; ++r) {
            int n = li * 16 + r;
            float px = pts[0][n], py = pts[1][n], pz = pts[2][n];
            d[r] = sa - 2.0f * (fx * px + fy * py + fz * pz)
                      + (px * px + py * py + pz * pz);
        }
        int nidx = 0;
        for (int j = 0; j < NSEL; ++j) {
            float best = 1e30f; int bidx = 0;
            #pragma unroll
            for (int r = 0; r < 16; ++r) {
                int n = li * 16 + r;
                if (d[r] < best) { best = d[r]; bidx = n; }
            }
            #pragma unroll
            for (int off = 1; off < 8; off <<= 1) {
                float ov = __shfl_xor(best, off);
                int   oi = __shfl_xor(bidx, off);
                if (ov < best || (ov == best && oi < bidx)) { best = ov; bidx = oi; }
            }
            if (li == j) nidx = bidx;
            if ((bidx >> 4) == li) {
                int slot = bidx & 15;
                #pragma unroll
                for (int r = 0; r < 16; ++r)
                    if (r == slot) d[r] = 1e30f;
            }
        }
        if (active) idxbuf[(m * AT + a) * NSEL + li] = nidx;
    }
}

// ---------------------------------------------------------------- MLP (MFMA + LDS epilogue)
// 128 threads = 2 waves = 128 rows. Layers 1-2 per-thread f32; f2 -> LDS bf16
// (stride 17 dw); layer 3 = 16x mfma_f32_16x16x32_bf16 per wave; f3 (relu+bias
// folded) -> LDS bf16 [row][h] stride 66 us (33 dw == 1 mod 32: conflict-free
// row reads); then R3-style cheap per-thread score/softmax/weighted-sum.
__global__ __launch_bounds__(128) void k_mlpm(
    const float* __restrict__ x, const float* __restrict__ g_loc,
    const int* __restrict__ idxbuf,
    const float* __restrict__ w1, const float* __restrict__ b1,
    const float* __restrict__ w2, const float* __restrict__ b2,
    const unsigned short* __restrict__ w3m, const float* __restrict__ b3,
    const float* __restrict__ aw, const float* __restrict__ ab,
    float* __restrict__ vox, float* __restrict__ attn_out)
{
    const int tid = threadIdx.x;
    const int row0 = blockIdx.x * 128;
    const int row = row0 + tid;

    __shared__ float pts[2][5][NP];           // 5120 B
    __shared__ unsigned int f2frag[128 * 17]; // 8704 B (bf16 pairs)
    __shared__ unsigned short f3us[128 * 66]; // 16896 B (bf16, stride 66)
    __shared__ float sbuf[16 * 65];           // 4160 B  -> total 34880 B

    const int m0 = row0 / 1800;
    const int m1 = (row0 + 127) / 1800;
    #pragma unroll
    for (int mm = 0; mm < 2; ++mm) {
        int mload = (mm == 0) ? m0 : m1;
        for (int i = tid; i < NP * 5; i += 128) {
            int n = i / 5, c = i % 5;
            pts[mm][c][n] = x[mload * (NP * 5) + i];
        }
    }
    __syncthreads();

    // ---- phase A: layers 1-2, per-thread ----
    const int m = row / 1800;
    const int rr = row % 1800;
    const int a = rr >> 3;
    const int sel = (m == m0) ? 0 : 1;

    const int azi = a / 25, ar = a % 25, ayi = ar / 5, axi = ar % 5;
    const float gx = g_loc[m * 2 + 0], gy = g_loc[m * 2 + 1];
    const float fx = ((float)axi - 2.0f) * 0.2f + gx;
    const float fy = ((float)ayi - 2.0f) * 0.2f + gy;
    const float fz = (float)azi * 0.22f + 0.1f;

    const int nidx = idxbuf[row];
    const float in0 = pts[sel][0][nidx] - fx;
    const float in1 = pts[sel][1][nidx] - fy;
    const float in2 = pts[sel][2][nidx] - fz;
    const float in3 = pts[sel][3][nidx];
    const float in4 = pts[sel][4][nidx];

    float f1v[16];
    #pragma unroll
    for (int j = 0; j < 16; ++j) {
        float s = b1[j];
        s += in0 * w1[0 * 16 + j] + in1 * w1[1 * 16 + j] + in2 * w1[2 * 16 + j]
           + in3 * w1[3 * 16 + j] + in4 * w1[4 * 16 + j];
        f1v[j] = fmaxf(s, 0.0f);
    }
    float f2v[32];
    #pragma unroll
    for (int j = 0; j < 32; ++j) {
        float s = b2[j];
        #pragma unroll
        for (int i = 0; i < 16; ++i) s += f1v[i] * w2[i * 32 + j];
        f2v[j] = fmaxf(s, 0.0f);
    }
    #pragma unroll
    for (int kd = 0; kd < 16; ++kd) {
        unsigned dw = (unsigned)f2bf(f2v[2 * kd]) |
                      ((unsigned)f2bf(f2v[2 * kd + 1]) << 16);
        f2frag[tid * 17 + kd] = dw;
    }
    __syncthreads();

    // ---- phase B: MFMA layer 3, relu+bias, store f3 to LDS (bf16) ----
    const int wv = tid >> 6, lane = tid & 63;
    const int quad = lane >> 4, mcol = lane & 15;

    bf16x8 w3f[4];
    #pragma unroll
    for (int nt = 0; nt < 4; ++nt) {
        uint4 u = ((const uint4*)w3m)[nt * 64 + lane];
        w3f[nt] = __builtin_bit_cast(bf16x8, u);
    }
    float b3v[4];
    #pragma unroll
    for (int nt = 0; nt < 4; ++nt) b3v[nt] = b3[nt * 16 + mcol];

    #pragma unroll
    for (int mt = 0; mt < 4; ++mt) {
        const int rowbase = (wv * 4 + mt) * 16;
        const int abase = (rowbase + mcol) * 17 + quad * 4;
        uint4 au;
        au.x = f2frag[abase + 0]; au.y = f2frag[abase + 1];
        au.z = f2frag[abase + 2]; au.w = f2frag[abase + 3];
        bf16x8 af = __builtin_bit_cast(bf16x8, au);

        #pragma unroll
        for (int nt = 0; nt < 4; ++nt) {
            f32x4 z = (f32x4){0.f, 0.f, 0.f, 0.f};
            f32x4 acc = __builtin_amdgcn_mfma_f32_16x16x32_bf16(af, w3f[nt], z, 0, 0, 0);
            #pragma unroll
            for (int reg = 0; reg < 4; ++reg) {
                float v = fmaxf(acc[reg] + b3v[nt], 0.0f);
                f3us[(rowbase + quad * 4 + reg) * 66 + nt * 16 + mcol] = f2bf(v);
            }
        }
    }
    __syncthreads();

    // ---- phase C: score, softmax, weighted sum (R3-style) ----
    const unsigned int* f3dw = (const unsigned int*)f3us;   // row stride 33 dw
    float s0 = 0.f, s1 = 0.f;
    #pragma unroll
    for (int kd = 0; kd < 32; ++kd) {
        unsigned dw = f3dw[tid * 33 + kd];
        s0 = fmaf(__uint_as_float(dw << 16), aw[2 * kd], s0);
        s1 = fmaf(__uint_as_float(dw & 0xFFFF0000u), aw[2 * kd + 1], s1);
    }
    float sc = s0 + s1 + ab[0];

    float mx = sc;
    #pragma unroll
    for (int off = 1; off < 8; off <<= 1) mx = fmaxf(mx, __shfl_xor(mx, off));
    float e = expf(sc - mx);
    float den = e;
    #pragma unroll
    for (int off = 1; off < 8; off <<= 1) den += __shfl_xor(den, off);
    const float at = e / den;
    attn_out[row] = at;

    const int lgrp = tid >> 3;
    const int li = tid & 7;
    const int wl = tid & 63;
    float o[8];
    #pragma unroll
    for (int hh = 0; hh < 8; ++hh) o[hh] = 0.0f;
    #pragma unroll
    for (int ns = 0; ns < 8; ++ns) {
        float atn = __shfl(at, (wl >> 3) * 8 + ns);
        const int frow = lgrp * 8 + ns;
        #pragma unroll
        for (int hh = 0; hh < 8; ++hh)
            o[hh] = fmaf(atn, bf2f(f3us[frow * 66 + hh * 8 + li]), o[hh]);
    }
    #pragma unroll
    for (int hh = 0; hh < 8; ++hh)
        sbuf[lgrp * 65 + hh * 8 + li] = o[hh];
    __syncthreads();

    const int al = tid & 15, j = tid >> 4;
    const int ga = (row0 >> 3) + al;
    const int ma = ga / 225, aa2 = ga % 225;
    #pragma unroll
    for (int rep = 0; rep < 8; ++rep) {
        int h = j * 8 + rep;
        vox[(ma * 64 + h) * AT + aa2] = sbuf[al * 65 + h];
    }
}

// ---------------------------------------------------------------- conv1 MFMA
__global__ __launch_bounds__(256) void k_conv1m(
    const float* __restrict__ vox, const unsigned short* __restrict__ w1m,
    const float* __restrict__ b1, float* __restrict__ out)
{
    const int m = blockIdx.x;
    const int tid = threadIdx.x;
    __shared__ unsigned short voxT[225 * 66];

    for (int i = tid; i < 64 * 225; i += 256) {
        int c = i / 225, a = i - c * 225;
        voxT[a * 66 + c] = f2bf(vox[m * (64 * 225) + i]);
    }
    __syncthreads();

    const int wv = tid >> 6, lane = tid & 63;
    const int quad = lane >> 4, n = lane & 15;
    const int p = wv * 16 + n;
    const int pe = (p > 62) ? 62 : p;
    const int zo = pe / 9, pr = pe % 9, yo = pr / 3, xo = pr % 3;
    const int basep = zo * 25 + yo * 5 + xo;

    f32x4 acc[6];
    #pragma unroll
    for (int t = 0; t < 6; ++t) acc[t] = (f32x4){0.f, 0.f, 0.f, 0.f};

    const uint4* Aptr = (const uint4*)w1m;

    auto loadB = [&](int s) -> uint4 {
        int tap = s >> 1;
        int dz = tap / 9, tr = tap % 9, dy = tr / 3, dx = tr % 3;
        int row = basep + dz * 25 + dy * 5 + dx;
        int bidx = row * 66 + (s & 1) * 32 + quad * 8;
        const unsigned int* vp = (const unsigned int*)(voxT + bidx);
        uint4 r; r.x = vp[0]; r.y = vp[1]; r.z = vp[2]; r.w = vp[3];
        return r;
    };

    uint4 Acur[6], Anxt[6];
    #pragma unroll
    for (int t = 0; t < 6; ++t) Acur[t] = Aptr[t * 64 + lane];
    uint4 Bcur = loadB(0), Bnxt;

    for (int s = 0; s < 54; ++s) {
        if (s < 53) {
            Bnxt = loadB(s + 1);
            #pragma unroll
            for (int t = 0; t < 6; ++t)
                Anxt[t] = Aptr[((s + 1) * 6 + t) * 64 + lane];
        }
        bf16x8 bf = __builtin_bit_cast(bf16x8, Bcur);
        #pragma unroll
        for (int t = 0; t < 6; ++t) {
            bf16x8 af = __builtin_bit_cast(bf16x8, Acur[t]);
            acc[t] = __builtin_amdgcn_mfma_f32_16x16x32_bf16(af, bf, acc[t], 0, 0, 0);
        }
        #pragma unroll
        for (int t = 0; t < 6; ++t) Acur[t] = Anxt[t];
        Bcur = Bnxt;
    }

    if (p < 63) {
        #pragma unroll
        for (int t = 0; t < 6; ++t) {
            #pragma unroll
            for (int r = 0; r < 4; ++r) {
                int o = t * 16 + quad * 4 + r;
                out[m * (96 * 63) + o * 63 + p] = fmaxf(acc[t][r] + b1[o], 0.0f);
            }
        }
    }
}

// ---------------------------------------------------------------- conv2
__global__ __launch_bounds__(256) void k_conv2(
    const float* __restrict__ c1, const float* __restrict__ w2t,
    const float* __restrict__ b2, float* __restrict__ out)
{
    const int tid = threadIdx.x;
    const int mm = tid >> 7, o = tid & 127;
    const int m0 = blockIdx.x * 2;
    __shared__ float inb[2][96 * 63];
    for (int idx = tid; idx < 2 * 96 * 63; idx += 256)
        inb[idx / (96 * 63)][idx % (96 * 63)] = c1[m0 * (96 * 63) + idx];
    __syncthreads();

    float acc[5] = {0, 0, 0, 0, 0};
    for (int c = 0; c < 96; ++c) {
        #pragma unroll
        for (int tap = 0; tap < 27; ++tap) {
            const int dz = tap / 9, r9 = tap % 9;
            float w = w2t[(c * 27 + tap) * 128 + o];
            #pragma unroll
            for (int zo = 0; zo < 5; ++zo)
                acc[zo] = fmaf(w, inb[mm][c * 63 + (zo + dz) * 9 + r9], acc[zo]);
        }
    }
    float bias = b2[o];
    #pragma unroll
    for (int zo = 0; zo < 5; ++zo)
        out[(m0 + mm) * (128 * 5) + o * 5 + zo] = fmaxf(acc[zo] + bias, 0.0f);
}

// ---------------------------------------------------------------- conv3
__global__ __launch_bounds__(256) void k_conv3(
    const float* __restrict__ c2, const float* __restrict__ w3t,
    const float* __restrict__ b3, float* __restrict__ vv)
{
    const int tid = threadIdx.x;
    const int mm = tid >> 6, u = tid & 63;
    const int m0 = blockIdx.x * 4;
    __shared__ float inb[4][640];
    for (int idx = tid; idx < 4 * 640; idx += 256)
        inb[idx / 640][idx % 640] = c2[m0 * 640 + idx];
    __syncthreads();
    float acc = b3[u];
    for (int k = 0; k < 640; ++k)
        acc = fmaf(inb[mm][k], w3t[k * 64 + u], acc);
    vv[(m0 + mm) * 64 + u] = acc;
}

// ---------------------------------------------------------------- x @ Wi + b
__global__ __launch_bounds__(256) void k_xwi(
    const float* __restrict__ vv, const float* __restrict__ wi,
    const float* __restrict__ lb, float* __restrict__ xwi)
{
    const int m = blockIdx.x;
    const int j = threadIdx.x;
    float acc = lb[j];
    #pragma unroll
    for (int k = 0; k < 64; ++k)
        acc = fmaf(vv[m * 64 + k], wi[k * 256 + j], acc);
    xwi[m * 256 + j] = acc;
}

// ---------------------------------------------------------------- LSTM
__global__ __launch_bounds__(256) void k_lstm(
    const float* __restrict__ xwi, const float* __restrict__ whg,
    const float* __restrict__ h0, const float* __restrict__ c0,
    float* __restrict__ avec, float* __restrict__ hn, float* __restrict__ cn)
{
    const int b = blockIdx.x;
    const int j = threadIdx.x;
    __shared__ float hbuf[64];
    __shared__ float gbuf[256];

    float wh[64];
    #pragma unroll
    for (int k = 0; k < 64; ++k) wh[k] = whg[k * 256 + j];

    if (j < 64) hbuf[j] = h0[b * 64 + j];
    float c = (j < 64) ? c0[b * 64 + j] : 0.0f;
    __syncthreads();

    for (int t = 0; t < 64; ++t) {
        float g = xwi[(b * 64 + t) * 256 + j];
        #pragma unroll
        for (int k = 0; k < 64; ++k) g = fmaf(hbuf[k], wh[k], g);
        gbuf[j] = g;
        __syncthreads();
        if (j < 64) {
            float gi = gbuf[j], gf = gbuf[64 + j], gg = gbuf[128 + j], go = gbuf[192 + j];
            c = sigm(gf) * c + sigm(gi) * tanhf(gg);
            float h = sigm(go) * tanhf(c);
            hbuf[j] = h;
            avec[(b * 64 + t) * 64 + j] = h;
        }
        __syncthreads();
    }
    if (j < 64) {
        hn[b * 64 + j] = hbuf[j];
        cn[b * 64 + j] = c;
    }
}

// ---------------------------------------------------------------- launch
extern "C" void kernel_launch(void* const* d_in, const int* in_sizes, int n_in,
                              void* d_out, int out_size, void* d_ws, size_t ws_size,
                              hipStream_t stream) {
    const float* x     = (const float*)d_in[0];
    const float* g_loc = (const float*)d_in[1];
    const float* h0    = (const float*)d_in[2];
    const float* c0    = (const float*)d_in[3];
    const float* pn_w1 = (const float*)d_in[4];
    const float* pn_b1 = (const float*)d_in[5];
    const float* pn_w2 = (const float*)d_in[6];
    const float* pn_b2 = (const float*)d_in[7];
    const float* pn_w3 = (const float*)d_in[8];
    const float* pn_b3 = (const float*)d_in[9];
    const float* aw    = (const float*)d_in[10];
    const float* ab    = (const float*)d_in[11];
    const float* vx_w1 = (const float*)d_in[12];
    const float* vx_b1 = (const float*)d_in[13];
    const float* vx_w2 = (const float*)d_in[14];
    const float* vx_b2 = (const float*)d_in[15];
    const float* vx_w3 = (const float*)d_in[16];
    const float* vx_b3 = (const float*)d_in[17];
    const float* lwi   = (const float*)d_in[18];
    const float* lwh   = (const float*)d_in[19];
    const float* lb    = (const float*)d_in[20];

    float* ws  = (float*)d_ws;
    float* vox = ws;
    float* c1  = vox + SZ_VOX;
    float* c2  = c1 + SZ_C1;
    float* vv  = c2 + SZ_C2;
    float* xwi = vv + SZ_VV;
    float* w1r = xwi + SZ_XWI;            // region reserved SZ_W1T floats
    float* w2t = w1r + SZ_W1T;
    float* w3t = w2t + SZ_W2T;
    unsigned short* w1m = (unsigned short*)w1r;
    unsigned short* w3m = (unsigned short*)xwi;  // aliases xwi head; xwi written later
    int*   idxb = (int*)c1;               // idx lives in the (not-yet-written) c1 region

    float* out   = (float*)d_out;
    float* avec  = out;                   // 65536
    float* attnw = out + 65536;           // 1843200
    float* hn    = out + 65536 + 1843200; // 1024
    float* cn    = hn + 1024;             // 1024

    k_transpose<<<1538, 256, 0, stream>>>(vx_w1, vx_w2, vx_w3, pn_w3,
                                          w1m, w2t, w3t, w3m);
    k_group<<<1024, 256, 0, stream>>>(x, g_loc, idxb);
    k_mlpm<<<14400, 128, 0, stream>>>(x, g_loc, idxb, pn_w1, pn_b1, pn_w2, pn_b2,
                                      w3m, pn_b3, aw, ab, vox, attnw);
    k_conv1m<<<1024, 256, 0, stream>>>(vox, w1m, vx_b1, c1);
    k_conv2<<<512, 256, 0, stream>>>(c1, w2t, vx_b2, c2);
    k_conv3<<<256, 256, 0, stream>>>(c2, w3t, vx_b3, vv);
    k_xwi<<<1024, 256, 0, stream>>>(vv, lwi, lb, xwi);
    k_lstm<<<16, 256, 0, stream>>>(xwi, lwh, h0, c0, avec, hn, cn);
}

// Round 7
// 454.223 us; speedup vs baseline: 1.8827x; 1.1680x over previous
//
#include <hip/hip_runtime.h>
#include <cmath>

// Shapes (fixed by the problem)
#define AT 225      // Z*Y*X anchors
#define NP 128      // points per sample
#define MT 1024     // B*T
#define NSEL 8
#define HD 64

// workspace float offsets
#define SZ_VOX  (1024u*64u*225u)
#define SZ_C1   (1024u*96u*63u)      // c1[m][o][p]  (idx aliases this before conv1)
#define SZ_C2   (1024u*128u*5u)
#define SZ_VV   (1024u*64u)
#define SZ_XWI  (1024u*256u)         // (w3m aliases its head before k_c3x runs)
#define SZ_W1T  (64u*27u*96u)        // holds w1m (bf16 A-frags, conv1)
#define SZ_W2T  (96u*27u*128u)       // holds w2n (bf16 B-frags, conv2)
#define SZ_W3T  (640u*64u)
#define SZ_W2M  (512u)               // pn layer2 B-frags (128 uint4)

#define C2S 98                       // conv2 LDS row stride (us), 49 dw (odd)

typedef __attribute__((ext_vector_type(8))) short bf16x8;
typedef __attribute__((ext_vector_type(4))) float f32x4;

__device__ __forceinline__ float sigm(float x) { return 1.0f / (1.0f + expf(-x)); }

__device__ __forceinline__ unsigned short f2bf(float f) {
    unsigned u = __float_as_uint(f);
    unsigned r = u + 0x7FFF + ((u >> 16) & 1);   // RNE
    return (unsigned short)(r >> 16);
}
__device__ __forceinline__ unsigned pk2(float a, float b) {
    return (unsigned)f2bf(a) | ((unsigned)f2bf(b) << 16);
}

// ---------------------------------------------------------------- transpose
// w1m [0,20736) uint4          : conv1 A-frags (round-2 layout)
// w2n [20736,62208) uint4      : conv2 B-frags, k = tap*96+c
// w3t [62208,103168) floats    : w3t[k*64+u] = w3[u][k]
// w3m [103168,103424) uint4    : pn layer3 B-frags (round-3 layout)
// w2m [103424,103552) uint4    : pn layer2 B-frags, K padded 16->32 w/ zeros
__global__ __launch_bounds__(256) void k_transpose(
    const float* __restrict__ w1, const float* __restrict__ w2,
    const float* __restrict__ w3, const float* __restrict__ pnw3,
    const float* __restrict__ pnw2,
    unsigned short* __restrict__ w1m, unsigned short* __restrict__ w2n,
    float* __restrict__ w3t, unsigned short* __restrict__ w3m,
    unsigned short* __restrict__ w2m)
{
    int idx = blockIdx.x * 256 + threadIdx.x;
    if (idx < 20736) {
        int lane = idx & 63, r = idx >> 6;
        int t = r % 6, s = r / 6;
        int o = t * 16 + (lane & 15);
        int kb = s * 32 + (lane >> 4) * 8;
        unsigned int dw[4];
        #pragma unroll
        for (int jd = 0; jd < 4; ++jd) {
            int k0 = kb + 2 * jd, k1 = k0 + 1;
            dw[jd] = (unsigned)f2bf(w1[o * 1728 + (k0 & 63) * 27 + (k0 >> 6)]) |
                     ((unsigned)f2bf(w1[o * 1728 + (k1 & 63) * 27 + (k1 >> 6)]) << 16);
        }
        uint4 v; v.x = dw[0]; v.y = dw[1]; v.z = dw[2]; v.w = dw[3];
        ((uint4*)w1m)[idx] = v;
    } else if (idx < 62208) {
        int q = idx - 20736;
        int lane = q & 63, r = q >> 6;
        int nt = r & 7, s = r >> 3;
        int o = nt * 16 + (lane & 15);
        int kb = s * 32 + (lane >> 4) * 8;
        unsigned int dw[4];
        #pragma unroll
        for (int jd = 0; jd < 4; ++jd) {
            int k0 = kb + 2 * jd, k1 = k0 + 1;
            dw[jd] = (unsigned)f2bf(w2[o * 2592 + (k0 % 96) * 27 + (k0 / 96)]) |
                     ((unsigned)f2bf(w2[o * 2592 + (k1 % 96) * 27 + (k1 / 96)]) << 16);
        }
        uint4 v; v.x = dw[0]; v.y = dw[1]; v.z = dw[2]; v.w = dw[3];
        ((uint4*)w2n)[q] = v;
    } else if (idx < 103168) {
        int k = idx - 62208;
        int u = k & 63, r = k >> 6;
        w3t[k] = w3[u * 640 + r];
    } else if (idx < 103424) {
        int k = idx - 103168;
        int lane = k & 63, nt = k >> 6;
        int n = nt * 16 + (lane & 15);
        int kb = (lane >> 4) * 8;
        unsigned int dw[4];
        #pragma unroll
        for (int jd = 0; jd < 4; ++jd) {
            int k0 = kb + 2 * jd;
            dw[jd] = (unsigned)f2bf(pnw3[k0 * 64 + n]) |
                     ((unsigned)f2bf(pnw3[(k0 + 1) * 64 + n]) << 16);
        }
        uint4 v; v.x = dw[0]; v.y = dw[1]; v.z = dw[2]; v.w = dw[3];
        ((uint4*)w3m)[k] = v;
    } else if (idx < 103552) {
        int k = idx - 103424;
        int lane = k & 63, nt = k >> 6;          // nt 0..1
        int n = nt * 16 + (lane & 15);
        int kb = (lane >> 4) * 8;
        unsigned int dw[4];
        #pragma unroll
        for (int jd = 0; jd < 4; ++jd) {
            int k0 = kb + 2 * jd, k1 = k0 + 1;
            float a = (k0 < 16) ? pnw2[k0 * 32 + n] : 0.0f;
            float b = (k1 < 16) ? pnw2[k1 * 32 + n] : 0.0f;
            dw[jd] = pk2(a, b);
        }
        uint4 v; v.x = dw[0]; v.y = dw[1]; v.z = dw[2]; v.w = dw[3];
        ((uint4*)w2m)[k] = v;
    }
}

// ---------------------------------------------------------------- grouping
__global__ __launch_bounds__(256) void k_group(
    const float* __restrict__ x, const float* __restrict__ g_loc,
    int* __restrict__ idxbuf)
{
    const int m = blockIdx.x;
    const int tid = threadIdx.x;
    __shared__ float pts[3][NP];

    for (int idx = tid; idx < NP * 5; idx += 256) {
        int n = idx / 5, c = idx % 5;
        if (c < 3) pts[c][n] = x[m * (NP * 5) + idx];
    }
    __syncthreads();

    const float gx = g_loc[m * 2 + 0], gy = g_loc[m * 2 + 1];
    const int grp = tid >> 3, li = tid & 7;

    for (int ca = 0; ca < 256; ca += 32) {
        const int a = ca + grp;
        const bool active = (a < AT);
        const int aa = active ? a : (AT - 1);
        const int azi = aa / 25, ar = aa % 25, ayi = ar / 5, axi = ar % 5;
        const float fx = ((float)axi - 2.0f) * 0.2f + gx;
        const float fy = ((float)ayi - 2.0f) * 0.2f + gy;
        const float fz = (float)azi * 0.22f + 0.1f;
        const float sa = fx * fx + fy * fy + fz * fz;

        float d[16];
        #pragma unroll
        for (int r = 0; r < 16; ++r) {
            int n = li * 16 + r;
            float px = pts[0][n], py = pts[1][n], pz = pts[2][n];
            d[r] = sa - 2.0f * (fx * px + fy * py + fz * pz)
                      + (px * px + py * py + pz * pz);
        }
        int nidx = 0;
        for (int j = 0; j < NSEL; ++j) {
            float best = 1e30f; int bidx = 0;
            #pragma unroll
            for (int r = 0; r < 16; ++r) {
                int n = li * 16 + r;
                if (d[r] < best) { best = d[r]; bidx = n; }
            }
            #pragma unroll
            for (int off = 1; off < 8; off <<= 1) {
                float ov = __shfl_xor(best, off);
                int   oi = __shfl_xor(bidx, off);
                if (ov < best || (ov == best && oi < bidx)) { best = ov; bidx = oi; }
            }
            if (li == j) nidx = bidx;
            if ((bidx >> 4) == li) {
                int slot = bidx & 15;
                #pragma unroll
                for (int r = 0; r < 16; ++r)
                    if (r == slot) d[r] = 1e30f;
            }
        }
        if (active) idxbuf[(m * AT + a) * NSEL + li] = nidx;
    }
}

// ---------------------------------------------------------------- MLP (MFMA L2+L3)
// 128 thr = 2 waves = 128 rows. L1 per-thread; f1 (K-padded) -> fbuf; L2 via
// 8 MFMA overwriting fbuf; L3 via 16 MFMA -> f3us bf16; phase C: row-major
// score reads + conflict-free paired wsum reads (h = q*16+li*2+{0,1}).
// NOTE: fbuf/f3us are written via ushort* and read via uint* (type-punned
// LDS). __syncthreads() between write and read phases is REQUIRED — it is
// the only fence TBAA-driven scheduling cannot cross (R6 removed them and
// miscompiled: stale f1 read under the L3 loads).
__global__ __launch_bounds__(128) void k_mlpm(
    const float* __restrict__ x, const float* __restrict__ g_loc,
    const int* __restrict__ idxbuf,
    const float* __restrict__ w1, const float* __restrict__ b1,
    const unsigned short* __restrict__ w2m, const float* __restrict__ b2,
    const unsigned short* __restrict__ w3m, const float* __restrict__ b3,
    const float* __restrict__ aw, const float* __restrict__ ab,
    float* __restrict__ vox, float* __restrict__ attn_out)
{
    const int tid = threadIdx.x;
    const int row0 = blockIdx.x * 128;
    const int row = row0 + tid;

    __shared__ float pts[2][5][NP];           // 5120 B
    __shared__ unsigned int fbuf[128 * 17];   // 8704 B: f1 then f2 (bf16 pairs)
    __shared__ unsigned short f3us[128 * 66]; // 16896 B
    __shared__ float sbuf[16 * 65];           // 4160 B   => 34880 B total

    const int m0 = row0 / 1800;
    const int m1 = (row0 + 127) / 1800;
    #pragma unroll
    for (int mm = 0; mm < 2; ++mm) {
        int mload = (mm == 0) ? m0 : m1;
        for (int i = tid; i < NP * 5; i += 128) {
            int n = i / 5, c = i % 5;
            pts[mm][c][n] = x[mload * (NP * 5) + i];
        }
    }
    __syncthreads();

    // ---- phase A: layer 1 per-thread, pack f1 to fbuf (K 16..31 zeroed) ----
    const int m = row / 1800;
    const int rr = row % 1800;
    const int a = rr >> 3;
    const int sel = (m == m0) ? 0 : 1;

    const int azi = a / 25, ar = a % 25, ayi = ar / 5, axi = ar % 5;
    const float gx = g_loc[m * 2 + 0], gy = g_loc[m * 2 + 1];
    const float fx = ((float)axi - 2.0f) * 0.2f + gx;
    const float fy = ((float)ayi - 2.0f) * 0.2f + gy;
    const float fz = (float)azi * 0.22f + 0.1f;

    const int nidx = idxbuf[row];
    const float in0 = pts[sel][0][nidx] - fx;
    const float in1 = pts[sel][1][nidx] - fy;
    const float in2 = pts[sel][2][nidx] - fz;
    const float in3 = pts[sel][3][nidx];
    const float in4 = pts[sel][4][nidx];

    float f1v[16];
    #pragma unroll
    for (int j = 0; j < 16; ++j) {
        float s = b1[j];
        s += in0 * w1[0 * 16 + j] + in1 * w1[1 * 16 + j] + in2 * w1[2 * 16 + j]
           + in3 * w1[3 * 16 + j] + in4 * w1[4 * 16 + j];
        f1v[j] = fmaxf(s, 0.0f);
    }
    #pragma unroll
    for (int kd = 0; kd < 8; ++kd)
        fbuf[tid * 17 + kd] = pk2(f1v[2 * kd], f1v[2 * kd + 1]);
    #pragma unroll
    for (int kd = 8; kd < 16; ++kd)
        fbuf[tid * 17 + kd] = 0u;
    __syncthreads();

    // ---- phase B: MFMA layers ----
    const int wv = tid >> 6, lane = tid & 63;
    const int quad = lane >> 4, mcol = lane & 15;
    unsigned short* fus = (unsigned short*)fbuf;   // row stride 34 us

    // layer 2: D[128 rows][32] = f1 @ w2 (K=32 padded)
    bf16x8 w2f[2];
    #pragma unroll
    for (int nt = 0; nt < 2; ++nt) {
        uint4 u = ((const uint4*)w2m)[nt * 64 + lane];
        w2f[nt] = __builtin_bit_cast(bf16x8, u);
    }
    float b2v[2] = { b2[mcol], b2[16 + mcol] };

    #pragma unroll
    for (int mt = 0; mt < 4; ++mt) {
        const int rowbase = (wv * 4 + mt) * 16;
        const int abase = (rowbase + mcol) * 17 + quad * 4;
        uint4 au;
        au.x = fbuf[abase + 0]; au.y = fbuf[abase + 1];
        au.z = fbuf[abase + 2]; au.w = fbuf[abase + 3];
        bf16x8 af = __builtin_bit_cast(bf16x8, au);
        #pragma unroll
        for (int nt = 0; nt < 2; ++nt) {
            f32x4 z = (f32x4){0.f, 0.f, 0.f, 0.f};
            f32x4 acc = __builtin_amdgcn_mfma_f32_16x16x32_bf16(af, w2f[nt], z, 0, 0, 0);
            #pragma unroll
            for (int reg = 0; reg < 4; ++reg) {
                float v = fmaxf(acc[reg] + b2v[nt], 0.0f);
                fus[(rowbase + quad * 4 + reg) * 34 + nt * 16 + mcol] = f2bf(v);
            }
        }
    }
    __syncthreads();   // fence: ushort f2 stores -> uint A-frag loads (L3)

    // layer 3: D[128 rows][64] = f2 @ w3
    bf16x8 w3f[4];
    #pragma unroll
    for (int nt = 0; nt < 4; ++nt) {
        uint4 u = ((const uint4*)w3m)[nt * 64 + lane];
        w3f[nt] = __builtin_bit_cast(bf16x8, u);
    }
    float b3v[4];
    #pragma unroll
    for (int nt = 0; nt < 4; ++nt) b3v[nt] = b3[nt * 16 + mcol];

    #pragma unroll
    for (int mt = 0; mt < 4; ++mt) {
        const int rowbase = (wv * 4 + mt) * 16;
        const int abase = (rowbase + mcol) * 17 + quad * 4;
        uint4 au;
        au.x = fbuf[abase + 0]; au.y = fbuf[abase + 1];
        au.z = fbuf[abase + 2]; au.w = fbuf[abase + 3];
        bf16x8 af = __builtin_bit_cast(bf16x8, au);
        #pragma unroll
        for (int nt = 0; nt < 4; ++nt) {
            f32x4 z = (f32x4){0.f, 0.f, 0.f, 0.f};
            f32x4 acc = __builtin_amdgcn_mfma_f32_16x16x32_bf16(af, w3f[nt], z, 0, 0, 0);
            #pragma unroll
            for (int reg = 0; reg < 4; ++reg) {
                float v = fmaxf(acc[reg] + b3v[nt], 0.0f);
                f3us[(rowbase + quad * 4 + reg) * 66 + nt * 16 + mcol] = f2bf(v);
            }
        }
    }
    __syncthreads();   // fence: ushort f3 stores -> uint phase-C loads

    // ---- phase C: score, softmax, weighted sum ----
    const unsigned int* f3dw = (const unsigned int*)f3us;   // row stride 33 dw
    float s0 = 0.f, s1 = 0.f;
    #pragma unroll
    for (int kd = 0; kd < 32; ++kd) {
        unsigned dw = f3dw[tid * 33 + kd];
        s0 = fmaf(__uint_as_float(dw << 16), aw[2 * kd], s0);
        s1 = fmaf(__uint_as_float(dw & 0xFFFF0000u), aw[2 * kd + 1], s1);
    }
    float sc = s0 + s1 + ab[0];

    float mx = sc;
    #pragma unroll
    for (int off = 1; off < 8; off <<= 1) mx = fmaxf(mx, __shfl_xor(mx, off));
    float e = expf(sc - mx);
    float den = e;
    #pragma unroll
    for (int off = 1; off < 8; off <<= 1) den += __shfl_xor(den, off);
    const float at = e / den;
    attn_out[row] = at;

    // lane li owns h = q*16 + li*2 + {0,1}  (conflict-free b32 reads)
    const int lgrp = tid >> 3;
    const int li = tid & 7;
    const int wl = tid & 63;
    float oo[8];
    #pragma unroll
    for (int i = 0; i < 8; ++i) oo[i] = 0.0f;
    #pragma unroll
    for (int ns = 0; ns < 8; ++ns) {
        float atn = __shfl(at, (wl >> 3) * 8 + ns);
        const int rbase = (lgrp * 8 + ns) * 33;
        #pragma unroll
        for (int q = 0; q < 4; ++q) {
            unsigned dw = f3dw[rbase + q * 8 + li];
            oo[2 * q + 0] = fmaf(atn, __uint_as_float(dw << 16), oo[2 * q + 0]);
            oo[2 * q + 1] = fmaf(atn, __uint_as_float(dw & 0xFFFF0000u), oo[2 * q + 1]);
        }
    }
    #pragma unroll
    for (int q = 0; q < 4; ++q) {
        sbuf[lgrp * 65 + q * 16 + li * 2 + 0] = oo[2 * q + 0];
        sbuf[lgrp * 65 + q * 16 + li * 2 + 1] = oo[2 * q + 1];
    }
    __syncthreads();

    const int al = tid & 15, j = tid >> 4;
    const int ga = (row0 >> 3) + al;
    const int ma = ga / 225, aa2 = ga % 225;
    #pragma unroll
    for (int rep = 0; rep < 8; ++rep) {
        int h = j * 8 + rep;
        vox[(ma * 64 + h) * AT + aa2] = sbuf[al * 65 + h];
    }
}

// ---------------------------------------------------------------- conv1 MFMA
__global__ __launch_bounds__(256) void k_conv1m(
    const float* __restrict__ vox, const unsigned short* __restrict__ w1m,
    const float* __restrict__ b1, float* __restrict__ out)
{
    const int m = blockIdx.x;
    const int tid = threadIdx.x;
    __shared__ unsigned short voxT[225 * 66];

    for (int i = tid; i < 64 * 225; i += 256) {
        int c = i / 225, a = i - c * 225;
        voxT[a * 66 + c] = f2bf(vox[m * (64 * 225) + i]);
    }
    __syncthreads();

    const int wv = tid >> 6, lane = tid & 63;
    const int quad = lane >> 4, n = lane & 15;
    const int p = wv * 16 + n;
    const int pe = (p > 62) ? 62 : p;
    const int zo = pe / 9, pr = pe % 9, yo = pr / 3, xo = pr % 3;
    const int basep = zo * 25 + yo * 5 + xo;

    f32x4 acc[6];
    #pragma unroll
    for (int t = 0; t < 6; ++t) acc[t] = (f32x4){0.f, 0.f, 0.f, 0.f};

    const uint4* Aptr = (const uint4*)w1m;

    auto loadB = [&](int s) -> uint4 {
        int tap = s >> 1;
        int dz = tap / 9, tr = tap % 9, dy = tr / 3, dx = tr % 3;
        int rw = basep + dz * 25 + dy * 5 + dx;
        int bidx = rw * 66 + (s & 1) * 32 + quad * 8;
        const unsigned int* vp = (const unsigned int*)(voxT + bidx);
        uint4 r; r.x = vp[0]; r.y = vp[1]; r.z = vp[2]; r.w = vp[3];
        return r;
    };

    uint4 Acur[6], Anxt[6];
    #pragma unroll
    for (int t = 0; t < 6; ++t) Acur[t] = Aptr[t * 64 + lane];
    uint4 Bcur = loadB(0), Bnxt;

    for (int s = 0; s < 54; ++s) {
        if (s < 53) {
            Bnxt = loadB(s + 1);
            #pragma unroll
            for (int t = 0; t < 6; ++t)
                Anxt[t] = Aptr[((s + 1) * 6 + t) * 64 + lane];
        }
        bf16x8 bf = __builtin_bit_cast(bf16x8, Bcur);
        #pragma unroll
        for (int t = 0; t < 6; ++t) {
            bf16x8 af = __builtin_bit_cast(bf16x8, Acur[t]);
            acc[t] = __builtin_amdgcn_mfma_f32_16x16x32_bf16(af, bf, acc[t], 0, 0, 0);
        }
        #pragma unroll
        for (int t = 0; t < 6; ++t) Acur[t] = Anxt[t];
        Bcur = Bnxt;
    }

    if (p < 63) {
        #pragma unroll
        for (int t = 0; t < 6; ++t) {
            #pragma unroll
            for (int r = 0; r < 4; ++r) {
                int o = t * 16 + quad * 4 + r;
                out[m * (96 * 63) + o * 63 + p] = fmaxf(acc[t][r] + b1[o], 0.0f);
            }
        }
    }
}

// ---------------------------------------------------------------- conv2 MFMA
// 3 images per block; M rows = mi*5+zo (15 used of 16); K = tap*96+c (81 steps
// of 32: tap = s/3, cbase = (s%3)*32). A from transposed bf16 LDS tile
// (stride 98 us, odd-dword => conflict-free); B streamed from w2n (coalesced).
__global__ __launch_bounds__(256) void k_conv2m(
    const float* __restrict__ c1, const unsigned short* __restrict__ w2n,
    const float* __restrict__ b2, float* __restrict__ out)
{
    const int tid = threadIdx.x;
    const int m0 = blockIdx.x * 3;
    __shared__ unsigned short c1T[3 * 63 * C2S];   // 37044 B

    for (int i = tid; i < 3 * 96 * 63; i += 256) {
        int mi = i / (96 * 63), r = i % (96 * 63);
        int o = r / 63, p = r % 63;
        int mg = m0 + mi;
        float v = (mg < MT) ? c1[mg * (96 * 63) + r] : 0.0f;
        c1T[(mi * 63 + p) * C2S + o] = f2bf(v);
    }
    __syncthreads();

    const int wv = tid >> 6, lane = tid & 63;
    const int quad = lane >> 4, ncol = lane & 15;
    const int arow = lane & 15;
    const int mi = (arow < 15) ? arow / 5 : 2;
    const int zo = (arow < 15) ? arow % 5 : 4;

    f32x4 acc[2];
    acc[0] = (f32x4){0.f, 0.f, 0.f, 0.f};
    acc[1] = (f32x4){0.f, 0.f, 0.f, 0.f};
    const uint4* Bptr = (const uint4*)w2n;

    for (int tap = 0; tap < 27; ++tap) {
        const int dz = tap / 9, r9 = tap % 9;
        const int rowb = (mi * 63 + (zo + dz) * 9 + r9) * C2S;
        #pragma unroll
        for (int sub = 0; sub < 3; ++sub) {
            const int s = tap * 3 + sub;
            const unsigned int* ap =
                (const unsigned int*)(c1T + rowb + sub * 32 + quad * 8);
            uint4 au; au.x = ap[0]; au.y = ap[1]; au.z = ap[2]; au.w = ap[3];
            bf16x8 af = __builtin_bit_cast(bf16x8, au);
            #pragma unroll
            for (int nt = 0; nt < 2; ++nt) {
                uint4 bu = Bptr[(s * 8 + wv * 2 + nt) * 64 + lane];
                bf16x8 bf = __builtin_bit_cast(bf16x8, bu);
                acc[nt] = __builtin_amdgcn_mfma_f32_16x16x32_bf16(af, bf, acc[nt], 0, 0, 0);
            }
        }
    }

    #pragma unroll
    for (int nt = 0; nt < 2; ++nt) {
        const int o = (wv * 2 + nt) * 16 + ncol;
        const float bias = b2[o];
        #pragma unroll
        for (int reg = 0; reg < 4; ++reg) {
            int rr = quad * 4 + reg;
            if (rr < 15) {
                int mg = m0 + rr / 5;
                if (mg < MT)
                    out[mg * 640 + o * 5 + (rr % 5)] =
                        fmaxf(acc[nt][reg] + bias, 0.0f);
            }
        }
    }
}

// ---------------------------------------------------------------- conv3 + xwi
__global__ __launch_bounds__(256) void k_c3x(
    const float* __restrict__ c2, const float* __restrict__ w3t,
    const float* __restrict__ b3, const float* __restrict__ wi,
    const float* __restrict__ lb, float* __restrict__ xwi)
{
    const int tid = threadIdx.x;
    const int mm = tid >> 6, u = tid & 63;
    const int m0 = blockIdx.x * 4;
    __shared__ float inb[4][640];
    __shared__ float vvl[4][64];
    for (int idx = tid; idx < 4 * 640; idx += 256)
        inb[idx / 640][idx % 640] = c2[m0 * 640 + idx];
    __syncthreads();
    float acc = b3[u];
    for (int k = 0; k < 640; ++k)
        acc = fmaf(inb[mm][k], w3t[k * 64 + u], acc);
    vvl[mm][u] = acc;
    __syncthreads();
    #pragma unroll
    for (int mi = 0; mi < 4; ++mi) {
        float a2 = lb[tid];
        #pragma unroll
        for (int k = 0; k < 64; ++k)
            a2 = fmaf(vvl[mi][k], wi[k * 256 + tid], a2);
        xwi[(m0 + mi) * 256 + tid] = a2;
    }
}

// ---------------------------------------------------------------- LSTM
__global__ __launch_bounds__(256) void k_lstm(
    const float* __restrict__ xwi, const float* __restrict__ whg,
    const float* __restrict__ h0, const float* __restrict__ c0,
    float* __restrict__ avec, float* __restrict__ hn, float* __restrict__ cn)
{
    const int b = blockIdx.x;
    const int j = threadIdx.x;
    __shared__ float hbuf[64];
    __shared__ float gbuf[256];

    float wh[64];
    #pragma unroll
    for (int k = 0; k < 64; ++k) wh[k] = whg[k * 256 + j];

    if (j < 64) hbuf[j] = h0[b * 64 + j];
    float c = (j < 64) ? c0[b * 64 + j] : 0.0f;
    __syncthreads();

    for (int t = 0; t < 64; ++t) {
        float g = xwi[(b * 64 + t) * 256 + j];
        #pragma unroll
        for (int k = 0; k < 64; ++k) g = fmaf(hbuf[k], wh[k], g);
        gbuf[j] = g;
        __syncthreads();
        if (j < 64) {
            float gi = gbuf[j], gf = gbuf[64 + j], gg = gbuf[128 + j], go = gbuf[192 + j];
            c = sigm(gf) * c + sigm(gi) * tanhf(gg);
            float h = sigm(go) * tanhf(c);
            hbuf[j] = h;
            avec[(b * 64 + t) * 64 + j] = h;
        }
        __syncthreads();
    }
    if (j < 64) {
        hn[b * 64 + j] = hbuf[j];
        cn[b * 64 + j] = c;
    }
}

// ---------------------------------------------------------------- launch
extern "C" void kernel_launch(void* const* d_in, const int* in_sizes, int n_in,
                              void* d_out, int out_size, void* d_ws, size_t ws_size,
                              hipStream_t stream) {
    const float* x     = (const float*)d_in[0];
    const float* g_loc = (const float*)d_in[1];
    const float* h0    = (const float*)d_in[2];
    const float* c0    = (const float*)d_in[3];
    const float* pn_w1 = (const float*)d_in[4];
    const float* pn_b1 = (const float*)d_in[5];
    const float* pn_w2 = (const float*)d_in[6];
    const float* pn_b2 = (const float*)d_in[7];
    const float* pn_w3 = (const float*)d_in[8];
    const float* pn_b3 = (const float*)d_in[9];
    const float* aw    = (const float*)d_in[10];
    const float* ab    = (const float*)d_in[11];
    const float* vx_w1 = (const float*)d_in[12];
    const float* vx_b1 = (const float*)d_in[13];
    const float* vx_w2 = (const float*)d_in[14];
    const float* vx_b2 = (const float*)d_in[15];
    const float* vx_w3 = (const float*)d_in[16];
    const float* vx_b3 = (const float*)d_in[17];
    const float* lwi   = (const float*)d_in[18];
    const float* lwh   = (const float*)d_in[19];
    const float* lb    = (const float*)d_in[20];

    float* ws  = (float*)d_ws;
    float* vox = ws;
    float* c1  = vox + SZ_VOX;
    float* c2  = c1 + SZ_C1;
    float* vv  = c2 + SZ_C2;          // unused now (kept for layout stability)
    float* xwi = vv + SZ_VV;
    float* w1r = xwi + SZ_XWI;
    float* w2r = w1r + SZ_W1T;
    float* w3t = w2r + SZ_W2T;
    float* w2mr = w3t + SZ_W3T;
    unsigned short* w1m = (unsigned short*)w1r;
    unsigned short* w2n = (unsigned short*)w2r;
    unsigned short* w2m = (unsigned short*)w2mr;
    unsigned short* w3m = (unsigned short*)xwi;  // aliases xwi head; xwi written later
    int*   idxb = (int*)c1;           // idx lives in the (not-yet-written) c1 region

    float* out   = (float*)d_out;
    float* avec  = out;                   // 65536
    float* attnw = out + 65536;           // 1843200
    float* hn    = out + 65536 + 1843200; // 1024
    float* cn    = hn + 1024;             // 1024

    k_transpose<<<405, 256, 0, stream>>>(vx_w1, vx_w2, vx_w3, pn_w3, pn_w2,
                                         w1m, w2n, w3t, w3m, w2m);
    k_group<<<1024, 256, 0, stream>>>(x, g_loc, idxb);
    k_mlpm<<<14400, 128, 0, stream>>>(x, g_loc, idxb, pn_w1, pn_b1, w2m, pn_b2,
                                      w3m, pn_b3, aw, ab, vox, attnw);
    k_conv1m<<<1024, 256, 0, stream>>>(vox, w1m, vx_b1, c1);
    k_conv2m<<<342, 256, 0, stream>>>(c1, w2n, vx_b2, c2);
    k_c3x<<<256, 256, 0, stream>>>(c2, w3t, vx_b3, lwi, lb, xwi);
    k_lstm<<<16, 256, 0, stream>>>(xwi, lwh, h0, c0, avec, hn, cn);
}

// Round 8
// 387.803 us; speedup vs baseline: 2.2051x; 1.1713x over previous
//
#include <hip/hip_runtime.h>
#include <cmath>

// Shapes (fixed by the problem)
#define AT 225      // Z*Y*X anchors
#define NP 128      // points per sample
#define MT 1024     // B*T
#define NSEL 8
#define HD 64

// workspace float offsets
#define SZ_VOX  (1024u*64u*225u)     // region sized in floats; holds bf16 vox now
#define SZ_C1   (1024u*96u*63u)      // region holds bf16 c1 now (idx aliases head before conv1)
#define SZ_C2   (1024u*128u*5u)
#define SZ_VV   (1024u*64u)
#define SZ_XWI  (1024u*256u)         // (w3m aliases its head before k_c3x runs)
#define SZ_W1T  (64u*27u*96u)        // holds w1m (bf16 A-frags, conv1)
#define SZ_W2T  (96u*27u*128u)       // holds w2n (bf16 B-frags, conv2)
#define SZ_W3T  (640u*64u)
#define SZ_W2M  (512u)               // pn layer2 B-frags (128 uint4)

#define C2S 98                       // conv2 LDS row stride (us), 49 dw (odd)

typedef __attribute__((ext_vector_type(8))) short bf16x8;
typedef __attribute__((ext_vector_type(4))) float f32x4;

__device__ __forceinline__ float sigm(float x) { return 1.0f / (1.0f + expf(-x)); }

__device__ __forceinline__ unsigned short f2bf(float f) {
    unsigned u = __float_as_uint(f);
    unsigned r = u + 0x7FFF + ((u >> 16) & 1);   // RNE
    return (unsigned short)(r >> 16);
}
__device__ __forceinline__ unsigned pk2(float a, float b) {
    return (unsigned)f2bf(a) | ((unsigned)f2bf(b) << 16);
}

// ---------------------------------------------------------------- transpose
__global__ __launch_bounds__(256) void k_transpose(
    const float* __restrict__ w1, const float* __restrict__ w2,
    const float* __restrict__ w3, const float* __restrict__ pnw3,
    const float* __restrict__ pnw2,
    unsigned short* __restrict__ w1m, unsigned short* __restrict__ w2n,
    float* __restrict__ w3t, unsigned short* __restrict__ w3m,
    unsigned short* __restrict__ w2m)
{
    int idx = blockIdx.x * 256 + threadIdx.x;
    if (idx < 20736) {
        int lane = idx & 63, r = idx >> 6;
        int t = r % 6, s = r / 6;
        int o = t * 16 + (lane & 15);
        int kb = s * 32 + (lane >> 4) * 8;
        unsigned int dw[4];
        #pragma unroll
        for (int jd = 0; jd < 4; ++jd) {
            int k0 = kb + 2 * jd, k1 = k0 + 1;
            dw[jd] = (unsigned)f2bf(w1[o * 1728 + (k0 & 63) * 27 + (k0 >> 6)]) |
                     ((unsigned)f2bf(w1[o * 1728 + (k1 & 63) * 27 + (k1 >> 6)]) << 16);
        }
        uint4 v; v.x = dw[0]; v.y = dw[1]; v.z = dw[2]; v.w = dw[3];
        ((uint4*)w1m)[idx] = v;
    } else if (idx < 62208) {
        int q = idx - 20736;
        int lane = q & 63, r = q >> 6;
        int nt = r & 7, s = r >> 3;
        int o = nt * 16 + (lane & 15);
        int kb = s * 32 + (lane >> 4) * 8;
        unsigned int dw[4];
        #pragma unroll
        for (int jd = 0; jd < 4; ++jd) {
            int k0 = kb + 2 * jd, k1 = k0 + 1;
            dw[jd] = (unsigned)f2bf(w2[o * 2592 + (k0 % 96) * 27 + (k0 / 96)]) |
                     ((unsigned)f2bf(w2[o * 2592 + (k1 % 96) * 27 + (k1 / 96)]) << 16);
        }
        uint4 v; v.x = dw[0]; v.y = dw[1]; v.z = dw[2]; v.w = dw[3];
        ((uint4*)w2n)[q] = v;
    } else if (idx < 103168) {
        int k = idx - 62208;
        int u = k & 63, r = k >> 6;
        w3t[k] = w3[u * 640 + r];
    } else if (idx < 103424) {
        int k = idx - 103168;
        int lane = k & 63, nt = k >> 6;
        int n = nt * 16 + (lane & 15);
        int kb = (lane >> 4) * 8;
        unsigned int dw[4];
        #pragma unroll
        for (int jd = 0; jd < 4; ++jd) {
            int k0 = kb + 2 * jd;
            dw[jd] = (unsigned)f2bf(pnw3[k0 * 64 + n]) |
                     ((unsigned)f2bf(pnw3[(k0 + 1) * 64 + n]) << 16);
        }
        uint4 v; v.x = dw[0]; v.y = dw[1]; v.z = dw[2]; v.w = dw[3];
        ((uint4*)w3m)[k] = v;
    } else if (idx < 103552) {
        int k = idx - 103424;
        int lane = k & 63, nt = k >> 6;          // nt 0..1
        int n = nt * 16 + (lane & 15);
        int kb = (lane >> 4) * 8;
        unsigned int dw[4];
        #pragma unroll
        for (int jd = 0; jd < 4; ++jd) {
            int k0 = kb + 2 * jd, k1 = k0 + 1;
            float a = (k0 < 16) ? pnw2[k0 * 32 + n] : 0.0f;
            float b = (k1 < 16) ? pnw2[k1 * 32 + n] : 0.0f;
            dw[jd] = pk2(a, b);
        }
        uint4 v; v.x = dw[0]; v.y = dw[1]; v.z = dw[2]; v.w = dw[3];
        ((uint4*)w2m)[k] = v;
    }
}

// ---------------------------------------------------------------- grouping
__global__ __launch_bounds__(256) void k_group(
    const float* __restrict__ x, const float* __restrict__ g_loc,
    int* __restrict__ idxbuf)
{
    const int m = blockIdx.x;
    const int tid = threadIdx.x;
    __shared__ float pts[3][NP];

    for (int idx = tid; idx < NP * 5; idx += 256) {
        int n = idx / 5, c = idx % 5;
        if (c < 3) pts[c][n] = x[m * (NP * 5) + idx];
    }
    __syncthreads();

    const float gx = g_loc[m * 2 + 0], gy = g_loc[m * 2 + 1];
    const int grp = tid >> 3, li = tid & 7;

    for (int ca = 0; ca < 256; ca += 32) {
        const int a = ca + grp;
        const bool active = (a < AT);
        const int aa = active ? a : (AT - 1);
        const int azi = aa / 25, ar = aa % 25, ayi = ar / 5, axi = ar % 5;
        const float fx = ((float)axi - 2.0f) * 0.2f + gx;
        const float fy = ((float)ayi - 2.0f) * 0.2f + gy;
        const float fz = (float)azi * 0.22f + 0.1f;
        const float sa = fx * fx + fy * fy + fz * fz;

        float d[16];
        #pragma unroll
        for (int r = 0; r < 16; ++r) {
            int n = li * 16 + r;
            float px = pts[0][n], py = pts[1][n], pz = pts[2][n];
            d[r] = sa - 2.0f * (fx * px + fy * py + fz * pz)
                      + (px * px + py * py + pz * pz);
        }
        int nidx = 0;
        for (int j = 0; j < NSEL; ++j) {
            float best = 1e30f; int bidx = 0;
            #pragma unroll
            for (int r = 0; r < 16; ++r) {
                int n = li * 16 + r;
                if (d[r] < best) { best = d[r]; bidx = n; }
            }
            #pragma unroll
            for (int off = 1; off < 8; off <<= 1) {
                float ov = __shfl_xor(best, off);
                int   oi = __shfl_xor(bidx, off);
                if (ov < best || (ov == best && oi < bidx)) { best = ov; bidx = oi; }
            }
            if (li == j) nidx = bidx;
            if ((bidx >> 4) == li) {
                int slot = bidx & 15;
                #pragma unroll
                for (int r = 0; r < 16; ++r)
                    if (r == slot) d[r] = 1e30f;
            }
        }
        if (active) idxbuf[(m * AT + a) * NSEL + li] = nidx;
    }
}

// ---------------------------------------------------------------- MLP (MFMA L2+L3)
// LDS aliasing (all transitions barrier-separated; punned ushort/uint access
// REQUIRES those barriers — see R6 failure):
//   [0,8704)      fbuf (f1 then f2)  ... sbuf (4160 B) aliases head in phase C
//   [8704,25600)  f3us (16896 B)     ... pts (5120 B) aliases head in phase A
// Total 25600 B -> 6 blocks/CU (vs 35328/4 before).
__global__ __launch_bounds__(128) void k_mlpm(
    const float* __restrict__ x, const float* __restrict__ g_loc,
    const int* __restrict__ idxbuf,
    const float* __restrict__ w1, const float* __restrict__ b1,
    const unsigned short* __restrict__ w2m, const float* __restrict__ b2,
    const unsigned short* __restrict__ w3m, const float* __restrict__ b3,
    const float* __restrict__ aw, const float* __restrict__ ab,
    unsigned short* __restrict__ vox, float* __restrict__ attn_out)
{
    const int tid = threadIdx.x;
    const int row0 = blockIdx.x * 128;
    const int row = row0 + tid;

    __shared__ __align__(16) char smem[25600];
    unsigned int*   fbuf = (unsigned int*)smem;              // 8704 B
    unsigned short* f3us = (unsigned short*)(smem + 8704);   // 16896 B
    float*          pts  = (float*)(smem + 8704);            // aliases f3us head
    float*          sbuf = (float*)smem;                     // aliases fbuf head

    const int m0 = row0 / 1800;
    const int m1 = (row0 + 127) / 1800;
    #pragma unroll
    for (int mm = 0; mm < 2; ++mm) {
        int mload = (mm == 0) ? m0 : m1;
        for (int i = tid; i < NP * 5; i += 128) {
            int n = i / 5, c = i % 5;
            pts[(mm * 5 + c) * NP + n] = x[mload * (NP * 5) + i];
        }
    }
    __syncthreads();

    // ---- phase A: layer 1 per-thread, pack f1 to fbuf (K 16..31 zeroed) ----
    const int m = row / 1800;
    const int rr = row % 1800;
    const int a = rr >> 3;
    const int sel = (m == m0) ? 0 : 5;

    const int azi = a / 25, ar = a % 25, ayi = ar / 5, axi = ar % 5;
    const float gx = g_loc[m * 2 + 0], gy = g_loc[m * 2 + 1];
    const float fx = ((float)axi - 2.0f) * 0.2f + gx;
    const float fy = ((float)ayi - 2.0f) * 0.2f + gy;
    const float fz = (float)azi * 0.22f + 0.1f;

    const int nidx = idxbuf[row];
    const float in0 = pts[(sel + 0) * NP + nidx] - fx;
    const float in1 = pts[(sel + 1) * NP + nidx] - fy;
    const float in2 = pts[(sel + 2) * NP + nidx] - fz;
    const float in3 = pts[(sel + 3) * NP + nidx];
    const float in4 = pts[(sel + 4) * NP + nidx];

    float f1v[16];
    #pragma unroll
    for (int j = 0; j < 16; ++j) {
        float s = b1[j];
        s += in0 * w1[0 * 16 + j] + in1 * w1[1 * 16 + j] + in2 * w1[2 * 16 + j]
           + in3 * w1[3 * 16 + j] + in4 * w1[4 * 16 + j];
        f1v[j] = fmaxf(s, 0.0f);
    }
    __syncthreads();   // pts reads done before fbuf writes land over... (order safety)
    #pragma unroll
    for (int kd = 0; kd < 8; ++kd)
        fbuf[tid * 17 + kd] = pk2(f1v[2 * kd], f1v[2 * kd + 1]);
    #pragma unroll
    for (int kd = 8; kd < 16; ++kd)
        fbuf[tid * 17 + kd] = 0u;
    __syncthreads();

    // ---- phase B: MFMA layers ----
    const int wv = tid >> 6, lane = tid & 63;
    const int quad = lane >> 4, mcol = lane & 15;
    unsigned short* fus = (unsigned short*)fbuf;   // row stride 34 us

    // layer 2: D[128 rows][32] = f1 @ w2 (K=32 padded)
    bf16x8 w2f[2];
    #pragma unroll
    for (int nt = 0; nt < 2; ++nt) {
        uint4 u = ((const uint4*)w2m)[nt * 64 + lane];
        w2f[nt] = __builtin_bit_cast(bf16x8, u);
    }
    float b2v[2] = { b2[mcol], b2[16 + mcol] };

    #pragma unroll
    for (int mt = 0; mt < 4; ++mt) {
        const int rowbase = (wv * 4 + mt) * 16;
        const int abase = (rowbase + mcol) * 17 + quad * 4;
        uint4 au;
        au.x = fbuf[abase + 0]; au.y = fbuf[abase + 1];
        au.z = fbuf[abase + 2]; au.w = fbuf[abase + 3];
        bf16x8 af = __builtin_bit_cast(bf16x8, au);
        #pragma unroll
        for (int nt = 0; nt < 2; ++nt) {
            f32x4 z = (f32x4){0.f, 0.f, 0.f, 0.f};
            f32x4 acc = __builtin_amdgcn_mfma_f32_16x16x32_bf16(af, w2f[nt], z, 0, 0, 0);
            #pragma unroll
            for (int reg = 0; reg < 4; ++reg) {
                float v = fmaxf(acc[reg] + b2v[nt], 0.0f);
                fus[(rowbase + quad * 4 + reg) * 34 + nt * 16 + mcol] = f2bf(v);
            }
        }
    }
    __syncthreads();   // fence: ushort f2 stores -> uint A-frag loads (L3)

    // layer 3: D[128 rows][64] = f2 @ w3
    bf16x8 w3f[4];
    #pragma unroll
    for (int nt = 0; nt < 4; ++nt) {
        uint4 u = ((const uint4*)w3m)[nt * 64 + lane];
        w3f[nt] = __builtin_bit_cast(bf16x8, u);
    }
    float b3v[4];
    #pragma unroll
    for (int nt = 0; nt < 4; ++nt) b3v[nt] = b3[nt * 16 + mcol];

    #pragma unroll
    for (int mt = 0; mt < 4; ++mt) {
        const int rowbase = (wv * 4 + mt) * 16;
        const int abase = (rowbase + mcol) * 17 + quad * 4;
        uint4 au;
        au.x = fbuf[abase + 0]; au.y = fbuf[abase + 1];
        au.z = fbuf[abase + 2]; au.w = fbuf[abase + 3];
        bf16x8 af = __builtin_bit_cast(bf16x8, au);
        #pragma unroll
        for (int nt = 0; nt < 4; ++nt) {
            f32x4 z = (f32x4){0.f, 0.f, 0.f, 0.f};
            f32x4 acc = __builtin_amdgcn_mfma_f32_16x16x32_bf16(af, w3f[nt], z, 0, 0, 0);
            #pragma unroll
            for (int reg = 0; reg < 4; ++reg) {
                float v = fmaxf(acc[reg] + b3v[nt], 0.0f);
                f3us[(rowbase + quad * 4 + reg) * 66 + nt * 16 + mcol] = f2bf(v);
            }
        }
    }
    __syncthreads();   // fence: ushort f3 stores -> uint phase-C loads

    // ---- phase C: score, softmax, weighted sum ----
    const unsigned int* f3dw = (const unsigned int*)f3us;   // row stride 33 dw
    float s0 = 0.f, s1 = 0.f;
    #pragma unroll
    for (int kd = 0; kd < 32; ++kd) {
        unsigned dw = f3dw[tid * 33 + kd];
        s0 = fmaf(__uint_as_float(dw << 16), aw[2 * kd], s0);
        s1 = fmaf(__uint_as_float(dw & 0xFFFF0000u), aw[2 * kd + 1], s1);
    }
    float sc = s0 + s1 + ab[0];

    float mx = sc;
    #pragma unroll
    for (int off = 1; off < 8; off <<= 1) mx = fmaxf(mx, __shfl_xor(mx, off));
    float e = expf(sc - mx);
    float den = e;
    #pragma unroll
    for (int off = 1; off < 8; off <<= 1) den += __shfl_xor(den, off);
    const float at = e / den;
    attn_out[row] = at;

    // lane li owns h = q*16 + li*2 + {0,1}  (conflict-free b32 reads)
    const int lgrp = tid >> 3;
    const int li = tid & 7;
    const int wl = tid & 63;
    float oo[8];
    #pragma unroll
    for (int i = 0; i < 8; ++i) oo[i] = 0.0f;
    #pragma unroll
    for (int ns = 0; ns < 8; ++ns) {
        float atn = __shfl(at, (wl >> 3) * 8 + ns);
        const int rbase = (lgrp * 8 + ns) * 33;
        #pragma unroll
        for (int q = 0; q < 4; ++q) {
            unsigned dw = f3dw[rbase + q * 8 + li];
            oo[2 * q + 0] = fmaf(atn, __uint_as_float(dw << 16), oo[2 * q + 0]);
            oo[2 * q + 1] = fmaf(atn, __uint_as_float(dw & 0xFFFF0000u), oo[2 * q + 1]);
        }
    }
    __syncthreads();   // fence: fbuf A-frag loads done -> sbuf (alias) writes
    #pragma unroll
    for (int q = 0; q < 4; ++q) {
        sbuf[lgrp * 65 + q * 16 + li * 2 + 0] = oo[2 * q + 0];
        sbuf[lgrp * 65 + q * 16 + li * 2 + 1] = oo[2 * q + 1];
    }
    __syncthreads();

    const int al = tid & 15, j = tid >> 4;
    const int ga = (row0 >> 3) + al;
    const int ma = ga / 225, aa2 = ga % 225;
    #pragma unroll
    for (int rep = 0; rep < 8; ++rep) {
        int h = j * 8 + rep;
        vox[(ma * 64 + h) * AT + aa2] = f2bf(sbuf[al * 65 + h]);
    }
}

// ---------------------------------------------------------------- conv1 MFMA
// vox arrives bf16 -> staging is a pure transpose copy (uint loads, b16 stores)
__global__ __launch_bounds__(256) void k_conv1m(
    const unsigned short* __restrict__ vox, const unsigned short* __restrict__ w1m,
    const float* __restrict__ b1, unsigned short* __restrict__ out)
{
    const int m = blockIdx.x;
    const int tid = threadIdx.x;
    __shared__ unsigned short voxT[225 * 66];

    const unsigned int* vsrc = (const unsigned int*)(vox + (size_t)m * 14400);
    for (int i = tid; i < 7200; i += 256) {
        unsigned v = vsrc[i];
        int e0 = 2 * i, e1 = e0 + 1;
        int c0 = e0 / 225, a0 = e0 - c0 * 225;
        int c1i = e1 / 225, a1 = e1 - c1i * 225;
        voxT[a0 * 66 + c0] = (unsigned short)(v & 0xFFFFu);
        voxT[a1 * 66 + c1i] = (unsigned short)(v >> 16);
    }
    __syncthreads();

    const int wv = tid >> 6, lane = tid & 63;
    const int quad = lane >> 4, n = lane & 15;
    const int p = wv * 16 + n;
    const int pe = (p > 62) ? 62 : p;
    const int zo = pe / 9, pr = pe % 9, yo = pr / 3, xo = pr % 3;
    const int basep = zo * 25 + yo * 5 + xo;

    f32x4 acc[6];
    #pragma unroll
    for (int t = 0; t < 6; ++t) acc[t] = (f32x4){0.f, 0.f, 0.f, 0.f};

    const uint4* Aptr = (const uint4*)w1m;

    auto loadB = [&](int s) -> uint4 {
        int tap = s >> 1;
        int dz = tap / 9, tr = tap % 9, dy = tr / 3, dx = tr % 3;
        int rw = basep + dz * 25 + dy * 5 + dx;
        int bidx = rw * 66 + (s & 1) * 32 + quad * 8;
        const unsigned int* vp = (const unsigned int*)(voxT + bidx);
        uint4 r; r.x = vp[0]; r.y = vp[1]; r.z = vp[2]; r.w = vp[3];
        return r;
    };

    uint4 Acur[6], Anxt[6];
    #pragma unroll
    for (int t = 0; t < 6; ++t) Acur[t] = Aptr[t * 64 + lane];
    uint4 Bcur = loadB(0), Bnxt;

    for (int s = 0; s < 54; ++s) {
        if (s < 53) {
            Bnxt = loadB(s + 1);
            #pragma unroll
            for (int t = 0; t < 6; ++t)
                Anxt[t] = Aptr[((s + 1) * 6 + t) * 64 + lane];
        }
        bf16x8 bf = __builtin_bit_cast(bf16x8, Bcur);
        #pragma unroll
        for (int t = 0; t < 6; ++t) {
            bf16x8 af = __builtin_bit_cast(bf16x8, Acur[t]);
            acc[t] = __builtin_amdgcn_mfma_f32_16x16x32_bf16(af, bf, acc[t], 0, 0, 0);
        }
        #pragma unroll
        for (int t = 0; t < 6; ++t) Acur[t] = Anxt[t];
        Bcur = Bnxt;
    }

    if (p < 63) {
        #pragma unroll
        for (int t = 0; t < 6; ++t) {
            #pragma unroll
            for (int r = 0; r < 4; ++r) {
                int o = t * 16 + quad * 4 + r;
                out[m * (96 * 63) + o * 63 + p] =
                    f2bf(fmaxf(acc[t][r] + b1[o], 0.0f));
            }
        }
    }
}

// ---------------------------------------------------------------- conv2 MFMA
// c1 arrives bf16 -> staging is a pure transpose copy.
__global__ __launch_bounds__(256) void k_conv2m(
    const unsigned short* __restrict__ c1, const unsigned short* __restrict__ w2n,
    const float* __restrict__ b2, float* __restrict__ out)
{
    const int tid = threadIdx.x;
    const int m0 = blockIdx.x * 3;
    __shared__ unsigned short c1T[3 * 63 * C2S];   // 37044 B

    const unsigned int* csrc = (const unsigned int*)(c1 + (size_t)m0 * 6048);
    for (int i = tid; i < 9072; i += 256) {
        int e0 = 2 * i;
        int mi = e0 / 6048;            // 6048 even -> uint never crosses image
        unsigned v = (m0 + mi < MT) ? csrc[i] : 0u;
        int r0 = e0 - mi * 6048, r1 = r0 + 1;
        int o0 = r0 / 63, p0 = r0 - o0 * 63;
        int o1 = r1 / 63, p1 = r1 - o1 * 63;
        c1T[(mi * 63 + p0) * C2S + o0] = (unsigned short)(v & 0xFFFFu);
        c1T[(mi * 63 + p1) * C2S + o1] = (unsigned short)(v >> 16);
    }
    __syncthreads();

    const int wv = tid >> 6, lane = tid & 63;
    const int quad = lane >> 4, ncol = lane & 15;
    const int arow = lane & 15;
    const int mi = (arow < 15) ? arow / 5 : 2;
    const int zo = (arow < 15) ? arow % 5 : 4;

    f32x4 acc[2];
    acc[0] = (f32x4){0.f, 0.f, 0.f, 0.f};
    acc[1] = (f32x4){0.f, 0.f, 0.f, 0.f};
    const uint4* Bptr = (const uint4*)w2n;

    for (int tap = 0; tap < 27; ++tap) {
        const int dz = tap / 9, r9 = tap % 9;
        const int rowb = (mi * 63 + (zo + dz) * 9 + r9) * C2S;
        #pragma unroll
        for (int sub = 0; sub < 3; ++sub) {
            const int s = tap * 3 + sub;
            const unsigned int* ap =
                (const unsigned int*)(c1T + rowb + sub * 32 + quad * 8);
            uint4 au; au.x = ap[0]; au.y = ap[1]; au.z = ap[2]; au.w = ap[3];
            bf16x8 af = __builtin_bit_cast(bf16x8, au);
            #pragma unroll
            for (int nt = 0; nt < 2; ++nt) {
                uint4 bu = Bptr[(s * 8 + wv * 2 + nt) * 64 + lane];
                bf16x8 bf = __builtin_bit_cast(bf16x8, bu);
                acc[nt] = __builtin_amdgcn_mfma_f32_16x16x32_bf16(af, bf, acc[nt], 0, 0, 0);
            }
        }
    }

    #pragma unroll
    for (int nt = 0; nt < 2; ++nt) {
        const int o = (wv * 2 + nt) * 16 + ncol;
        const float bias = b2[o];
        #pragma unroll
        for (int reg = 0; reg < 4; ++reg) {
            int rr = quad * 4 + reg;
            if (rr < 15) {
                int mg = m0 + rr / 5;
                if (mg < MT)
                    out[mg * 640 + o * 5 + (rr % 5)] =
                        fmaxf(acc[nt][reg] + bias, 0.0f);
            }
        }
    }
}

// ---------------------------------------------------------------- conv3 + xwi
// one m per block; conv3 K split over 4 partial-threads (chain 160 not 640);
// 1024 blocks -> 4 blocks/CU -> 4 waves/SIMD.
__global__ __launch_bounds__(256) void k_c3x(
    const float* __restrict__ c2, const float* __restrict__ w3t,
    const float* __restrict__ b3, const float* __restrict__ wi,
    const float* __restrict__ lb, float* __restrict__ xwi)
{
    const int tid = threadIdx.x;
    const int m = blockIdx.x;
    __shared__ float inb[640];
    __shared__ float part[4][64];
    __shared__ float vvl[64];

    for (int i = tid; i < 640; i += 256) inb[i] = c2[m * 640 + i];
    __syncthreads();

    const int u = tid & 63, kq = tid >> 6;
    float acc = 0.0f;
    const int k0 = kq * 160;
    #pragma unroll 8
    for (int k = k0; k < k0 + 160; ++k)
        acc = fmaf(inb[k], w3t[k * 64 + u], acc);
    part[kq][u] = acc;
    __syncthreads();

    if (tid < 64)
        vvl[tid] = b3[tid] + ((part[0][tid] + part[1][tid])
                 + (part[2][tid] + part[3][tid]));
    __syncthreads();

    float a2 = lb[tid];
    #pragma unroll
    for (int k = 0; k < 64; ++k)
        a2 = fmaf(vvl[k], wi[k * 256 + tid], a2);
    xwi[m * 256 + tid] = a2;
}

// ---------------------------------------------------------------- LSTM
__global__ __launch_bounds__(256) void k_lstm(
    const float* __restrict__ xwi, const float* __restrict__ whg,
    const float* __restrict__ h0, const float* __restrict__ c0,
    float* __restrict__ avec, float* __restrict__ hn, float* __restrict__ cn)
{
    const int b = blockIdx.x;
    const int j = threadIdx.x;
    __shared__ float hbuf[64];
    __shared__ float gbuf[256];

    float wh[64];
    #pragma unroll
    for (int k = 0; k < 64; ++k) wh[k] = whg[k * 256 + j];

    if (j < 64) hbuf[j] = h0[b * 64 + j];
    float c = (j < 64) ? c0[b * 64 + j] : 0.0f;
    __syncthreads();

    for (int t = 0; t < 64; ++t) {
        float g = xwi[(b * 64 + t) * 256 + j];
        #pragma unroll
        for (int k = 0; k < 64; ++k) g = fmaf(hbuf[k], wh[k], g);
        gbuf[j] = g;
        __syncthreads();
        if (j < 64) {
            float gi = gbuf[j], gf = gbuf[64 + j], gg = gbuf[128 + j], go = gbuf[192 + j];
            c = sigm(gf) * c + sigm(gi) * tanhf(gg);
            float h = sigm(go) * tanhf(c);
            hbuf[j] = h;
            avec[(b * 64 + t) * 64 + j] = h;
        }
        __syncthreads();
    }
    if (j < 64) {
        hn[b * 64 + j] = hbuf[j];
        cn[b * 64 + j] = c;
    }
}

// ---------------------------------------------------------------- launch
extern "C" void kernel_launch(void* const* d_in, const int* in_sizes, int n_in,
                              void* d_out, int out_size, void* d_ws, size_t ws_size,
                              hipStream_t stream) {
    const float* x     = (const float*)d_in[0];
    const float* g_loc = (const float*)d_in[1];
    const float* h0    = (const float*)d_in[2];
    const float* c0    = (const float*)d_in[3];
    const float* pn_w1 = (const float*)d_in[4];
    const float* pn_b1 = (const float*)d_in[5];
    const float* pn_w2 = (const float*)d_in[6];
    const float* pn_b2 = (const float*)d_in[7];
    const float* pn_w3 = (const float*)d_in[8];
    const float* pn_b3 = (const float*)d_in[9];
    const float* aw    = (const float*)d_in[10];
    const float* ab    = (const float*)d_in[11];
    const float* vx_w1 = (const float*)d_in[12];
    const float* vx_b1 = (const float*)d_in[13];
    const float* vx_w2 = (const float*)d_in[14];
    const float* vx_b2 = (const float*)d_in[15];
    const float* vx_w3 = (const float*)d_in[16];
    const float* vx_b3 = (const float*)d_in[17];
    const float* lwi   = (const float*)d_in[18];
    const float* lwh   = (const float*)d_in[19];
    const float* lb    = (const float*)d_in[20];

    float* ws  = (float*)d_ws;
    float* voxr = ws;
    float* c1r  = voxr + SZ_VOX;
    float* c2  = c1r + SZ_C1;
    float* vv  = c2 + SZ_C2;          // unused (layout stability)
    float* xwi = vv + SZ_VV;
    float* w1r = xwi + SZ_XWI;
    float* w2r = w1r + SZ_W1T;
    float* w3t = w2r + SZ_W2T;
    float* w2mr = w3t + SZ_W3T;
    unsigned short* voxh = (unsigned short*)voxr;
    unsigned short* c1h  = (unsigned short*)c1r;
    unsigned short* w1m = (unsigned short*)w1r;
    unsigned short* w2n = (unsigned short*)w2r;
    unsigned short* w2m = (unsigned short*)w2mr;
    unsigned short* w3m = (unsigned short*)xwi;  // aliases xwi head; xwi written later
    int*   idxb = (int*)c1r;          // idx lives in the (not-yet-written) c1 region
                                      // NOTE: conv1m writes c1h AFTER k_mlpm reads idxb

    float* out   = (float*)d_out;
    float* avec  = out;                   // 65536
    float* attnw = out + 65536;           // 1843200
    float* hn    = out + 65536 + 1843200; // 1024
    float* cn    = hn + 1024;             // 1024

    k_transpose<<<405, 256, 0, stream>>>(vx_w1, vx_w2, vx_w3, pn_w3, pn_w2,
                                         w1m, w2n, w3t, w3m, w2m);
    k_group<<<1024, 256, 0, stream>>>(x, g_loc, idxb);
    k_mlpm<<<14400, 128, 0, stream>>>(x, g_loc, idxb, pn_w1, pn_b1, w2m, pn_b2,
                                      w3m, pn_b3, aw, ab, voxh, attnw);
    k_conv1m<<<1024, 256, 0, stream>>>(voxh, w1m, vx_b1, c1h);
    k_conv2m<<<342, 256, 0, stream>>>(c1h, w2n, vx_b2, c2);
    k_c3x<<<1024, 256, 0, stream>>>(c2, w3t, vx_b3, lwi, lb, xwi);
    k_lstm<<<16, 256, 0, stream>>>(xwi, lwh, h0, c0, avec, hn, cn);
}

// Round 9
// 378.360 us; speedup vs baseline: 2.2602x; 1.0250x over previous
//
#include <hip/hip_runtime.h>
#include <cmath>

// Shapes (fixed by the problem)
#define AT 225      // Z*Y*X anchors
#define NP 128      // points per sample
#define MT 1024     // B*T
#define NSEL 8
#define HD 64

// workspace float offsets
#define SZ_VOX  (1024u*64u*225u)     // region sized in floats; holds bf16 vox
#define SZ_C1   (1024u*96u*63u)      // region holds bf16 c1 (idx aliases head before conv1)
#define SZ_C2   (1024u*128u*5u)
#define SZ_VV   (1024u*64u)
#define SZ_XWI  (1024u*256u)         // (w3m aliases its head before k_c3x runs)
#define SZ_W1T  (64u*27u*96u)        // holds w1m (bf16 A-frags, conv1)
#define SZ_W2T  (96u*27u*128u)       // holds w2n (bf16 B-frags, conv2)
#define SZ_W3T  (640u*64u)
#define SZ_W2M  (512u)               // pn layer2 B-frags (128 uint4)

#define C2S 98                       // conv2 LDS row stride (us), 49 dw (odd)

typedef __attribute__((ext_vector_type(8))) short bf16x8;
typedef __attribute__((ext_vector_type(4))) float f32x4;

__device__ __forceinline__ float sigm(float x) { return 1.0f / (1.0f + expf(-x)); }

__device__ __forceinline__ unsigned short f2bf(float f) {
    unsigned u = __float_as_uint(f);
    unsigned r = u + 0x7FFF + ((u >> 16) & 1);   // RNE
    return (unsigned short)(r >> 16);
}

#if defined(__has_builtin)
#if __has_builtin(__builtin_amdgcn_cvt_pk_bf16_f32)
#define HAVE_CVT_PK_BF16 1
#endif
#endif

__device__ __forceinline__ unsigned pk2(float a, float b) {
#ifdef HAVE_CVT_PK_BF16
    auto v = __builtin_amdgcn_cvt_pk_bf16_f32(a, b);
    return __builtin_bit_cast(unsigned, v);
#else
    return (unsigned)f2bf(a) | ((unsigned)f2bf(b) << 16);
#endif
}

// ---------------------------------------------------------------- transpose
__global__ __launch_bounds__(256) void k_transpose(
    const float* __restrict__ w1, const float* __restrict__ w2,
    const float* __restrict__ w3, const float* __restrict__ pnw3,
    const float* __restrict__ pnw2,
    unsigned short* __restrict__ w1m, unsigned short* __restrict__ w2n,
    float* __restrict__ w3t, unsigned short* __restrict__ w3m,
    unsigned short* __restrict__ w2m)
{
    int idx = blockIdx.x * 256 + threadIdx.x;
    if (idx < 20736) {
        int lane = idx & 63, r = idx >> 6;
        int t = r % 6, s = r / 6;
        int o = t * 16 + (lane & 15);
        int kb = s * 32 + (lane >> 4) * 8;
        unsigned int dw[4];
        #pragma unroll
        for (int jd = 0; jd < 4; ++jd) {
            int k0 = kb + 2 * jd, k1 = k0 + 1;
            dw[jd] = (unsigned)f2bf(w1[o * 1728 + (k0 & 63) * 27 + (k0 >> 6)]) |
                     ((unsigned)f2bf(w1[o * 1728 + (k1 & 63) * 27 + (k1 >> 6)]) << 16);
        }
        uint4 v; v.x = dw[0]; v.y = dw[1]; v.z = dw[2]; v.w = dw[3];
        ((uint4*)w1m)[idx] = v;
    } else if (idx < 62208) {
        int q = idx - 20736;
        int lane = q & 63, r = q >> 6;
        int nt = r & 7, s = r >> 3;
        int o = nt * 16 + (lane & 15);
        int kb = s * 32 + (lane >> 4) * 8;
        unsigned int dw[4];
        #pragma unroll
        for (int jd = 0; jd < 4; ++jd) {
            int k0 = kb + 2 * jd, k1 = k0 + 1;
            dw[jd] = (unsigned)f2bf(w2[o * 2592 + (k0 % 96) * 27 + (k0 / 96)]) |
                     ((unsigned)f2bf(w2[o * 2592 + (k1 % 96) * 27 + (k1 / 96)]) << 16);
        }
        uint4 v; v.x = dw[0]; v.y = dw[1]; v.z = dw[2]; v.w = dw[3];
        ((uint4*)w2n)[q] = v;
    } else if (idx < 103168) {
        int k = idx - 62208;
        int u = k & 63, r = k >> 6;
        w3t[k] = w3[u * 640 + r];
    } else if (idx < 103424) {
        int k = idx - 103168;
        int lane = k & 63, nt = k >> 6;
        int n = nt * 16 + (lane & 15);
        int kb = (lane >> 4) * 8;
        unsigned int dw[4];
        #pragma unroll
        for (int jd = 0; jd < 4; ++jd) {
            int k0 = kb + 2 * jd;
            dw[jd] = (unsigned)f2bf(pnw3[k0 * 64 + n]) |
                     ((unsigned)f2bf(pnw3[(k0 + 1) * 64 + n]) << 16);
        }
        uint4 v; v.x = dw[0]; v.y = dw[1]; v.z = dw[2]; v.w = dw[3];
        ((uint4*)w3m)[k] = v;
    } else if (idx < 103552) {
        int k = idx - 103424;
        int lane = k & 63, nt = k >> 6;          // nt 0..1
        int n = nt * 16 + (lane & 15);
        int kb = (lane >> 4) * 8;
        unsigned int dw[4];
        #pragma unroll
        for (int jd = 0; jd < 4; ++jd) {
            int k0 = kb + 2 * jd, k1 = k0 + 1;
            float a = (k0 < 16) ? pnw2[k0 * 32 + n] : 0.0f;
            float b = (k1 < 16) ? pnw2[k1 * 32 + n] : 0.0f;
            dw[jd] = (unsigned)f2bf(a) | ((unsigned)f2bf(b) << 16);
        }
        uint4 v; v.x = dw[0]; v.y = dw[1]; v.z = dw[2]; v.w = dw[3];
        ((uint4*)w2m)[k] = v;
    }
}

// ---------------------------------------------------------------- grouping
__global__ __launch_bounds__(256) void k_group(
    const float* __restrict__ x, const float* __restrict__ g_loc,
    int* __restrict__ idxbuf)
{
    const int m = blockIdx.x;
    const int tid = threadIdx.x;
    __shared__ float pts[3][NP];

    for (int idx = tid; idx < NP * 5; idx += 256) {
        int n = idx / 5, c = idx % 5;
        if (c < 3) pts[c][n] = x[m * (NP * 5) + idx];
    }
    __syncthreads();

    const float gx = g_loc[m * 2 + 0], gy = g_loc[m * 2 + 1];
    const int grp = tid >> 3, li = tid & 7;

    for (int ca = 0; ca < 256; ca += 32) {
        const int a = ca + grp;
        const bool active = (a < AT);
        const int aa = active ? a : (AT - 1);
        const int azi = aa / 25, ar = aa % 25, ayi = ar / 5, axi = ar % 5;
        const float fx = ((float)axi - 2.0f) * 0.2f + gx;
        const float fy = ((float)ayi - 2.0f) * 0.2f + gy;
        const float fz = (float)azi * 0.22f + 0.1f;
        const float sa = fx * fx + fy * fy + fz * fz;

        float d[16];
        #pragma unroll
        for (int r = 0; r < 16; ++r) {
            int n = li * 16 + r;
            float px = pts[0][n], py = pts[1][n], pz = pts[2][n];
            d[r] = sa - 2.0f * (fx * px + fy * py + fz * pz)
                      + (px * px + py * py + pz * pz);
        }
        int nidx = 0;
        for (int j = 0; j < NSEL; ++j) {
            float best = 1e30f; int bidx = 0;
            #pragma unroll
            for (int r = 0; r < 16; ++r) {
                int n = li * 16 + r;
                if (d[r] < best) { best = d[r]; bidx = n; }
            }
            #pragma unroll
            for (int off = 1; off < 8; off <<= 1) {
                float ov = __shfl_xor(best, off);
                int   oi = __shfl_xor(bidx, off);
                if (ov < best || (ov == best && oi < bidx)) { best = ov; bidx = oi; }
            }
            if (li == j) nidx = bidx;
            if ((bidx >> 4) == li) {
                int slot = bidx & 15;
                #pragma unroll
                for (int r = 0; r < 16; ++r)
                    if (r == slot) d[r] = 1e30f;
            }
        }
        if (active) idxbuf[(m * AT + a) * NSEL + li] = nidx;
    }
}

// ---------------------------------------------------------------- MLP (MFMA L2+L3)
// LDS aliasing (all transitions barrier-separated; punned ushort/uint access
// REQUIRES those barriers — see R6 failure):
//   [0,8704)      fbuf (f1 then f2)  ... sbuf (4160 B) aliases head in phase C
//   [8704,25600)  f3us (16896 B)     ... pts (5120 B, raw x-layout) aliases head
__global__ __launch_bounds__(128) void k_mlpm(
    const float* __restrict__ x, const float* __restrict__ g_loc,
    const int* __restrict__ idxbuf,
    const float* __restrict__ w1, const float* __restrict__ b1,
    const unsigned short* __restrict__ w2m, const float* __restrict__ b2,
    const unsigned short* __restrict__ w3m, const float* __restrict__ b3,
    const float* __restrict__ aw, const float* __restrict__ ab,
    unsigned short* __restrict__ vox, float* __restrict__ attn_out)
{
    const int tid = threadIdx.x;
    const int row0 = blockIdx.x * 128;
    const int row = row0 + tid;

    __shared__ __align__(16) char smem[25600];
    unsigned int*   fbuf = (unsigned int*)smem;              // 8704 B
    unsigned short* f3us = (unsigned short*)(smem + 8704);   // 16896 B
    float*          pts  = (float*)(smem + 8704);            // aliases f3us head
    float*          sbuf = (float*)smem;                     // aliases fbuf head

    const int m0 = row0 / 1800;
    const int m1 = (row0 + 127) / 1800;
    // raw-layout staging: pts[0..640) = x[m0], pts[640..1280) = x[m1]; no div/mod
    #pragma unroll
    for (int i = tid; i < 640; i += 128) {
        pts[i]       = x[m0 * 640 + i];
        pts[640 + i] = x[m1 * 640 + i];
    }
    __syncthreads();

    // ---- phase A: layer 1 per-thread, pack f1 to fbuf (K 16..31 zeroed) ----
    const int m = row / 1800;
    const int rr = row % 1800;
    const int a = rr >> 3;
    const int base = (m == m0) ? 0 : 640;

    const int azi = a / 25, ar = a % 25, ayi = ar / 5, axi = ar % 5;
    const float gx = g_loc[m * 2 + 0], gy = g_loc[m * 2 + 1];
    const float fx = ((float)axi - 2.0f) * 0.2f + gx;
    const float fy = ((float)ayi - 2.0f) * 0.2f + gy;
    const float fz = (float)azi * 0.22f + 0.1f;

    const int nidx = idxbuf[row];
    const float in0 = pts[base + nidx * 5 + 0] - fx;
    const float in1 = pts[base + nidx * 5 + 1] - fy;
    const float in2 = pts[base + nidx * 5 + 2] - fz;
    const float in3 = pts[base + nidx * 5 + 3];
    const float in4 = pts[base + nidx * 5 + 4];

    float f1v[16];
    #pragma unroll
    for (int j = 0; j < 16; ++j) {
        float s = b1[j];
        s += in0 * w1[0 * 16 + j] + in1 * w1[1 * 16 + j] + in2 * w1[2 * 16 + j]
           + in3 * w1[3 * 16 + j] + in4 * w1[4 * 16 + j];
        f1v[j] = fmaxf(s, 0.0f);
    }
    __syncthreads();   // pts reads complete before any reuse / ordering safety
    #pragma unroll
    for (int kd = 0; kd < 8; ++kd)
        fbuf[tid * 17 + kd] = pk2(f1v[2 * kd], f1v[2 * kd + 1]);
    #pragma unroll
    for (int kd = 8; kd < 16; ++kd)
        fbuf[tid * 17 + kd] = 0u;
    __syncthreads();

    // ---- phase B: MFMA layers ----
    const int wv = tid >> 6, lane = tid & 63;
    const int quad = lane >> 4, mcol = lane & 15;
    unsigned short* fus = (unsigned short*)fbuf;   // row stride 34 us

    // layer 2: D[128 rows][32] = f1 @ w2 (K=32 padded)
    bf16x8 w2f[2];
    #pragma unroll
    for (int nt = 0; nt < 2; ++nt) {
        uint4 u = ((const uint4*)w2m)[nt * 64 + lane];
        w2f[nt] = __builtin_bit_cast(bf16x8, u);
    }
    float b2v[2] = { b2[mcol], b2[16 + mcol] };

    #pragma unroll
    for (int mt = 0; mt < 4; ++mt) {
        const int rowbase = (wv * 4 + mt) * 16;
        const int abase = (rowbase + mcol) * 17 + quad * 4;
        uint4 au;
        au.x = fbuf[abase + 0]; au.y = fbuf[abase + 1];
        au.z = fbuf[abase + 2]; au.w = fbuf[abase + 3];
        bf16x8 af = __builtin_bit_cast(bf16x8, au);
        #pragma unroll
        for (int nt = 0; nt < 2; ++nt) {
            f32x4 z = (f32x4){0.f, 0.f, 0.f, 0.f};
            f32x4 acc = __builtin_amdgcn_mfma_f32_16x16x32_bf16(af, w2f[nt], z, 0, 0, 0);
            #pragma unroll
            for (int reg = 0; reg < 4; ++reg) {
                float v = fmaxf(acc[reg] + b2v[nt], 0.0f);
                fus[(rowbase + quad * 4 + reg) * 34 + nt * 16 + mcol] = f2bf(v);
            }
        }
    }
    __syncthreads();   // fence: ushort f2 stores -> uint A-frag loads (L3)

    // layer 3: D[128 rows][64] = f2 @ w3
    bf16x8 w3f[4];
    #pragma unroll
    for (int nt = 0; nt < 4; ++nt) {
        uint4 u = ((const uint4*)w3m)[nt * 64 + lane];
        w3f[nt] = __builtin_bit_cast(bf16x8, u);
    }
    float b3v[4];
    #pragma unroll
    for (int nt = 0; nt < 4; ++nt) b3v[nt] = b3[nt * 16 + mcol];

    #pragma unroll
    for (int mt = 0; mt < 4; ++mt) {
        const int rowbase = (wv * 4 + mt) * 16;
        const int abase = (rowbase + mcol) * 17 + quad * 4;
        uint4 au;
        au.x = fbuf[abase + 0]; au.y = fbuf[abase + 1];
        au.z = fbuf[abase + 2]; au.w = fbuf[abase + 3];
        bf16x8 af = __builtin_bit_cast(bf16x8, au);
        #pragma unroll
        for (int nt = 0; nt < 4; ++nt) {
            f32x4 z = (f32x4){0.f, 0.f, 0.f, 0.f};
            f32x4 acc = __builtin_amdgcn_mfma_f32_16x16x32_bf16(af, w3f[nt], z, 0, 0, 0);
            #pragma unroll
            for (int reg = 0; reg < 4; ++reg) {
                float v = fmaxf(acc[reg] + b3v[nt], 0.0f);
                f3us[(rowbase + quad * 4 + reg) * 66 + nt * 16 + mcol] = f2bf(v);
            }
        }
    }
    __syncthreads();   // fence: ushort f3 stores -> uint phase-C loads

    // ---- phase C: score, softmax, weighted sum ----
    const unsigned int* f3dw = (const unsigned int*)f3us;   // row stride 33 dw
    float s0 = 0.f, s1 = 0.f;
    #pragma unroll
    for (int kd = 0; kd < 32; ++kd) {
        unsigned dw = f3dw[tid * 33 + kd];
        s0 = fmaf(__uint_as_float(dw << 16), aw[2 * kd], s0);
        s1 = fmaf(__uint_as_float(dw & 0xFFFF0000u), aw[2 * kd + 1], s1);
    }
    float sc = s0 + s1 + ab[0];

    float mx = sc;
    #pragma unroll
    for (int off = 1; off < 8; off <<= 1) mx = fmaxf(mx, __shfl_xor(mx, off));
    float e = expf(sc - mx);
    float den = e;
    #pragma unroll
    for (int off = 1; off < 8; off <<= 1) den += __shfl_xor(den, off);
    const float at = e / den;
    attn_out[row] = at;

    // lane li owns h = q*16 + li*2 + {0,1}  (conflict-free b32 reads)
    const int lgrp = tid >> 3;
    const int li = tid & 7;
    const int wl = tid & 63;
    float oo[8];
    #pragma unroll
    for (int i = 0; i < 8; ++i) oo[i] = 0.0f;
    #pragma unroll
    for (int ns = 0; ns < 8; ++ns) {
        float atn = __shfl(at, (wl >> 3) * 8 + ns);
        const int rbase = (lgrp * 8 + ns) * 33;
        #pragma unroll
        for (int q = 0; q < 4; ++q) {
            unsigned dw = f3dw[rbase + q * 8 + li];
            oo[2 * q + 0] = fmaf(atn, __uint_as_float(dw << 16), oo[2 * q + 0]);
            oo[2 * q + 1] = fmaf(atn, __uint_as_float(dw & 0xFFFF0000u), oo[2 * q + 1]);
        }
    }
    __syncthreads();   // fence: fbuf A-frag loads done -> sbuf (alias) writes
    #pragma unroll
    for (int q = 0; q < 4; ++q) {
        sbuf[lgrp * 65 + q * 16 + li * 2 + 0] = oo[2 * q + 0];
        sbuf[lgrp * 65 + q * 16 + li * 2 + 1] = oo[2 * q + 1];
    }
    __syncthreads();

    const int al = tid & 15, j = tid >> 4;
    const int ga = (row0 >> 3) + al;
    const int ma = ga / 225, aa2 = ga % 225;
    #pragma unroll
    for (int rep = 0; rep < 8; ++rep) {
        int h = j * 8 + rep;
        vox[(ma * 64 + h) * AT + aa2] = f2bf(sbuf[al * 65 + h]);
    }
}

// ---------------------------------------------------------------- conv1 MFMA
// Prefetch depth 2 on A (global/L2) to cover ~200-cyc L2 latency; B (LDS) depth 2.
__global__ __launch_bounds__(256) void k_conv1m(
    const unsigned short* __restrict__ vox, const unsigned short* __restrict__ w1m,
    const float* __restrict__ b1, unsigned short* __restrict__ out)
{
    const int m = blockIdx.x;
    const int tid = threadIdx.x;
    __shared__ unsigned short voxT[225 * 66];

    const unsigned int* vsrc = (const unsigned int*)(vox + (size_t)m * 14400);
    for (int i = tid; i < 7200; i += 256) {
        unsigned v = vsrc[i];
        int e0 = 2 * i, e1 = e0 + 1;
        int c0 = e0 / 225, a0 = e0 - c0 * 225;
        int c1i = e1 / 225, a1 = e1 - c1i * 225;
        voxT[a0 * 66 + c0] = (unsigned short)(v & 0xFFFFu);
        voxT[a1 * 66 + c1i] = (unsigned short)(v >> 16);
    }
    __syncthreads();

    const int wv = tid >> 6, lane = tid & 63;
    const int quad = lane >> 4, n = lane & 15;
    const int p = wv * 16 + n;
    const int pe = (p > 62) ? 62 : p;
    const int zo = pe / 9, pr = pe % 9, yo = pr / 3, xo = pr % 3;
    const int basep = zo * 25 + yo * 5 + xo;

    f32x4 acc[6];
    #pragma unroll
    for (int t = 0; t < 6; ++t) acc[t] = (f32x4){0.f, 0.f, 0.f, 0.f};

    const uint4* Aptr = (const uint4*)w1m;

    auto loadB = [&](int s) -> uint4 {
        int tap = s >> 1;
        int dz = tap / 9, tr = tap % 9, dy = tr / 3, dx = tr % 3;
        int rw = basep + dz * 25 + dy * 5 + dx;
        int bidx = rw * 66 + (s & 1) * 32 + quad * 8;
        const unsigned int* vp = (const unsigned int*)(voxT + bidx);
        uint4 r; r.x = vp[0]; r.y = vp[1]; r.z = vp[2]; r.w = vp[3];
        return r;
    };

    uint4 A0[6], A1[6], A2[6];
    uint4 B0, B1, B2;
    #pragma unroll
    for (int t = 0; t < 6; ++t) {
        A0[t] = Aptr[(0 * 6 + t) * 64 + lane];
        A1[t] = Aptr[(1 * 6 + t) * 64 + lane];
    }
    B0 = loadB(0); B1 = loadB(1);

    for (int s = 0; s < 54; ++s) {
        if (s < 52) {
            B2 = loadB(s + 2);
            #pragma unroll
            for (int t = 0; t < 6; ++t)
                A2[t] = Aptr[((s + 2) * 6 + t) * 64 + lane];
        }
        bf16x8 bf = __builtin_bit_cast(bf16x8, B0);
        #pragma unroll
        for (int t = 0; t < 6; ++t) {
            bf16x8 af = __builtin_bit_cast(bf16x8, A0[t]);
            acc[t] = __builtin_amdgcn_mfma_f32_16x16x32_bf16(af, bf, acc[t], 0, 0, 0);
        }
        #pragma unroll
        for (int t = 0; t < 6; ++t) { A0[t] = A1[t]; A1[t] = A2[t]; }
        B0 = B1; B1 = B2;
    }

    if (p < 63) {
        #pragma unroll
        for (int t = 0; t < 6; ++t) {
            #pragma unroll
            for (int r = 0; r < 4; ++r) {
                int o = t * 16 + quad * 4 + r;
                out[m * (96 * 63) + o * 63 + p] =
                    f2bf(fmaxf(acc[t][r] + b1[o], 0.0f));
            }
        }
    }
}

// ---------------------------------------------------------------- conv2 MFMA
// 2 images per block (rows mi*5+zo, 10 of 16 used); grid 512 = exactly
// 2 blocks/CU (balanced; old 342-grid had worst-CU 2 blocks / best 1).
__global__ __launch_bounds__(256) void k_conv2m(
    const unsigned short* __restrict__ c1, const unsigned short* __restrict__ w2n,
    const float* __restrict__ b2, float* __restrict__ out)
{
    const int tid = threadIdx.x;
    const int m0 = blockIdx.x * 2;
    __shared__ unsigned short c1T[2 * 63 * C2S];   // 24696 B

    const unsigned int* csrc = (const unsigned int*)(c1 + (size_t)m0 * 6048);
    for (int i = tid; i < 6048; i += 256) {
        unsigned v = csrc[i];
        int e0 = 2 * i;
        int mi = (i >= 3024);
        int r0 = e0 - mi * 6048, r1 = r0 + 1;
        int o0 = r0 / 63, p0 = r0 - o0 * 63;
        int o1 = r1 / 63, p1 = r1 - o1 * 63;
        c1T[(mi * 63 + p0) * C2S + o0] = (unsigned short)(v & 0xFFFFu);
        c1T[(mi * 63 + p1) * C2S + o1] = (unsigned short)(v >> 16);
    }
    __syncthreads();

    const int wv = tid >> 6, lane = tid & 63;
    const int quad = lane >> 4, ncol = lane & 15;
    const int arow = lane & 15;
    const int mi = (arow < 10) ? arow / 5 : 1;
    const int zo = (arow < 10) ? arow % 5 : 4;

    f32x4 acc[2];
    acc[0] = (f32x4){0.f, 0.f, 0.f, 0.f};
    acc[1] = (f32x4){0.f, 0.f, 0.f, 0.f};
    const uint4* Bptr = (const uint4*)w2n;

    for (int tap = 0; tap < 27; ++tap) {
        const int dz = tap / 9, r9 = tap % 9;
        const int rowb = (mi * 63 + (zo + dz) * 9 + r9) * C2S;
        #pragma unroll
        for (int sub = 0; sub < 3; ++sub) {
            const int s = tap * 3 + sub;
            const unsigned int* ap =
                (const unsigned int*)(c1T + rowb + sub * 32 + quad * 8);
            uint4 au; au.x = ap[0]; au.y = ap[1]; au.z = ap[2]; au.w = ap[3];
            bf16x8 af = __builtin_bit_cast(bf16x8, au);
            #pragma unroll
            for (int nt = 0; nt < 2; ++nt) {
                uint4 bu = Bptr[(s * 8 + wv * 2 + nt) * 64 + lane];
                bf16x8 bf = __builtin_bit_cast(bf16x8, bu);
                acc[nt] = __builtin_amdgcn_mfma_f32_16x16x32_bf16(af, bf, acc[nt], 0, 0, 0);
            }
        }
    }

    #pragma unroll
    for (int nt = 0; nt < 2; ++nt) {
        const int o = (wv * 2 + nt) * 16 + ncol;
        const float bias = b2[o];
        #pragma unroll
        for (int reg = 0; reg < 4; ++reg) {
            int rr = quad * 4 + reg;
            if (rr < 10) {
                int mg = m0 + rr / 5;
                out[mg * 640 + o * 5 + (rr % 5)] =
                    fmaxf(acc[nt][reg] + bias, 0.0f);
            }
        }
    }
}

// ---------------------------------------------------------------- conv3 + xwi
__global__ __launch_bounds__(256) void k_c3x(
    const float* __restrict__ c2, const float* __restrict__ w3t,
    const float* __restrict__ b3, const float* __restrict__ wi,
    const float* __restrict__ lb, float* __restrict__ xwi)
{
    const int tid = threadIdx.x;
    const int m = blockIdx.x;
    __shared__ float inb[640];
    __shared__ float part[4][64];
    __shared__ float vvl[64];

    for (int i = tid; i < 640; i += 256) inb[i] = c2[m * 640 + i];
    __syncthreads();

    const int u = tid & 63, kq = tid >> 6;
    float acc = 0.0f;
    const int k0 = kq * 160;
    #pragma unroll 8
    for (int k = k0; k < k0 + 160; ++k)
        acc = fmaf(inb[k], w3t[k * 64 + u], acc);
    part[kq][u] = acc;
    __syncthreads();

    if (tid < 64)
        vvl[tid] = b3[tid] + ((part[0][tid] + part[1][tid])
                 + (part[2][tid] + part[3][tid]));
    __syncthreads();

    float a2 = lb[tid];
    #pragma unroll
    for (int k = 0; k < 64; ++k)
        a2 = fmaf(vvl[k], wi[k * 256 + tid], a2);
    xwi[m * 256 + tid] = a2;
}

// ---------------------------------------------------------------- LSTM
// h broadcast via float4 reads (16 LDS instr/step instead of 64); barriers
// separate the float stores from float4 reads (type-punned LDS).
__global__ __launch_bounds__(256) void k_lstm(
    const float* __restrict__ xwi, const float* __restrict__ whg,
    const float* __restrict__ h0, const float* __restrict__ c0,
    float* __restrict__ avec, float* __restrict__ hn, float* __restrict__ cn)
{
    const int b = blockIdx.x;
    const int j = threadIdx.x;
    __shared__ __align__(16) float hbuf[64];
    __shared__ float gbuf[256];

    float wh[64];
    #pragma unroll
    for (int k = 0; k < 64; ++k) wh[k] = whg[k * 256 + j];

    if (j < 64) hbuf[j] = h0[b * 64 + j];
    float c = (j < 64) ? c0[b * 64 + j] : 0.0f;
    __syncthreads();

    const float4* hb4 = (const float4*)hbuf;
    for (int t = 0; t < 64; ++t) {
        float g = xwi[(b * 64 + t) * 256 + j];
        #pragma unroll
        for (int k4 = 0; k4 < 16; ++k4) {
            float4 h4 = hb4[k4];
            g = fmaf(h4.x, wh[4 * k4 + 0], g);
            g = fmaf(h4.y, wh[4 * k4 + 1], g);
            g = fmaf(h4.z, wh[4 * k4 + 2], g);
            g = fmaf(h4.w, wh[4 * k4 + 3], g);
        }
        gbuf[j] = g;
        __syncthreads();
        if (j < 64) {
            float gi = gbuf[j], gf = gbuf[64 + j], gg = gbuf[128 + j], go = gbuf[192 + j];
            c = sigm(gf) * c + sigm(gi) * tanhf(gg);
            float h = sigm(go) * tanhf(c);
            hbuf[j] = h;
            avec[(b * 64 + t) * 64 + j] = h;
        }
        __syncthreads();
    }
    if (j < 64) {
        hn[b * 64 + j] = hbuf[j];
        cn[b * 64 + j] = c;
    }
}

// ---------------------------------------------------------------- launch
extern "C" void kernel_launch(void* const* d_in, const int* in_sizes, int n_in,
                              void* d_out, int out_size, void* d_ws, size_t ws_size,
                              hipStream_t stream) {
    const float* x     = (const float*)d_in[0];
    const float* g_loc = (const float*)d_in[1];
    const float* h0    = (const float*)d_in[2];
    const float* c0    = (const float*)d_in[3];
    const float* pn_w1 = (const float*)d_in[4];
    const float* pn_b1 = (const float*)d_in[5];
    const float* pn_w2 = (const float*)d_in[6];
    const float* pn_b2 = (const float*)d_in[7];
    const float* pn_w3 = (const float*)d_in[8];
    const float* pn_b3 = (const float*)d_in[9];
    const float* aw    = (const float*)d_in[10];
    const float* ab    = (const float*)d_in[11];
    const float* vx_w1 = (const float*)d_in[12];
    const float* vx_b1 = (const float*)d_in[13];
    const float* vx_w2 = (const float*)d_in[14];
    const float* vx_b2 = (const float*)d_in[15];
    const float* vx_w3 = (const float*)d_in[16];
    const float* vx_b3 = (const float*)d_in[17];
    const float* lwi   = (const float*)d_in[18];
    const float* lwh   = (const float*)d_in[19];
    const float* lb    = (const float*)d_in[20];

    float* ws  = (float*)d_ws;
    float* voxr = ws;
    float* c1r  = voxr + SZ_VOX;
    float* c2  = c1r + SZ_C1;
    float* vv  = c2 + SZ_C2;          // unused (layout stability)
    float* xwi = vv + SZ_VV;
    float* w1r = xwi + SZ_XWI;
    float* w2r = w1r + SZ_W1T;
    float* w3t = w2r + SZ_W2T;
    float* w2mr = w3t + SZ_W3T;
    unsigned short* voxh = (unsigned short*)voxr;
    unsigned short* c1h  = (unsigned short*)c1r;
    unsigned short* w1m = (unsigned short*)w1r;
    unsigned short* w2n = (unsigned short*)w2r;
    unsigned short* w2m = (unsigned short*)w2mr;
    unsigned short* w3m = (unsigned short*)xwi;  // aliases xwi head; xwi written later
    int*   idxb = (int*)c1r;          // idx lives in the (not-yet-written) c1 region

    float* out   = (float*)d_out;
    float* avec  = out;                   // 65536
    float* attnw = out + 65536;           // 1843200
    float* hn    = out + 65536 + 1843200; // 1024
    float* cn    = hn + 1024;             // 1024

    k_transpose<<<405, 256, 0, stream>>>(vx_w1, vx_w2, vx_w3, pn_w3, pn_w2,
                                         w1m, w2n, w3t, w3m, w2m);
    k_group<<<1024, 256, 0, stream>>>(x, g_loc, idxb);
    k_mlpm<<<14400, 128, 0, stream>>>(x, g_loc, idxb, pn_w1, pn_b1, w2m, pn_b2,
                                      w3m, pn_b3, aw, ab, voxh, attnw);
    k_conv1m<<<1024, 256, 0, stream>>>(voxh, w1m, vx_b1, c1h);
    k_conv2m<<<512, 256, 0, stream>>>(c1h, w2n, vx_b2, c2);
    k_c3x<<<1024, 256, 0, stream>>>(c2, w3t, vx_b3, lwi, lb, xwi);
    k_lstm<<<16, 256, 0, stream>>>(xwi, lwh, h0, c0, avec, hn, cn);
}

// Round 10
// 358.038 us; speedup vs baseline: 2.3884x; 1.0568x over previous
//
#include <hip/hip_runtime.h>
#include <cmath>

// Shapes (fixed by the problem)
#define AT 225      // Z*Y*X anchors
#define NP 128      // points per sample
#define MT 1024     // B*T
#define NSEL 8
#define HD 64

// workspace float offsets
#define SZ_VOX  (1024u*64u*225u)     // region sized in floats; holds bf16 vox
#define SZ_C1   (1024u*96u*63u)      // region holds bf16 c1 (idx aliases head before conv1)
#define SZ_C2   (1024u*128u*5u)
#define SZ_VV   (1024u*64u)
#define SZ_XWI  (1024u*256u)         // (w3m aliases its head before k_c3x runs)
#define SZ_W1T  (64u*27u*96u)        // holds w1m (bf16 A-frags, conv1)
#define SZ_W2T  (96u*27u*128u)       // holds w2n (bf16 B-frags, conv2)
#define SZ_W3T  (640u*64u)
#define SZ_W2M  (512u)               // pn layer2 B-frags (128 uint4)

#define C2S 98                       // conv2 LDS row stride (us), 49 dw (odd)

typedef __attribute__((ext_vector_type(8))) short bf16x8;
typedef __attribute__((ext_vector_type(4))) float f32x4;

__device__ __forceinline__ float sigm(float x) { return 1.0f / (1.0f + expf(-x)); }

__device__ __forceinline__ unsigned short f2bf(float f) {
    unsigned u = __float_as_uint(f);
    unsigned r = u + 0x7FFF + ((u >> 16) & 1);   // RNE
    return (unsigned short)(r >> 16);
}

#if defined(__has_builtin)
#if __has_builtin(__builtin_amdgcn_cvt_pk_bf16_f32)
#define HAVE_CVT_PK_BF16 1
#endif
#endif

__device__ __forceinline__ unsigned pk2(float a, float b) {
#ifdef HAVE_CVT_PK_BF16
    auto v = __builtin_amdgcn_cvt_pk_bf16_f32(a, b);
    return __builtin_bit_cast(unsigned, v);
#else
    return (unsigned)f2bf(a) | ((unsigned)f2bf(b) << 16);
#endif
}

// ---------------------------------------------------------------- transpose
__global__ __launch_bounds__(256) void k_transpose(
    const float* __restrict__ w1, const float* __restrict__ w2,
    const float* __restrict__ w3, const float* __restrict__ pnw3,
    const float* __restrict__ pnw2,
    unsigned short* __restrict__ w1m, unsigned short* __restrict__ w2n,
    float* __restrict__ w3t, unsigned short* __restrict__ w3m,
    unsigned short* __restrict__ w2m)
{
    int idx = blockIdx.x * 256 + threadIdx.x;
    if (idx < 20736) {
        int lane = idx & 63, r = idx >> 6;
        int t = r % 6, s = r / 6;
        int o = t * 16 + (lane & 15);
        int kb = s * 32 + (lane >> 4) * 8;
        unsigned int dw[4];
        #pragma unroll
        for (int jd = 0; jd < 4; ++jd) {
            int k0 = kb + 2 * jd, k1 = k0 + 1;
            dw[jd] = (unsigned)f2bf(w1[o * 1728 + (k0 & 63) * 27 + (k0 >> 6)]) |
                     ((unsigned)f2bf(w1[o * 1728 + (k1 & 63) * 27 + (k1 >> 6)]) << 16);
        }
        uint4 v; v.x = dw[0]; v.y = dw[1]; v.z = dw[2]; v.w = dw[3];
        ((uint4*)w1m)[idx] = v;
    } else if (idx < 62208) {
        int q = idx - 20736;
        int lane = q & 63, r = q >> 6;
        int nt = r & 7, s = r >> 3;
        int o = nt * 16 + (lane & 15);
        int kb = s * 32 + (lane >> 4) * 8;
        unsigned int dw[4];
        #pragma unroll
        for (int jd = 0; jd < 4; ++jd) {
            int k0 = kb + 2 * jd, k1 = k0 + 1;
            dw[jd] = (unsigned)f2bf(w2[o * 2592 + (k0 % 96) * 27 + (k0 / 96)]) |
                     ((unsigned)f2bf(w2[o * 2592 + (k1 % 96) * 27 + (k1 / 96)]) << 16);
        }
        uint4 v; v.x = dw[0]; v.y = dw[1]; v.z = dw[2]; v.w = dw[3];
        ((uint4*)w2n)[q] = v;
    } else if (idx < 103168) {
        int k = idx - 62208;
        int u = k & 63, r = k >> 6;
        w3t[k] = w3[u * 640 + r];
    } else if (idx < 103424) {
        int k = idx - 103168;
        int lane = k & 63, nt = k >> 6;
        int n = nt * 16 + (lane & 15);
        int kb = (lane >> 4) * 8;
        unsigned int dw[4];
        #pragma unroll
        for (int jd = 0; jd < 4; ++jd) {
            int k0 = kb + 2 * jd;
            dw[jd] = (unsigned)f2bf(pnw3[k0 * 64 + n]) |
                     ((unsigned)f2bf(pnw3[(k0 + 1) * 64 + n]) << 16);
        }
        uint4 v; v.x = dw[0]; v.y = dw[1]; v.z = dw[2]; v.w = dw[3];
        ((uint4*)w3m)[k] = v;
    } else if (idx < 103552) {
        int k = idx - 103424;
        int lane = k & 63, nt = k >> 6;          // nt 0..1
        int n = nt * 16 + (lane & 15);
        int kb = (lane >> 4) * 8;
        unsigned int dw[4];
        #pragma unroll
        for (int jd = 0; jd < 4; ++jd) {
            int k0 = kb + 2 * jd, k1 = k0 + 1;
            float a = (k0 < 16) ? pnw2[k0 * 32 + n] : 0.0f;
            float b = (k1 < 16) ? pnw2[k1 * 32 + n] : 0.0f;
            dw[jd] = (unsigned)f2bf(a) | ((unsigned)f2bf(b) << 16);
        }
        uint4 v; v.x = dw[0]; v.y = dw[1]; v.z = dw[2]; v.w = dw[3];
        ((uint4*)w2m)[k] = v;
    }
}

// ---------------------------------------------------------------- grouping
__global__ __launch_bounds__(256) void k_group(
    const float* __restrict__ x, const float* __restrict__ g_loc,
    int* __restrict__ idxbuf)
{
    const int m = blockIdx.x;
    const int tid = threadIdx.x;
    __shared__ float pts[3][NP];

    for (int idx = tid; idx < NP * 5; idx += 256) {
        int n = idx / 5, c = idx % 5;
        if (c < 3) pts[c][n] = x[m * (NP * 5) + idx];
    }
    __syncthreads();

    const float gx = g_loc[m * 2 + 0], gy = g_loc[m * 2 + 1];
    const int grp = tid >> 3, li = tid & 7;

    for (int ca = 0; ca < 256; ca += 32) {
        const int a = ca + grp;
        const bool active = (a < AT);
        const int aa = active ? a : (AT - 1);
        const int azi = aa / 25, ar = aa % 25, ayi = ar / 5, axi = ar % 5;
        const float fx = ((float)axi - 2.0f) * 0.2f + gx;
        const float fy = ((float)ayi - 2.0f) * 0.2f + gy;
        const float fz = (float)azi * 0.22f + 0.1f;
        const float sa = fx * fx + fy * fy + fz * fz;

        float d[16];
        #pragma unroll
        for (int r = 0; r < 16; ++r) {
            int n = li * 16 + r;
            float px = pts[0][n], py = pts[1][n], pz = pts[2][n];
            d[r] = sa - 2.0f * (fx * px + fy * py + fz * pz)
                      + (px * px + py * py + pz * pz);
        }
        int nidx = 0;
        for (int j = 0; j < NSEL; ++j) {
            float best = 1e30f; int bidx = 0;
            #pragma unroll
            for (int r = 0; r < 16; ++r) {
                int n = li * 16 + r;
                if (d[r] < best) { best = d[r]; bidx = n; }
            }
            #pragma unroll
            for (int off = 1; off < 8; off <<= 1) {
                float ov = __shfl_xor(best, off);
                int   oi = __shfl_xor(bidx, off);
                if (ov < best || (ov == best && oi < bidx)) { best = ov; bidx = oi; }
            }
            if (li == j) nidx = bidx;
            if ((bidx >> 4) == li) {
                int slot = bidx & 15;
                #pragma unroll
                for (int r = 0; r < 16; ++r)
                    if (r == slot) d[r] = 1e30f;
            }
        }
        if (active) idxbuf[(m * AT + a) * NSEL + li] = nidx;
    }
}

// ---------------------------------------------------------------- MLP (MFMA L2+L3)
// LDS aliasing (all transitions barrier-separated; punned ushort/uint access
// REQUIRES those barriers — see R6 failure):
//   [0,8704)      fbuf (f1 then f2)  ... sbuf (4160 B) aliases head in phase C
//   [8704,25600)  f3us (16896 B)     ... pts (5120 B, raw x-layout) aliases head
__global__ __launch_bounds__(128) void k_mlpm(
    const float* __restrict__ x, const float* __restrict__ g_loc,
    const int* __restrict__ idxbuf,
    const float* __restrict__ w1, const float* __restrict__ b1,
    const unsigned short* __restrict__ w2m, const float* __restrict__ b2,
    const unsigned short* __restrict__ w3m, const float* __restrict__ b3,
    const float* __restrict__ aw, const float* __restrict__ ab,
    unsigned short* __restrict__ vox, float* __restrict__ attn_out)
{
    const int tid = threadIdx.x;
    const int row0 = blockIdx.x * 128;
    const int row = row0 + tid;

    __shared__ __align__(16) char smem[25600];
    unsigned int*   fbuf = (unsigned int*)smem;              // 8704 B
    unsigned short* f3us = (unsigned short*)(smem + 8704);   // 16896 B
    float*          pts  = (float*)(smem + 8704);            // aliases f3us head
    float*          sbuf = (float*)smem;                     // aliases fbuf head

    const int m0 = row0 / 1800;
    const int m1 = (row0 + 127) / 1800;
    #pragma unroll
    for (int i = tid; i < 640; i += 128) {
        pts[i]       = x[m0 * 640 + i];
        pts[640 + i] = x[m1 * 640 + i];
    }
    __syncthreads();

    // ---- phase A: layer 1 per-thread, pack f1 to fbuf (K 16..31 zeroed) ----
    const int m = row / 1800;
    const int rr = row % 1800;
    const int a = rr >> 3;
    const int base = (m == m0) ? 0 : 640;

    const int azi = a / 25, ar = a % 25, ayi = ar / 5, axi = ar % 5;
    const float gx = g_loc[m * 2 + 0], gy = g_loc[m * 2 + 1];
    const float fx = ((float)axi - 2.0f) * 0.2f + gx;
    const float fy = ((float)ayi - 2.0f) * 0.2f + gy;
    const float fz = (float)azi * 0.22f + 0.1f;

    const int nidx = idxbuf[row];
    const float in0 = pts[base + nidx * 5 + 0] - fx;
    const float in1 = pts[base + nidx * 5 + 1] - fy;
    const float in2 = pts[base + nidx * 5 + 2] - fz;
    const float in3 = pts[base + nidx * 5 + 3];
    const float in4 = pts[base + nidx * 5 + 4];

    float f1v[16];
    #pragma unroll
    for (int j = 0; j < 16; ++j) {
        float s = b1[j];
        s += in0 * w1[0 * 16 + j] + in1 * w1[1 * 16 + j] + in2 * w1[2 * 16 + j]
           + in3 * w1[3 * 16 + j] + in4 * w1[4 * 16 + j];
        f1v[j] = fmaxf(s, 0.0f);
    }
    __syncthreads();   // pts reads complete before fbuf/f3us reuse
    #pragma unroll
    for (int kd = 0; kd < 8; ++kd)
        fbuf[tid * 17 + kd] = pk2(f1v[2 * kd], f1v[2 * kd + 1]);
    #pragma unroll
    for (int kd = 8; kd < 16; ++kd)
        fbuf[tid * 17 + kd] = 0u;
    __syncthreads();

    // ---- phase B: MFMA layers ----
    const int wv = tid >> 6, lane = tid & 63;
    const int quad = lane >> 4, mcol = lane & 15;
    unsigned short* fus = (unsigned short*)fbuf;   // row stride 34 us

    // layer 2: D[128 rows][32] = f1 @ w2 (K=32 padded)
    bf16x8 w2f[2];
    #pragma unroll
    for (int nt = 0; nt < 2; ++nt) {
        uint4 u = ((const uint4*)w2m)[nt * 64 + lane];
        w2f[nt] = __builtin_bit_cast(bf16x8, u);
    }
    float b2v[2] = { b2[mcol], b2[16 + mcol] };

    #pragma unroll
    for (int mt = 0; mt < 4; ++mt) {
        const int rowbase = (wv * 4 + mt) * 16;
        const int abase = (rowbase + mcol) * 17 + quad * 4;
        uint4 au;
        au.x = fbuf[abase + 0]; au.y = fbuf[abase + 1];
        au.z = fbuf[abase + 2]; au.w = fbuf[abase + 3];
        bf16x8 af = __builtin_bit_cast(bf16x8, au);
        #pragma unroll
        for (int nt = 0; nt < 2; ++nt) {
            f32x4 z = (f32x4){0.f, 0.f, 0.f, 0.f};
            f32x4 acc = __builtin_amdgcn_mfma_f32_16x16x32_bf16(af, w2f[nt], z, 0, 0, 0);
            #pragma unroll
            for (int reg = 0; reg < 4; ++reg) {
                float v = fmaxf(acc[reg] + b2v[nt], 0.0f);
                fus[(rowbase + quad * 4 + reg) * 34 + nt * 16 + mcol] = f2bf(v);
            }
        }
    }
    __syncthreads();   // fence: ushort f2 stores -> uint A-frag loads (L3)

    // layer 3: D[128 rows][64] = f2 @ w3
    bf16x8 w3f[4];
    #pragma unroll
    for (int nt = 0; nt < 4; ++nt) {
        uint4 u = ((const uint4*)w3m)[nt * 64 + lane];
        w3f[nt] = __builtin_bit_cast(bf16x8, u);
    }
    float b3v[4];
    #pragma unroll
    for (int nt = 0; nt < 4; ++nt) b3v[nt] = b3[nt * 16 + mcol];

    #pragma unroll
    for (int mt = 0; mt < 4; ++mt) {
        const int rowbase = (wv * 4 + mt) * 16;
        const int abase = (rowbase + mcol) * 17 + quad * 4;
        uint4 au;
        au.x = fbuf[abase + 0]; au.y = fbuf[abase + 1];
        au.z = fbuf[abase + 2]; au.w = fbuf[abase + 3];
        bf16x8 af = __builtin_bit_cast(bf16x8, au);
        #pragma unroll
        for (int nt = 0; nt < 4; ++nt) {
            f32x4 z = (f32x4){0.f, 0.f, 0.f, 0.f};
            f32x4 acc = __builtin_amdgcn_mfma_f32_16x16x32_bf16(af, w3f[nt], z, 0, 0, 0);
            #pragma unroll
            for (int reg = 0; reg < 4; ++reg) {
                float v = fmaxf(acc[reg] + b3v[nt], 0.0f);
                f3us[(rowbase + quad * 4 + reg) * 66 + nt * 16 + mcol] = f2bf(v);
            }
        }
    }
    __syncthreads();   // fence: ushort f3 stores -> uint phase-C loads

    // ---- phase C: score, softmax, weighted sum ----
    const unsigned int* f3dw = (const unsigned int*)f3us;   // row stride 33 dw
    float s0 = 0.f, s1 = 0.f;
    #pragma unroll
    for (int kd = 0; kd < 32; ++kd) {
        unsigned dw = f3dw[tid * 33 + kd];
        s0 = fmaf(__uint_as_float(dw << 16), aw[2 * kd], s0);
        s1 = fmaf(__uint_as_float(dw & 0xFFFF0000u), aw[2 * kd + 1], s1);
    }
    float sc = s0 + s1 + ab[0];

    float mx = sc;
    #pragma unroll
    for (int off = 1; off < 8; off <<= 1) mx = fmaxf(mx, __shfl_xor(mx, off));
    float e = expf(sc - mx);
    float den = e;
    #pragma unroll
    for (int off = 1; off < 8; off <<= 1) den += __shfl_xor(den, off);
    const float at = e / den;
    attn_out[row] = at;

    // lane li owns h = q*16 + li*2 + {0,1}  (conflict-free b32 reads)
    const int lgrp = tid >> 3;
    const int li = tid & 7;
    const int wl = tid & 63;
    float oo[8];
    #pragma unroll
    for (int i = 0; i < 8; ++i) oo[i] = 0.0f;
    #pragma unroll
    for (int ns = 0; ns < 8; ++ns) {
        float atn = __shfl(at, (wl >> 3) * 8 + ns);
        const int rbase = (lgrp * 8 + ns) * 33;
        #pragma unroll
        for (int q = 0; q < 4; ++q) {
            unsigned dw = f3dw[rbase + q * 8 + li];
            oo[2 * q + 0] = fmaf(atn, __uint_as_float(dw << 16), oo[2 * q + 0]);
            oo[2 * q + 1] = fmaf(atn, __uint_as_float(dw & 0xFFFF0000u), oo[2 * q + 1]);
        }
    }
    __syncthreads();   // fence: fbuf A-frag loads done -> sbuf (alias) writes
    #pragma unroll
    for (int q = 0; q < 4; ++q) {
        sbuf[lgrp * 65 + q * 16 + li * 2 + 0] = oo[2 * q + 0];
        sbuf[lgrp * 65 + q * 16 + li * 2 + 1] = oo[2 * q + 1];
    }
    __syncthreads();

    const int al = tid & 15, j = tid >> 4;
    const int ga = (row0 >> 3) + al;
    const int ma = ga / 225, aa2 = ga % 225;
    #pragma unroll
    for (int rep = 0; rep < 8; ++rep) {
        int h = j * 8 + rep;
        vox[(ma * 64 + h) * AT + aa2] = f2bf(sbuf[al * 65 + h]);
    }
}

// ---------------------------------------------------------------- conv1 MFMA
// 2 images per block: A-frags (global/L2 stream) loaded ONCE per K-step and
// used for both images (12 MFMA / 6 A-loads) -> halves the 1.3 GB A-traffic.
// LDS 59.4 KB -> 2 blocks/CU; grid 512 = exactly 2 blocks/CU.
__global__ __launch_bounds__(256) void k_conv1m(
    const unsigned short* __restrict__ vox, const unsigned short* __restrict__ w1m,
    const float* __restrict__ b1, unsigned short* __restrict__ out)
{
    const int m0 = blockIdx.x * 2;
    const int tid = threadIdx.x;
    __shared__ unsigned short voxT[2][225 * 66];

    #pragma unroll
    for (int img = 0; img < 2; ++img) {
        const unsigned int* vsrc =
            (const unsigned int*)(vox + (size_t)(m0 + img) * 14400);
        for (int i = tid; i < 7200; i += 256) {
            unsigned v = vsrc[i];
            int e0 = 2 * i, e1 = e0 + 1;
            int c0 = e0 / 225, a0 = e0 - c0 * 225;
            int c1i = e1 / 225, a1 = e1 - c1i * 225;
            voxT[img][a0 * 66 + c0] = (unsigned short)(v & 0xFFFFu);
            voxT[img][a1 * 66 + c1i] = (unsigned short)(v >> 16);
        }
    }
    __syncthreads();

    const int wv = tid >> 6, lane = tid & 63;
    const int quad = lane >> 4, n = lane & 15;
    const int p = wv * 16 + n;
    const int pe = (p > 62) ? 62 : p;
    const int zo = pe / 9, pr = pe % 9, yo = pr / 3, xo = pr % 3;
    const int basep = zo * 25 + yo * 5 + xo;

    f32x4 acc[2][6];
    #pragma unroll
    for (int g = 0; g < 2; ++g)
        #pragma unroll
        for (int t = 0; t < 6; ++t) acc[g][t] = (f32x4){0.f, 0.f, 0.f, 0.f};

    const uint4* Aptr = (const uint4*)w1m;

    auto loadB = [&](int img, int s) -> uint4 {
        int tap = s >> 1;
        int dz = tap / 9, tr = tap % 9, dy = tr / 3, dx = tr % 3;
        int rw = basep + dz * 25 + dy * 5 + dx;
        int bidx = rw * 66 + (s & 1) * 32 + quad * 8;
        const unsigned int* vp = (const unsigned int*)(&voxT[img][0] + bidx);
        uint4 r; r.x = vp[0]; r.y = vp[1]; r.z = vp[2]; r.w = vp[3];
        return r;
    };

    uint4 Acur[6], Anxt[6];
    uint4 Bcur[2], Bnxt[2];
    #pragma unroll
    for (int t = 0; t < 6; ++t) Acur[t] = Aptr[t * 64 + lane];
    Bcur[0] = loadB(0, 0); Bcur[1] = loadB(1, 0);

    for (int s = 0; s < 54; ++s) {
        if (s < 53) {
            Bnxt[0] = loadB(0, s + 1);
            Bnxt[1] = loadB(1, s + 1);
            #pragma unroll
            for (int t = 0; t < 6; ++t)
                Anxt[t] = Aptr[((s + 1) * 6 + t) * 64 + lane];
        }
        bf16x8 bf0 = __builtin_bit_cast(bf16x8, Bcur[0]);
        bf16x8 bf1 = __builtin_bit_cast(bf16x8, Bcur[1]);
        #pragma unroll
        for (int t = 0; t < 6; ++t) {
            bf16x8 af = __builtin_bit_cast(bf16x8, Acur[t]);
            acc[0][t] = __builtin_amdgcn_mfma_f32_16x16x32_bf16(af, bf0, acc[0][t], 0, 0, 0);
            acc[1][t] = __builtin_amdgcn_mfma_f32_16x16x32_bf16(af, bf1, acc[1][t], 0, 0, 0);
        }
        #pragma unroll
        for (int t = 0; t < 6; ++t) Acur[t] = Anxt[t];
        Bcur[0] = Bnxt[0]; Bcur[1] = Bnxt[1];
    }

    if (p < 63) {
        #pragma unroll
        for (int g = 0; g < 2; ++g) {
            #pragma unroll
            for (int t = 0; t < 6; ++t) {
                #pragma unroll
                for (int r = 0; r < 4; ++r) {
                    int o = t * 16 + quad * 4 + r;
                    out[(m0 + g) * (96 * 63) + o * 63 + p] =
                        f2bf(fmaxf(acc[g][t][r] + b1[o], 0.0f));
                }
            }
        }
    }
}

// ---------------------------------------------------------------- conv2 MFMA
__global__ __launch_bounds__(256) void k_conv2m(
    const unsigned short* __restrict__ c1, const unsigned short* __restrict__ w2n,
    const float* __restrict__ b2, float* __restrict__ out)
{
    const int tid = threadIdx.x;
    const int m0 = blockIdx.x * 2;
    __shared__ unsigned short c1T[2 * 63 * C2S];   // 24696 B

    const unsigned int* csrc = (const unsigned int*)(c1 + (size_t)m0 * 6048);
    for (int i = tid; i < 6048; i += 256) {
        unsigned v = csrc[i];
        int e0 = 2 * i;
        int mi = (i >= 3024);
        int r0 = e0 - mi * 6048, r1 = r0 + 1;
        int o0 = r0 / 63, p0 = r0 - o0 * 63;
        int o1 = r1 / 63, p1 = r1 - o1 * 63;
        c1T[(mi * 63 + p0) * C2S + o0] = (unsigned short)(v & 0xFFFFu);
        c1T[(mi * 63 + p1) * C2S + o1] = (unsigned short)(v >> 16);
    }
    __syncthreads();

    const int wv = tid >> 6, lane = tid & 63;
    const int quad = lane >> 4, ncol = lane & 15;
    const int arow = lane & 15;
    const int mi = (arow < 10) ? arow / 5 : 1;
    const int zo = (arow < 10) ? arow % 5 : 4;

    f32x4 acc[2];
    acc[0] = (f32x4){0.f, 0.f, 0.f, 0.f};
    acc[1] = (f32x4){0.f, 0.f, 0.f, 0.f};
    const uint4* Bptr = (const uint4*)w2n;

    for (int tap = 0; tap < 27; ++tap) {
        const int dz = tap / 9, r9 = tap % 9;
        const int rowb = (mi * 63 + (zo + dz) * 9 + r9) * C2S;
        #pragma unroll
        for (int sub = 0; sub < 3; ++sub) {
            const int s = tap * 3 + sub;
            const unsigned int* ap =
                (const unsigned int*)(c1T + rowb + sub * 32 + quad * 8);
            uint4 au; au.x = ap[0]; au.y = ap[1]; au.z = ap[2]; au.w = ap[3];
            bf16x8 af = __builtin_bit_cast(bf16x8, au);
            #pragma unroll
            for (int nt = 0; nt < 2; ++nt) {
                uint4 bu = Bptr[(s * 8 + wv * 2 + nt) * 64 + lane];
                bf16x8 bf = __builtin_bit_cast(bf16x8, bu);
                acc[nt] = __builtin_amdgcn_mfma_f32_16x16x32_bf16(af, bf, acc[nt], 0, 0, 0);
            }
        }
    }

    #pragma unroll
    for (int nt = 0; nt < 2; ++nt) {
        const int o = (wv * 2 + nt) * 16 + ncol;
        const float bias = b2[o];
        #pragma unroll
        for (int reg = 0; reg < 4; ++reg) {
            int rr = quad * 4 + reg;
            if (rr < 10) {
                int mg = m0 + rr / 5;
                out[mg * 640 + o * 5 + (rr % 5)] =
                    fmaxf(acc[nt][reg] + bias, 0.0f);
            }
        }
    }
}

// ---------------------------------------------------------------- conv3 + xwi
__global__ __launch_bounds__(256) void k_c3x(
    const float* __restrict__ c2, const float* __restrict__ w3t,
    const float* __restrict__ b3, const float* __restrict__ wi,
    const float* __restrict__ lb, float* __restrict__ xwi)
{
    const int tid = threadIdx.x;
    const int m = blockIdx.x;
    __shared__ float inb[640];
    __shared__ float part[4][64];
    __shared__ float vvl[64];

    for (int i = tid; i < 640; i += 256) inb[i] = c2[m * 640 + i];
    __syncthreads();

    const int u = tid & 63, kq = tid >> 6;
    float acc = 0.0f;
    const int k0 = kq * 160;
    #pragma unroll 8
    for (int k = k0; k < k0 + 160; ++k)
        acc = fmaf(inb[k], w3t[k * 64 + u], acc);
    part[kq][u] = acc;
    __syncthreads();

    if (tid < 64)
        vvl[tid] = b3[tid] + ((part[0][tid] + part[1][tid])
                 + (part[2][tid] + part[3][tid]));
    __syncthreads();

    float a2 = lb[tid];
    #pragma unroll
    for (int k = 0; k < 64; ++k)
        a2 = fmaf(vvl[k], wi[k * 256 + tid], a2);
    xwi[m * 256 + tid] = a2;
}

// ---------------------------------------------------------------- LSTM
// Dependency-chain fixes: (1) 4 independent partial accumulators for the
// 64-FMA h.Wh dot (chain 256 -> ~64 cyc); (2) each of the 256 threads applies
// its own gate's activation (i/f/o: sigm, g: tanh) BEFORE the barrier, so the
// serial 64-thread tail keeps only tanh(c).
__global__ __launch_bounds__(256) void k_lstm(
    const float* __restrict__ xwi, const float* __restrict__ whg,
    const float* __restrict__ h0, const float* __restrict__ c0,
    float* __restrict__ avec, float* __restrict__ hn, float* __restrict__ cn)
{
    const int b = blockIdx.x;
    const int j = threadIdx.x;
    __shared__ __align__(16) float hbuf[64];
    __shared__ float gbuf[256];

    float wh[64];
    #pragma unroll
    for (int k = 0; k < 64; ++k) wh[k] = whg[k * 256 + j];

    if (j < 64) hbuf[j] = h0[b * 64 + j];
    float c = (j < 64) ? c0[b * 64 + j] : 0.0f;
    const bool is_tanh_gate = ((j >> 6) == 2);
    __syncthreads();

    const float4* hb4 = (const float4*)hbuf;
    for (int t = 0; t < 64; ++t) {
        float g = xwi[(b * 64 + t) * 256 + j];
        float p[4] = {0.f, 0.f, 0.f, 0.f};
        #pragma unroll
        for (int k4 = 0; k4 < 16; ++k4) {
            float4 h4 = hb4[k4];
            int q = k4 & 3;
            p[q] = fmaf(h4.x, wh[4 * k4 + 0], p[q]);
            p[q] = fmaf(h4.y, wh[4 * k4 + 1], p[q]);
            p[q] = fmaf(h4.z, wh[4 * k4 + 2], p[q]);
            p[q] = fmaf(h4.w, wh[4 * k4 + 3], p[q]);
        }
        g += (p[0] + p[1]) + (p[2] + p[3]);
        gbuf[j] = is_tanh_gate ? tanhf(g) : sigm(g);
        __syncthreads();
        if (j < 64) {
            c = gbuf[64 + j] * c + gbuf[j] * gbuf[128 + j];
            float h = gbuf[192 + j] * tanhf(c);
            hbuf[j] = h;
            avec[(b * 64 + t) * 64 + j] = h;
        }
        __syncthreads();
    }
    if (j < 64) {
        hn[b * 64 + j] = hbuf[j];
        cn[b * 64 + j] = c;
    }
}

// ---------------------------------------------------------------- launch
extern "C" void kernel_launch(void* const* d_in, const int* in_sizes, int n_in,
                              void* d_out, int out_size, void* d_ws, size_t ws_size,
                              hipStream_t stream) {
    const float* x     = (const float*)d_in[0];
    const float* g_loc = (const float*)d_in[1];
    const float* h0    = (const float*)d_in[2];
    const float* c0    = (const float*)d_in[3];
    const float* pn_w1 = (const float*)d_in[4];
    const float* pn_b1 = (const float*)d_in[5];
    const float* pn_w2 = (const float*)d_in[6];
    const float* pn_b2 = (const float*)d_in[7];
    const float* pn_w3 = (const float*)d_in[8];
    const float* pn_b3 = (const float*)d_in[9];
    const float* aw    = (const float*)d_in[10];
    const float* ab    = (const float*)d_in[11];
    const float* vx_w1 = (const float*)d_in[12];
    const float* vx_b1 = (const float*)d_in[13];
    const float* vx_w2 = (const float*)d_in[14];
    const float* vx_b2 = (const float*)d_in[15];
    const float* vx_w3 = (const float*)d_in[16];
    const float* vx_b3 = (const float*)d_in[17];
    const float* lwi   = (const float*)d_in[18];
    const float* lwh   = (const float*)d_in[19];
    const float* lb    = (const float*)d_in[20];

    float* ws  = (float*)d_ws;
    float* voxr = ws;
    float* c1r  = voxr + SZ_VOX;
    float* c2  = c1r + SZ_C1;
    float* vv  = c2 + SZ_C2;          // unused (layout stability)
    float* xwi = vv + SZ_VV;
    float* w1r = xwi + SZ_XWI;
    float* w2r = w1r + SZ_W1T;
    float* w3t = w2r + SZ_W2T;
    float* w2mr = w3t + SZ_W3T;
    unsigned short* voxh = (unsigned short*)voxr;
    unsigned short* c1h  = (unsigned short*)c1r;
    unsigned short* w1m = (unsigned short*)w1r;
    unsigned short* w2n = (unsigned short*)w2r;
    unsigned short* w2m = (unsigned short*)w2mr;
    unsigned short* w3m = (unsigned short*)xwi;  // aliases xwi head; xwi written later
    int*   idxb = (int*)c1r;          // idx lives in the (not-yet-written) c1 region

    float* out   = (float*)d_out;
    float* avec  = out;                   // 65536
    float* attnw = out + 65536;           // 1843200
    float* hn    = out + 65536 + 1843200; // 1024
    float* cn    = hn + 1024;             // 1024

    k_transpose<<<405, 256, 0, stream>>>(vx_w1, vx_w2, vx_w3, pn_w3, pn_w2,
                                         w1m, w2n, w3t, w3m, w2m);
    k_group<<<1024, 256, 0, stream>>>(x, g_loc, idxb);
    k_mlpm<<<14400, 128, 0, stream>>>(x, g_loc, idxb, pn_w1, pn_b1, w2m, pn_b2,
                                      w3m, pn_b3, aw, ab, voxh, attnw);
    k_conv1m<<<512, 256, 0, stream>>>(voxh, w1m, vx_b1, c1h);
    k_conv2m<<<512, 256, 0, stream>>>(c1h, w2n, vx_b2, c2);
    k_c3x<<<1024, 256, 0, stream>>>(c2, w3t, vx_b3, lwi, lb, xwi);
    k_lstm<<<16, 256, 0, stream>>>(xwi, lwh, h0, c0, avec, hn, cn);
}

// Round 12
// 353.868 us; speedup vs baseline: 2.4166x; 1.0118x over previous
//
#include <hip/hip_runtime.h>
#include <cmath>

// Shapes (fixed by the problem)
#define AT 225      // Z*Y*X anchors
#define NP 128      // points per sample
#define MT 1024     // B*T
#define NSEL 8
#define HD 64

// workspace float offsets
#define SZ_VOX  (1024u*64u*225u)     // region sized in floats; holds bf16 vox
#define SZ_C1   (1024u*96u*63u)      // region holds bf16 c1 (idx aliases head before conv1)
#define SZ_C2   (1024u*128u*5u)      // unused (c2 lives in LDS now)
#define SZ_VV   (1024u*64u)
#define SZ_XWI  (1024u*256u)         // (w3m aliases its head before k_c23 runs)
#define SZ_W1T  (64u*27u*96u)        // holds w1m (bf16 A-frags, conv1)
#define SZ_W2T  (96u*27u*128u)       // holds w2n (bf16 B-frags, conv2)
#define SZ_W3T  (640u*64u)
#define SZ_W2M  (512u)               // pn layer2 B-frags (128 uint4)

#define C2S 98                       // conv2 LDS row stride (us), 49 dw (odd)

typedef __attribute__((ext_vector_type(8))) short bf16x8;
typedef __attribute__((ext_vector_type(4))) float f32x4;

__device__ __forceinline__ float sigm(float x) { return 1.0f / (1.0f + expf(-x)); }

__device__ __forceinline__ unsigned short f2bf(float f) {
    unsigned u = __float_as_uint(f);
    unsigned r = u + 0x7FFF + ((u >> 16) & 1);   // RNE
    return (unsigned short)(r >> 16);
}

#if defined(__has_builtin)
#if __has_builtin(__builtin_amdgcn_cvt_pk_bf16_f32)
#define HAVE_CVT_PK_BF16 1
#endif
#endif

__device__ __forceinline__ unsigned pk2(float a, float b) {
#ifdef HAVE_CVT_PK_BF16
    auto v = __builtin_amdgcn_cvt_pk_bf16_f32(a, b);
    return __builtin_bit_cast(unsigned, v);
#else
    return (unsigned)f2bf(a) | ((unsigned)f2bf(b) << 16);
#endif
}

// ---------------------------------------------------------------- transpose
__global__ __launch_bounds__(256) void k_transpose(
    const float* __restrict__ w1, const float* __restrict__ w2,
    const float* __restrict__ w3, const float* __restrict__ pnw3,
    const float* __restrict__ pnw2,
    unsigned short* __restrict__ w1m, unsigned short* __restrict__ w2n,
    float* __restrict__ w3t, unsigned short* __restrict__ w3m,
    unsigned short* __restrict__ w2m)
{
    int idx = blockIdx.x * 256 + threadIdx.x;
    if (idx < 20736) {
        int lane = idx & 63, r = idx >> 6;
        int t = r % 6, s = r / 6;
        int o = t * 16 + (lane & 15);
        int kb = s * 32 + (lane >> 4) * 8;
        unsigned int dw[4];
        #pragma unroll
        for (int jd = 0; jd < 4; ++jd) {
            int k0 = kb + 2 * jd, k1 = k0 + 1;
            dw[jd] = (unsigned)f2bf(w1[o * 1728 + (k0 & 63) * 27 + (k0 >> 6)]) |
                     ((unsigned)f2bf(w1[o * 1728 + (k1 & 63) * 27 + (k1 >> 6)]) << 16);
        }
        uint4 v; v.x = dw[0]; v.y = dw[1]; v.z = dw[2]; v.w = dw[3];
        ((uint4*)w1m)[idx] = v;
    } else if (idx < 62208) {
        int q = idx - 20736;
        int lane = q & 63, r = q >> 6;
        int nt = r & 7, s = r >> 3;
        int o = nt * 16 + (lane & 15);
        int kb = s * 32 + (lane >> 4) * 8;
        unsigned int dw[4];
        #pragma unroll
        for (int jd = 0; jd < 4; ++jd) {
            int k0 = kb + 2 * jd, k1 = k0 + 1;
            dw[jd] = (unsigned)f2bf(w2[o * 2592 + (k0 % 96) * 27 + (k0 / 96)]) |
                     ((unsigned)f2bf(w2[o * 2592 + (k1 % 96) * 27 + (k1 / 96)]) << 16);
        }
        uint4 v; v.x = dw[0]; v.y = dw[1]; v.z = dw[2]; v.w = dw[3];
        ((uint4*)w2n)[q] = v;
    } else if (idx < 103168) {
        int k = idx - 62208;
        int u = k & 63, r = k >> 6;
        w3t[k] = w3[u * 640 + r];
    } else if (idx < 103424) {
        int k = idx - 103168;
        int lane = k & 63, nt = k >> 6;
        int n = nt * 16 + (lane & 15);
        int kb = (lane >> 4) * 8;
        unsigned int dw[4];
        #pragma unroll
        for (int jd = 0; jd < 4; ++jd) {
            int k0 = kb + 2 * jd;
            dw[jd] = (unsigned)f2bf(pnw3[k0 * 64 + n]) |
                     ((unsigned)f2bf(pnw3[(k0 + 1) * 64 + n]) << 16);
        }
        uint4 v; v.x = dw[0]; v.y = dw[1]; v.z = dw[2]; v.w = dw[3];
        ((uint4*)w3m)[k] = v;
    } else if (idx < 103552) {
        int k = idx - 103424;
        int lane = k & 63, nt = k >> 6;          // nt 0..1
        int n = nt * 16 + (lane & 15);
        int kb = (lane >> 4) * 8;
        unsigned int dw[4];
        #pragma unroll
        for (int jd = 0; jd < 4; ++jd) {
            int k0 = kb + 2 * jd, k1 = k0 + 1;
            float a = (k0 < 16) ? pnw2[k0 * 32 + n] : 0.0f;
            float b = (k1 < 16) ? pnw2[k1 * 32 + n] : 0.0f;
            dw[jd] = (unsigned)f2bf(a) | ((unsigned)f2bf(b) << 16);
        }
        uint4 v; v.x = dw[0]; v.y = dw[1]; v.z = dw[2]; v.w = dw[3];
        ((uint4*)w2m)[k] = v;
    }
}

// ---------------------------------------------------------------- grouping
// R10-verbatim: selection codegen is bit-stable in THIS compilation context;
// fusing it elsewhere changed FMA contraction and flipped near-tie neighbor
// picks (R11 failure). Do not merge into k_mlpm.
__global__ __launch_bounds__(256) void k_group(
    const float* __restrict__ x, const float* __restrict__ g_loc,
    int* __restrict__ idxbuf)
{
    const int m = blockIdx.x;
    const int tid = threadIdx.x;
    __shared__ float pts[3][NP];

    for (int idx = tid; idx < NP * 5; idx += 256) {
        int n = idx / 5, c = idx % 5;
        if (c < 3) pts[c][n] = x[m * (NP * 5) + idx];
    }
    __syncthreads();

    const float gx = g_loc[m * 2 + 0], gy = g_loc[m * 2 + 1];
    const int grp = tid >> 3, li = tid & 7;

    for (int ca = 0; ca < 256; ca += 32) {
        const int a = ca + grp;
        const bool active = (a < AT);
        const int aa = active ? a : (AT - 1);
        const int azi = aa / 25, ar = aa % 25, ayi = ar / 5, axi = ar % 5;
        const float fx = ((float)axi - 2.0f) * 0.2f + gx;
        const float fy = ((float)ayi - 2.0f) * 0.2f + gy;
        const float fz = (float)azi * 0.22f + 0.1f;
        const float sa = fx * fx + fy * fy + fz * fz;

        float d[16];
        #pragma unroll
        for (int r = 0; r < 16; ++r) {
            int n = li * 16 + r;
            float px = pts[0][n], py = pts[1][n], pz = pts[2][n];
            d[r] = sa - 2.0f * (fx * px + fy * py + fz * pz)
                      + (px * px + py * py + pz * pz);
        }
        int nidx = 0;
        for (int j = 0; j < NSEL; ++j) {
            float best = 1e30f; int bidx = 0;
            #pragma unroll
            for (int r = 0; r < 16; ++r) {
                int n = li * 16 + r;
                if (d[r] < best) { best = d[r]; bidx = n; }
            }
            #pragma unroll
            for (int off = 1; off < 8; off <<= 1) {
                float ov = __shfl_xor(best, off);
                int   oi = __shfl_xor(bidx, off);
                if (ov < best || (ov == best && oi < bidx)) { best = ov; bidx = oi; }
            }
            if (li == j) nidx = bidx;
            if ((bidx >> 4) == li) {
                int slot = bidx & 15;
                #pragma unroll
                for (int r = 0; r < 16; ++r)
                    if (r == slot) d[r] = 1e30f;
            }
        }
        if (active) idxbuf[(m * AT + a) * NSEL + li] = nidx;
    }
}

// ---------------------------------------------------------------- MLP (MFMA L2+L3)
// R10-verbatim. LDS aliasing (barrier-separated; punned ushort/uint REQUIRES
// barriers — R6):
//   [0,8704)      fbuf (f1 then f2)  ... sbuf (4160 B) aliases head in phase C
//   [8704,25600)  f3us (16896 B)     ... pts (5120 B, raw x-layout) aliases head
__global__ __launch_bounds__(128) void k_mlpm(
    const float* __restrict__ x, const float* __restrict__ g_loc,
    const int* __restrict__ idxbuf,
    const float* __restrict__ w1, const float* __restrict__ b1,
    const unsigned short* __restrict__ w2m, const float* __restrict__ b2,
    const unsigned short* __restrict__ w3m, const float* __restrict__ b3,
    const float* __restrict__ aw, const float* __restrict__ ab,
    unsigned short* __restrict__ vox, float* __restrict__ attn_out)
{
    const int tid = threadIdx.x;
    const int row0 = blockIdx.x * 128;
    const int row = row0 + tid;

    __shared__ __align__(16) char smem[25600];
    unsigned int*   fbuf = (unsigned int*)smem;              // 8704 B
    unsigned short* f3us = (unsigned short*)(smem + 8704);   // 16896 B
    float*          pts  = (float*)(smem + 8704);            // aliases f3us head
    float*          sbuf = (float*)smem;                     // aliases fbuf head

    const int m0 = row0 / 1800;
    const int m1 = (row0 + 127) / 1800;
    #pragma unroll
    for (int i = tid; i < 640; i += 128) {
        pts[i]       = x[m0 * 640 + i];
        pts[640 + i] = x[m1 * 640 + i];
    }
    __syncthreads();

    // ---- phase A: layer 1 per-thread, pack f1 to fbuf (K 16..31 zeroed) ----
    const int m = row / 1800;
    const int rr = row % 1800;
    const int a = rr >> 3;
    const int base = (m == m0) ? 0 : 640;

    const int azi = a / 25, ar = a % 25, ayi = ar / 5, axi = ar % 5;
    const float gx = g_loc[m * 2 + 0], gy = g_loc[m * 2 + 1];
    const float fx = ((float)axi - 2.0f) * 0.2f + gx;
    const float fy = ((float)ayi - 2.0f) * 0.2f + gy;
    const float fz = (float)azi * 0.22f + 0.1f;

    const int nidx = idxbuf[row];
    const float in0 = pts[base + nidx * 5 + 0] - fx;
    const float in1 = pts[base + nidx * 5 + 1] - fy;
    const float in2 = pts[base + nidx * 5 + 2] - fz;
    const float in3 = pts[base + nidx * 5 + 3];
    const float in4 = pts[base + nidx * 5 + 4];

    float f1v[16];
    #pragma unroll
    for (int j = 0; j < 16; ++j) {
        float s = b1[j];
        s += in0 * w1[0 * 16 + j] + in1 * w1[1 * 16 + j] + in2 * w1[2 * 16 + j]
           + in3 * w1[3 * 16 + j] + in4 * w1[4 * 16 + j];
        f1v[j] = fmaxf(s, 0.0f);
    }
    __syncthreads();   // pts reads complete before fbuf/f3us reuse
    #pragma unroll
    for (int kd = 0; kd < 8; ++kd)
        fbuf[tid * 17 + kd] = pk2(f1v[2 * kd], f1v[2 * kd + 1]);
    #pragma unroll
    for (int kd = 8; kd < 16; ++kd)
        fbuf[tid * 17 + kd] = 0u;
    __syncthreads();

    // ---- phase B: MFMA layers ----
    const int wv = tid >> 6, lane = tid & 63;
    const int quad = lane >> 4, mcol = lane & 15;
    unsigned short* fus = (unsigned short*)fbuf;   // row stride 34 us

    // layer 2: D[128 rows][32] = f1 @ w2 (K=32 padded)
    bf16x8 w2f[2];
    #pragma unroll
    for (int nt = 0; nt < 2; ++nt) {
        uint4 u = ((const uint4*)w2m)[nt * 64 + lane];
        w2f[nt] = __builtin_bit_cast(bf16x8, u);
    }
    float b2v[2] = { b2[mcol], b2[16 + mcol] };

    #pragma unroll
    for (int mt = 0; mt < 4; ++mt) {
        const int rowbase = (wv * 4 + mt) * 16;
        const int abase = (rowbase + mcol) * 17 + quad * 4;
        uint4 au;
        au.x = fbuf[abase + 0]; au.y = fbuf[abase + 1];
        au.z = fbuf[abase + 2]; au.w = fbuf[abase + 3];
        bf16x8 af = __builtin_bit_cast(bf16x8, au);
        #pragma unroll
        for (int nt = 0; nt < 2; ++nt) {
            f32x4 z = (f32x4){0.f, 0.f, 0.f, 0.f};
            f32x4 acc = __builtin_amdgcn_mfma_f32_16x16x32_bf16(af, w2f[nt], z, 0, 0, 0);
            #pragma unroll
            for (int reg = 0; reg < 4; ++reg) {
                float v = fmaxf(acc[reg] + b2v[nt], 0.0f);
                fus[(rowbase + quad * 4 + reg) * 34 + nt * 16 + mcol] = f2bf(v);
            }
        }
    }
    __syncthreads();   // fence: ushort f2 stores -> uint A-frag loads (L3)

    // layer 3: D[128 rows][64] = f2 @ w3
    bf16x8 w3f[4];
    #pragma unroll
    for (int nt = 0; nt < 4; ++nt) {
        uint4 u = ((const uint4*)w3m)[nt * 64 + lane];
        w3f[nt] = __builtin_bit_cast(bf16x8, u);
    }
    float b3v[4];
    #pragma unroll
    for (int nt = 0; nt < 4; ++nt) b3v[nt] = b3[nt * 16 + mcol];

    #pragma unroll
    for (int mt = 0; mt < 4; ++mt) {
        const int rowbase = (wv * 4 + mt) * 16;
        const int abase = (rowbase + mcol) * 17 + quad * 4;
        uint4 au;
        au.x = fbuf[abase + 0]; au.y = fbuf[abase + 1];
        au.z = fbuf[abase + 2]; au.w = fbuf[abase + 3];
        bf16x8 af = __builtin_bit_cast(bf16x8, au);
        #pragma unroll
        for (int nt = 0; nt < 4; ++nt) {
            f32x4 z = (f32x4){0.f, 0.f, 0.f, 0.f};
            f32x4 acc = __builtin_amdgcn_mfma_f32_16x16x32_bf16(af, w3f[nt], z, 0, 0, 0);
            #pragma unroll
            for (int reg = 0; reg < 4; ++reg) {
                float v = fmaxf(acc[reg] + b3v[nt], 0.0f);
                f3us[(rowbase + quad * 4 + reg) * 66 + nt * 16 + mcol] = f2bf(v);
            }
        }
    }
    __syncthreads();   // fence: ushort f3 stores -> uint phase-C loads

    // ---- phase C: score, softmax, weighted sum ----
    const unsigned int* f3dw = (const unsigned int*)f3us;   // row stride 33 dw
    float s0 = 0.f, s1 = 0.f;
    #pragma unroll
    for (int kd = 0; kd < 32; ++kd) {
        unsigned dw = f3dw[tid * 33 + kd];
        s0 = fmaf(__uint_as_float(dw << 16), aw[2 * kd], s0);
        s1 = fmaf(__uint_as_float(dw & 0xFFFF0000u), aw[2 * kd + 1], s1);
    }
    float sc = s0 + s1 + ab[0];

    float mx = sc;
    #pragma unroll
    for (int off = 1; off < 8; off <<= 1) mx = fmaxf(mx, __shfl_xor(mx, off));
    float e = expf(sc - mx);
    float den = e;
    #pragma unroll
    for (int off = 1; off < 8; off <<= 1) den += __shfl_xor(den, off);
    const float at = e / den;
    attn_out[row] = at;

    // lane li owns h = q*16 + li*2 + {0,1}  (conflict-free b32 reads)
    const int lgrp = tid >> 3;
    const int li = tid & 7;
    const int wl = tid & 63;
    float oo[8];
    #pragma unroll
    for (int i = 0; i < 8; ++i) oo[i] = 0.0f;
    #pragma unroll
    for (int ns = 0; ns < 8; ++ns) {
        float atn = __shfl(at, (wl >> 3) * 8 + ns);
        const int rbase = (lgrp * 8 + ns) * 33;
        #pragma unroll
        for (int q = 0; q < 4; ++q) {
            unsigned dw = f3dw[rbase + q * 8 + li];
            oo[2 * q + 0] = fmaf(atn, __uint_as_float(dw << 16), oo[2 * q + 0]);
            oo[2 * q + 1] = fmaf(atn, __uint_as_float(dw & 0xFFFF0000u), oo[2 * q + 1]);
        }
    }
    __syncthreads();   // fence: fbuf A-frag loads done -> sbuf (alias) writes
    #pragma unroll
    for (int q = 0; q < 4; ++q) {
        sbuf[lgrp * 65 + q * 16 + li * 2 + 0] = oo[2 * q + 0];
        sbuf[lgrp * 65 + q * 16 + li * 2 + 1] = oo[2 * q + 1];
    }
    __syncthreads();

    const int al = tid & 15, j = tid >> 4;
    const int ga = (row0 >> 3) + al;
    const int ma = ga / 225, aa2 = ga % 225;
    #pragma unroll
    for (int rep = 0; rep < 8; ++rep) {
        int h = j * 8 + rep;
        vox[(ma * 64 + h) * AT + aa2] = f2bf(sbuf[al * 65 + h]);
    }
}

// ---------------------------------------------------------------- conv1 MFMA
// 2 images per block; shared A stream; barrier every 4 K-steps aligns the 4
// waves so identical A-addresses hit L1 (numerics-neutral, scheduling only).
__global__ __launch_bounds__(256) void k_conv1m(
    const unsigned short* __restrict__ vox, const unsigned short* __restrict__ w1m,
    const float* __restrict__ b1, unsigned short* __restrict__ out)
{
    const int m0 = blockIdx.x * 2;
    const int tid = threadIdx.x;
    __shared__ unsigned short voxT[2][225 * 66];

    #pragma unroll
    for (int img = 0; img < 2; ++img) {
        const unsigned int* vsrc =
            (const unsigned int*)(vox + (size_t)(m0 + img) * 14400);
        for (int i = tid; i < 7200; i += 256) {
            unsigned v = vsrc[i];
            int e0 = 2 * i, e1 = e0 + 1;
            int c0 = e0 / 225, a0 = e0 - c0 * 225;
            int c1i = e1 / 225, a1 = e1 - c1i * 225;
            voxT[img][a0 * 66 + c0] = (unsigned short)(v & 0xFFFFu);
            voxT[img][a1 * 66 + c1i] = (unsigned short)(v >> 16);
        }
    }
    __syncthreads();

    const int wv = tid >> 6, lane = tid & 63;
    const int quad = lane >> 4, n = lane & 15;
    const int p = wv * 16 + n;
    const int pe = (p > 62) ? 62 : p;
    const int zo = pe / 9, pr = pe % 9, yo = pr / 3, xo = pr % 3;
    const int basep = zo * 25 + yo * 5 + xo;

    f32x4 acc[2][6];
    #pragma unroll
    for (int g = 0; g < 2; ++g)
        #pragma unroll
        for (int t = 0; t < 6; ++t) acc[g][t] = (f32x4){0.f, 0.f, 0.f, 0.f};

    const uint4* Aptr = (const uint4*)w1m;

    auto loadB = [&](int img, int s) -> uint4 {
        int tap = s >> 1;
        int dz = tap / 9, tr = tap % 9, dy = tr / 3, dx = tr % 3;
        int rw = basep + dz * 25 + dy * 5 + dx;
        int bidx = rw * 66 + (s & 1) * 32 + quad * 8;
        const unsigned int* vp = (const unsigned int*)(&voxT[img][0] + bidx);
        uint4 r; r.x = vp[0]; r.y = vp[1]; r.z = vp[2]; r.w = vp[3];
        return r;
    };

    uint4 Acur[6], Anxt[6];
    uint4 Bcur[2], Bnxt[2];
    #pragma unroll
    for (int t = 0; t < 6; ++t) Acur[t] = Aptr[t * 64 + lane];
    Bcur[0] = loadB(0, 0); Bcur[1] = loadB(1, 0);

    for (int s = 0; s < 54; ++s) {
        if ((s & 3) == 0) __syncthreads();   // align waves for L1 A-reuse
        if (s < 53) {
            Bnxt[0] = loadB(0, s + 1);
            Bnxt[1] = loadB(1, s + 1);
            #pragma unroll
            for (int t = 0; t < 6; ++t)
                Anxt[t] = Aptr[((s + 1) * 6 + t) * 64 + lane];
        }
        bf16x8 bf0 = __builtin_bit_cast(bf16x8, Bcur[0]);
        bf16x8 bf1 = __builtin_bit_cast(bf16x8, Bcur[1]);
        #pragma unroll
        for (int t = 0; t < 6; ++t) {
            bf16x8 af = __builtin_bit_cast(bf16x8, Acur[t]);
            acc[0][t] = __builtin_amdgcn_mfma_f32_16x16x32_bf16(af, bf0, acc[0][t], 0, 0, 0);
            acc[1][t] = __builtin_amdgcn_mfma_f32_16x16x32_bf16(af, bf1, acc[1][t], 0, 0, 0);
        }
        #pragma unroll
        for (int t = 0; t < 6; ++t) Acur[t] = Anxt[t];
        Bcur[0] = Bnxt[0]; Bcur[1] = Bnxt[1];
    }

    if (p < 63) {
        #pragma unroll
        for (int g = 0; g < 2; ++g) {
            #pragma unroll
            for (int t = 0; t < 6; ++t) {
                #pragma unroll
                for (int r = 0; r < 4; ++r) {
                    int o = t * 16 + quad * 4 + r;
                    out[(m0 + g) * (96 * 63) + o * 63 + p] =
                        f2bf(fmaxf(acc[g][t][r] + b1[o], 0.0f));
                }
            }
        }
    }
}

// ---------------------------------------------------------------- conv2 + conv3 + xwi
// conv2 MFMA exactly as R10 (2 images/block, grid 512); c2 passes through LDS
// as f32 (identical values to R10's HBM round-trip); conv3 + xwi use R10's
// EXACT summation order (4x160-K partials, (p0+p1)+(p2+p3), sequential xwi).
__global__ __launch_bounds__(256) void k_c23(
    const unsigned short* __restrict__ c1, const unsigned short* __restrict__ w2n,
    const float* __restrict__ b2, const float* __restrict__ w3t,
    const float* __restrict__ b3, const float* __restrict__ wi,
    const float* __restrict__ lb, float* __restrict__ xwi)
{
    const int tid = threadIdx.x;
    const int m0 = blockIdx.x * 2;
    __shared__ unsigned short c1T[2 * 63 * C2S];   // 24696 B
    __shared__ float c2l[2][640];                  // 5120 B
    __shared__ float part[2][4][64];               // 2048 B
    __shared__ float vvl[2][64];                   // 512 B

    const unsigned int* csrc = (const unsigned int*)(c1 + (size_t)m0 * 6048);
    for (int i = tid; i < 6048; i += 256) {
        unsigned v = csrc[i];
        int e0 = 2 * i;
        int mi = (i >= 3024);
        int r0 = e0 - mi * 6048, r1 = r0 + 1;
        int o0 = r0 / 63, p0 = r0 - o0 * 63;
        int o1 = r1 / 63, p1 = r1 - o1 * 63;
        c1T[(mi * 63 + p0) * C2S + o0] = (unsigned short)(v & 0xFFFFu);
        c1T[(mi * 63 + p1) * C2S + o1] = (unsigned short)(v >> 16);
    }
    __syncthreads();

    const int wv = tid >> 6, lane = tid & 63;
    const int quad = lane >> 4, ncol = lane & 15;
    const int arow = lane & 15;
    const int mi = (arow < 10) ? arow / 5 : 1;
    const int zo = (arow < 10) ? arow % 5 : 4;

    f32x4 acc[2];
    acc[0] = (f32x4){0.f, 0.f, 0.f, 0.f};
    acc[1] = (f32x4){0.f, 0.f, 0.f, 0.f};
    const uint4* Bptr = (const uint4*)w2n;

    for (int tap = 0; tap < 27; ++tap) {
        const int dz = tap / 9, r9 = tap % 9;
        const int rowb = (mi * 63 + (zo + dz) * 9 + r9) * C2S;
        #pragma unroll
        for (int sub = 0; sub < 3; ++sub) {
            const int s = tap * 3 + sub;
            const unsigned int* ap =
                (const unsigned int*)(c1T + rowb + sub * 32 + quad * 8);
            uint4 au; au.x = ap[0]; au.y = ap[1]; au.z = ap[2]; au.w = ap[3];
            bf16x8 af = __builtin_bit_cast(bf16x8, au);
            #pragma unroll
            for (int nt = 0; nt < 2; ++nt) {
                uint4 bu = Bptr[(s * 8 + wv * 2 + nt) * 64 + lane];
                bf16x8 bf = __builtin_bit_cast(bf16x8, bu);
                acc[nt] = __builtin_amdgcn_mfma_f32_16x16x32_bf16(af, bf, acc[nt], 0, 0, 0);
            }
        }
    }

    #pragma unroll
    for (int nt = 0; nt < 2; ++nt) {
        const int o = (wv * 2 + nt) * 16 + ncol;
        const float bias = b2[o];
        #pragma unroll
        for (int reg = 0; reg < 4; ++reg) {
            int rr = quad * 4 + reg;
            if (rr < 10)
                c2l[rr / 5][o * 5 + (rr % 5)] = fmaxf(acc[nt][reg] + bias, 0.0f);
        }
    }
    __syncthreads();

    // conv3: R10 order — per image, 4 partials of 160 K each (u=tid&63,
    // kq=tid>>6), sequential fmaf chain, unroll 8.
    {
        const int u = tid & 63, kq = tid >> 6;
        const int k0 = kq * 160;
        #pragma unroll
        for (int mi2 = 0; mi2 < 2; ++mi2) {
            float acc3 = 0.0f;
            #pragma unroll 8
            for (int k = k0; k < k0 + 160; ++k)
                acc3 = fmaf(c2l[mi2][k], w3t[k * 64 + u], acc3);
            part[mi2][kq][u] = acc3;
        }
    }
    __syncthreads();
    if (tid < 128) {
        int mi2 = tid >> 6, u = tid & 63;
        vvl[mi2][u] = b3[u] + ((part[mi2][0][u] + part[mi2][1][u])
                    + (part[mi2][2][u] + part[mi2][3][u]));
    }
    __syncthreads();

    // xwi: R10 order — sequential k 0..63
    #pragma unroll
    for (int mi2 = 0; mi2 < 2; ++mi2) {
        float a2 = lb[tid];
        #pragma unroll
        for (int k = 0; k < 64; ++k)
            a2 = fmaf(vvl[mi2][k], wi[k * 256 + tid], a2);
        xwi[(m0 + mi2) * 256 + tid] = a2;
    }
}

// ---------------------------------------------------------------- LSTM
__global__ __launch_bounds__(256) void k_lstm(
    const float* __restrict__ xwi, const float* __restrict__ whg,
    const float* __restrict__ h0, const float* __restrict__ c0,
    float* __restrict__ avec, float* __restrict__ hn, float* __restrict__ cn)
{
    const int b = blockIdx.x;
    const int j = threadIdx.x;
    __shared__ __align__(16) float hbuf[64];
    __shared__ float gbuf[256];

    float wh[64];
    #pragma unroll
    for (int k = 0; k < 64; ++k) wh[k] = whg[k * 256 + j];

    if (j < 64) hbuf[j] = h0[b * 64 + j];
    float c = (j < 64) ? c0[b * 64 + j] : 0.0f;
    const bool is_tanh_gate = ((j >> 6) == 2);
    __syncthreads();

    const float4* hb4 = (const float4*)hbuf;
    for (int t = 0; t < 64; ++t) {
        float g = xwi[(b * 64 + t) * 256 + j];
        float p[4] = {0.f, 0.f, 0.f, 0.f};
        #pragma unroll
        for (int k4 = 0; k4 < 16; ++k4) {
            float4 h4 = hb4[k4];
            int q = k4 & 3;
            p[q] = fmaf(h4.x, wh[4 * k4 + 0], p[q]);
            p[q] = fmaf(h4.y, wh[4 * k4 + 1], p[q]);
            p[q] = fmaf(h4.z, wh[4 * k4 + 2], p[q]);
            p[q] = fmaf(h4.w, wh[4 * k4 + 3], p[q]);
        }
        g += (p[0] + p[1]) + (p[2] + p[3]);
        gbuf[j] = is_tanh_gate ? tanhf(g) : sigm(g);
        __syncthreads();
        if (j < 64) {
            c = gbuf[64 + j] * c + gbuf[j] * gbuf[128 + j];
            float h = gbuf[192 + j] * tanhf(c);
            hbuf[j] = h;
            avec[(b * 64 + t) * 64 + j] = h;
        }
        __syncthreads();
    }
    if (j < 64) {
        hn[b * 64 + j] = hbuf[j];
        cn[b * 64 + j] = c;
    }
}

// ---------------------------------------------------------------- launch
extern "C" void kernel_launch(void* const* d_in, const int* in_sizes, int n_in,
                              void* d_out, int out_size, void* d_ws, size_t ws_size,
                              hipStream_t stream) {
    const float* x     = (const float*)d_in[0];
    const float* g_loc = (const float*)d_in[1];
    const float* h0    = (const float*)d_in[2];
    const float* c0    = (const float*)d_in[3];
    const float* pn_w1 = (const float*)d_in[4];
    const float* pn_b1 = (const float*)d_in[5];
    const float* pn_w2 = (const float*)d_in[6];
    const float* pn_b2 = (const float*)d_in[7];
    const float* pn_w3 = (const float*)d_in[8];
    const float* pn_b3 = (const float*)d_in[9];
    const float* aw    = (const float*)d_in[10];
    const float* ab    = (const float*)d_in[11];
    const float* vx_w1 = (const float*)d_in[12];
    const float* vx_b1 = (const float*)d_in[13];
    const float* vx_w2 = (const float*)d_in[14];
    const float* vx_b2 = (const float*)d_in[15];
    const float* vx_w3 = (const float*)d_in[16];
    const float* vx_b3 = (const float*)d_in[17];
    const float* lwi   = (const float*)d_in[18];
    const float* lwh   = (const float*)d_in[19];
    const float* lb    = (const float*)d_in[20];

    float* ws  = (float*)d_ws;
    float* voxr = ws;
    float* c1r  = voxr + SZ_VOX;
    float* c2  = c1r + SZ_C1;         // unused (c2 in LDS; layout stability)
    float* vv  = c2 + SZ_C2;          // unused
    float* xwi = vv + SZ_VV;
    float* w1r = xwi + SZ_XWI;
    float* w2r = w1r + SZ_W1T;
    float* w3t = w2r + SZ_W2T;
    float* w2mr = w3t + SZ_W3T;
    unsigned short* voxh = (unsigned short*)voxr;
    unsigned short* c1h  = (unsigned short*)c1r;
    unsigned short* w1m = (unsigned short*)w1r;
    unsigned short* w2n = (unsigned short*)w2r;
    unsigned short* w2m = (unsigned short*)w2mr;
    unsigned short* w3m = (unsigned short*)xwi;  // aliases xwi head; xwi written later
    int*   idxb = (int*)c1r;          // idx lives in the (not-yet-written) c1 region

    float* out   = (float*)d_out;
    float* avec  = out;                   // 65536
    float* attnw = out + 65536;           // 1843200
    float* hn    = out + 65536 + 1843200; // 1024
    float* cn    = hn + 1024;             // 1024

    k_transpose<<<405, 256, 0, stream>>>(vx_w1, vx_w2, vx_w3, pn_w3, pn_w2,
                                         w1m, w2n, w3t, w3m, w2m);
    k_group<<<1024, 256, 0, stream>>>(x, g_loc, idxb);
    k_mlpm<<<14400, 128, 0, stream>>>(x, g_loc, idxb, pn_w1, pn_b1, w2m, pn_b2,
                                      w3m, pn_b3, aw, ab, voxh, attnw);
    k_conv1m<<<512, 256, 0, stream>>>(voxh, w1m, vx_b1, c1h);
    k_c23<<<512, 256, 0, stream>>>(c1h, w2n, vx_b2, w3t, vx_b3, lwi, lb, xwi);
    k_lstm<<<16, 256, 0, stream>>>(xwi, lwh, h0, c0, avec, hn, cn);
}